// Round 10
// baseline (1585.283 us; speedup 1.0000x reference)
//
#include <hip/hip_runtime.h>
#include <float.h>
#include <type_traits>

#define BB 8
#define NN 2048
#define KNN 20

__device__ __forceinline__ float leaky(float v) { return fmaxf(v, 0.2f * v); }

// ---------- transpose x (B,3,N) -> xt (B,N,3) ----------
__global__ void k_transpose_x(const float* __restrict__ x, float* __restrict__ xt) {
    int i = blockIdx.x * 256 + threadIdx.x;
    if (i >= BB * NN * 3) return;
    int c = i % 3; int n = (i / 3) % NN; int b = i / (3 * NN);
    xt[i] = x[((size_t)b * 3 + c) * NN + n];
}

// ---------- LDS-tiled transpose w (CO,CI) -> wt (CI,CO), 64x64 tiles ----------
__global__ __launch_bounds__(256) void k_transpose_w_tiled(const float* __restrict__ w,
                                                           float* __restrict__ wt,
                                                           int CO, int CI) {
    __shared__ float tile[64][65];
    int o0 = blockIdx.x * 64;
    int c0 = blockIdx.y * 64;
    int tid = threadIdx.x;
    for (int i = tid; i < 64 * 64; i += 256) {
        int r = i >> 6, c = i & 63;
        tile[r][c] = w[(size_t)(o0 + r) * CI + c0 + c];
    }
    __syncthreads();
    for (int i = tid; i < 64 * 64; i += 256) {
        int cc = i >> 6, oo = i & 63;
        wt[(size_t)(c0 + cc) * CO + o0 + oo] = tile[oo][cc];
    }
}

// ---------- all 4 edgeconv weight splits in ONE dispatch ----------
__device__ __forceinline__ void wpair_one(const float* __restrict__ w, float* __restrict__ wtA,
                                          float* __restrict__ wtD, int CO, int CI, int i) {
    int o = i / CI, c = i % CI;
    float a = w[(size_t)o * 2 * CI + c];
    float bb = w[(size_t)o * 2 * CI + CI + c];
    wtA[c * CO + o] = a;
    wtD[c * CO + o] = bb - a;
}
__global__ void k_wpair_all(const float* w1, const float* w2, const float* w3, const float* w4,
                            float* A1, float* D1, float* A2, float* D2,
                            float* A3, float* D3, float* A4, float* D4) {
    int i = blockIdx.x * 256 + threadIdx.x;
    if (i < 192)            { wpair_one(w1, A1, D1, 64, 3, i); }
    else if (i < 4288)      { wpair_one(w2, A2, D2, 64, 64, i - 192); }
    else if (i < 12480)     { wpair_one(w3, A3, D3, 128, 64, i - 4288); }
    else if (i < 45248)     { wpair_one(w4, A4, D4, 256, 128, i - 12480); }
}

// ---------- squared norms per point ----------
template<int C>
__global__ void k_xx(const float* __restrict__ F, int FS, float* __restrict__ xx) {
    int i = blockIdx.x * 256 + threadIdx.x;
    if (i >= BB * NN) return;
    const float* r = F + (size_t)i * FS;
    float s = 0.f;
    #pragma unroll
    for (int c = 0; c < C; ++c) { float v = r[c]; s += v * v; }
    xx[i] = s;
}

// ---------- distance matrix, small-C (C=3): 64x64 tile ----------
template<int C>
__global__ __launch_bounds__(256) void k_dist(const float* __restrict__ F, int FS,
                                              const float* __restrict__ xx, int b0,
                                              float* __restrict__ D) {
    __shared__ __align__(16) float Xi[C * 64];
    __shared__ __align__(16) float Xj[C * 64];
    int tid = threadIdx.x;
    int bl = blockIdx.x >> 10;
    int t  = blockIdx.x & 1023;
    int i0 = (t >> 5) * 64, j0 = (t & 31) * 64;
    int b = b0 + bl;
    const float* Fb = F + (size_t)b * NN * FS;
    int ty = tid >> 4, tx = tid & 15;
    float acc[4][4] = {};
    for (int k = tid; k < 64 * C; k += 256) {
        int r = k & 63, c = k >> 6;
        Xi[c * 64 + r] = Fb[(size_t)(i0 + r) * FS + c];
        Xj[c * 64 + r] = Fb[(size_t)(j0 + r) * FS + c];
    }
    __syncthreads();
    for (int c = 0; c < C; ++c) {
        float a[4], bv[4];
        *(float4*)a  = *(const float4*)&Xi[c * 64 + 4 * ty];
        *(float4*)bv = *(const float4*)&Xj[c * 64 + 4 * tx];
        #pragma unroll
        for (int r = 0; r < 4; ++r)
            #pragma unroll
            for (int s = 0; s < 4; ++s) acc[r][s] += a[r] * bv[s];
    }
    const float* xxb = xx + (size_t)b * NN;
    float xxi[4], xxj[4];
    #pragma unroll
    for (int r = 0; r < 4; ++r) xxi[r] = xxb[i0 + 4 * ty + r];
    #pragma unroll
    for (int s = 0; s < 4; ++s) xxj[s] = xxb[j0 + 4 * tx + s];
    float* Dp = D + (size_t)bl * NN * NN;
    #pragma unroll
    for (int r = 0; r < 4; ++r) {
        float ov[4];
        #pragma unroll
        for (int s = 0; s < 4; ++s) ov[s] = 2.f * acc[r][s] - xxi[r] - xxj[s];
        *(float4*)(Dp + (size_t)(i0 + 4 * ty + r) * NN + j0 + 4 * tx) = *(float4*)ov;
    }
}

// ---------- distance matrix, big-C (64/128): 128x128 tile, 8x8 micro-tile ----------
template<int C>
__global__ __launch_bounds__(256) void k_dist128(const float* __restrict__ F, int FS,
                                                 const float* __restrict__ xx, int b0,
                                                 float* __restrict__ D) {
    constexpr int NCH = C / 32;
    __shared__ __align__(16) float Xi[32 * 128];
    __shared__ __align__(16) float Xj[32 * 128];
    int tid = threadIdx.x;
    int ty = tid >> 4, tx = tid & 15;
    int bl = blockIdx.x >> 8;
    int t  = blockIdx.x & 255;
    int i0 = (t >> 4) * 128, j0 = (t & 15) * 128;
    int b = b0 + bl;
    const float* Fb = F + (size_t)b * NN * FS;
    float acc[8][8] = {};
    for (int ch = 0; ch < NCH; ++ch) {
        int cb = ch * 32;
        if (ch) __syncthreads();
        for (int k = tid; k < 128 * 8; k += 256) {
            int r = k & 127, cc = k >> 7;
            float vi[4], vj[4];
            *(float4*)vi = *(const float4*)(Fb + (size_t)(i0 + r) * FS + cb + 4 * cc);
            *(float4*)vj = *(const float4*)(Fb + (size_t)(j0 + r) * FS + cb + 4 * cc);
            #pragma unroll
            for (int u = 0; u < 4; ++u) {
                Xi[(4 * cc + u) * 128 + r] = vi[u];
                Xj[(4 * cc + u) * 128 + r] = vj[u];
            }
        }
        __syncthreads();
        for (int c = 0; c < 32; ++c) {
            float a0[4], a1[4], w0[4], w1[4];
            *(float4*)a0 = *(const float4*)&Xi[c * 128 + 4 * ty];
            *(float4*)a1 = *(const float4*)&Xi[c * 128 + 64 + 4 * ty];
            *(float4*)w0 = *(const float4*)&Xj[c * 128 + 4 * tx];
            *(float4*)w1 = *(const float4*)&Xj[c * 128 + 64 + 4 * tx];
            #pragma unroll
            for (int r = 0; r < 4; ++r)
                #pragma unroll
                for (int s = 0; s < 4; ++s) {
                    acc[r][s]         += a0[r] * w0[s];
                    acc[r][4 + s]     += a0[r] * w1[s];
                    acc[4 + r][s]     += a1[r] * w0[s];
                    acc[4 + r][4 + s] += a1[r] * w1[s];
                }
        }
    }
    const float* xxb = xx + (size_t)b * NN;
    float xxi[8], xxj[8];
    #pragma unroll
    for (int r = 0; r < 4; ++r) {
        xxi[r]     = xxb[i0 + 4 * ty + r];
        xxi[4 + r] = xxb[i0 + 64 + 4 * ty + r];
        xxj[r]     = xxb[j0 + 4 * tx + r];
        xxj[4 + r] = xxb[j0 + 64 + 4 * tx + r];
    }
    float* Dp = D + (size_t)bl * NN * NN;
    #pragma unroll
    for (int r = 0; r < 8; ++r) {
        int row = i0 + (r < 4 ? 4 * ty + r : 64 + 4 * ty + (r - 4));
        float ov0[4], ov1[4];
        #pragma unroll
        for (int s = 0; s < 4; ++s) {
            ov0[s] = 2.f * acc[r][s]     - xxi[r] - xxj[s];
            ov1[s] = 2.f * acc[r][4 + s] - xxi[r] - xxj[4 + s];
        }
        *(float4*)(Dp + (size_t)row * NN + j0 + 4 * tx)      = *(float4*)ov0;
        *(float4*)(Dp + (size_t)row * NN + j0 + 64 + 4 * tx) = *(float4*)ov1;
    }
}

// ---------- top-20 selection: one BLOCK (256 thr) per query.
// Thread holds 8 dists in regs; per round: 7 reg compares -> 6-shfl wave
// reduce -> 4-entry LDS merge; owner clears via unrolled predicated compare.
// 8 waves/SIMD resident (2048 blocks/chunk) hides the round latency. ----------
__global__ __launch_bounds__(256) void k_select(const float* __restrict__ D,
                                                int* __restrict__ idxo, int b0) {
    __shared__ float swv[4];
    __shared__ int   swi[4];
    int tid = threadIdx.x;
    int lane = tid & 63, wvid = tid >> 6;
    int q = blockIdx.x;                 // chunk-local query
    int bl = q / NN, n = q % NN;
    const float* row = D + (size_t)q * NN;
    float d[8];
    *(float4*)&d[0] = *(const float4*)(row + 4 * tid);
    *(float4*)&d[4] = *(const float4*)(row + 1024 + 4 * tid);
    int* op = idxo + ((size_t)(b0 + bl) * NN + n) * KNN;
    for (int k = 0; k < KNN; ++k) {
        // local top-1 over 8 regs (slots scan in ascending global col; strict >
        // keeps the smallest col on ties)
        float bv = d[0]; int bs = 0;
        #pragma unroll
        for (int j = 1; j < 8; ++j) if (d[j] > bv) { bv = d[j]; bs = j; }
        int bg = bs < 4 ? 4 * tid + bs : 1024 + 4 * tid + (bs - 4);
        // wave butterfly (value desc, col asc)
        #pragma unroll
        for (int s = 1; s < 64; s <<= 1) {
            float ov = __shfl_xor(bv, s);
            int og = __shfl_xor(bg, s);
            if (ov > bv || (ov == bv && og < bg)) { bv = ov; bg = og; }
        }
        if (lane == 0) { swv[wvid] = bv; swi[wvid] = bg; }
        __syncthreads();
        float wv0 = swv[0]; int wg0 = swi[0];
        #pragma unroll
        for (int t = 1; t < 4; ++t) {
            float v = swv[t]; int g = swi[t];
            if (v > wv0 || (v == wv0 && g < wg0)) { wv0 = v; wg0 = g; }
        }
        if (tid == 0) op[k] = wg0;
        // owner clears its register slot
        if (tid == ((wg0 & 1023) >> 2)) {
            int slot = (wg0 >> 10) * 4 + (wg0 & 3);
            #pragma unroll
            for (int j = 0; j < 8; ++j) if (j == slot) d[j] = -FLT_MAX;
        }
        __syncthreads();   // protect swv/swi for next round
    }
}

// ---------- pair GEMM: Y = F*wtA (union buffer), C2 = F*wtD -> xcat slot ----------
template<int CIN, int COUT>
__global__ __launch_bounds__(256) void k_gemm_pair(const float* __restrict__ F, int FS, int b0,
    const float* __restrict__ wtA, const float* __restrict__ wtD,
    float* __restrict__ Y, float* __restrict__ c2x) {
    constexpr int CCH = (CIN >= 32) ? 32 : CIN;
    constexpr int NCH = CIN / CCH;
    __shared__ __align__(16) float Xi[CCH * 64];
    __shared__ __align__(16) float Wa[CCH * 64];
    __shared__ __align__(16) float Wd[CCH * 64];
    int tid = threadIdx.x;
    int r0 = blockIdx.x * 64;
    int c0 = blockIdx.y * 64;
    int b = b0 + r0 / NN;
    int n0 = r0 % NN;
    const float* Fb = F + ((size_t)b * NN + n0) * FS;
    int ty = tid >> 4, tx = tid & 15;
    float accY[4][4] = {}, accD[4][4] = {};
    for (int ch = 0; ch < NCH; ++ch) {
        int cb = ch * CCH;
        if (ch) __syncthreads();
        if constexpr (CCH % 4 == 0) {
            for (int t = tid; t < 64 * (CCH / 4); t += 256) {
                int r = t & 63, cc = t >> 6;
                float v[4];
                *(float4*)v = *(const float4*)(Fb + (size_t)r * FS + cb + 4 * cc);
                #pragma unroll
                for (int u = 0; u < 4; ++u) Xi[(4 * cc + u) * 64 + r] = v[u];
            }
            for (int t = tid; t < CCH * 16; t += 256) {
                int c = t >> 4, q = t & 15;
                *(float4*)&Wa[c * 64 + 4 * q] = *(const float4*)(wtA + (size_t)(cb + c) * COUT + c0 + 4 * q);
                *(float4*)&Wd[c * 64 + 4 * q] = *(const float4*)(wtD + (size_t)(cb + c) * COUT + c0 + 4 * q);
            }
        } else {
            for (int t = tid; t < 64 * CCH; t += 256) {
                int r = t & 63, c = t >> 6;
                Xi[c * 64 + r] = Fb[(size_t)r * FS + cb + c];
            }
            for (int t = tid; t < CCH * 64; t += 256) {
                int col = t & 63, c = t >> 6;
                Wa[c * 64 + col] = wtA[(size_t)(cb + c) * COUT + c0 + col];
                Wd[c * 64 + col] = wtD[(size_t)(cb + c) * COUT + c0 + col];
            }
        }
        __syncthreads();
        for (int c = 0; c < CCH; ++c) {
            float a[4], wa[4], wd[4];
            *(float4*)a  = *(const float4*)&Xi[c * 64 + 4 * ty];
            *(float4*)wa = *(const float4*)&Wa[c * 64 + 4 * tx];
            *(float4*)wd = *(const float4*)&Wd[c * 64 + 4 * tx];
            #pragma unroll
            for (int r = 0; r < 4; ++r)
                #pragma unroll
                for (int s = 0; s < 4; ++s) {
                    accY[r][s] += a[r] * wa[s];
                    accD[r][s] += a[r] * wd[s];
                }
        }
    }
    #pragma unroll
    for (int r = 0; r < 4; ++r) {
        *(float4*)(Y + (size_t)(r0 + 4 * ty + r) * COUT + c0 + 4 * tx) = *(float4*)accY[r];
        *(float4*)(c2x + ((size_t)b0 * NN + r0 + 4 * ty + r) * 512 + c0 + 4 * tx) = *(float4*)accD[r];
    }
}

// ---------- gather-max: io slot holds C2 on entry, final features on exit ----------
template<int COUT>
__global__ __launch_bounds__(256) void k_gather(const float* __restrict__ Y,
    const int* __restrict__ idx, const float* __restrict__ sc, const float* __restrict__ bi,
    float* io, int b0) {
    constexpr int LPP = COUT / 4;
    constexpr int PPW = 64 / LPP;
    constexpr int PPB = 4 * PPW;
    int tid = threadIdx.x;
    int lane = tid & 63, wv = tid >> 6;
    int pl = blockIdx.x * PPB + wv * PPW + lane / LPP;
    int bl = pl / NN, n = pl % NN;
    int o0 = 4 * (lane % LPP);
    float* iop = io + ((size_t)(b0 + bl) * NN + n) * 512 + o0;
    float c2[4], s4[4], b4[4];
    *(float4*)c2 = *(const float4*)iop;
    *(float4*)s4 = *(const float4*)(sc + o0);
    *(float4*)b4 = *(const float4*)(bi + o0);
    const int* ip = idx + ((size_t)(b0 + bl) * NN + n) * KNN;
    const float* Yb = Y + (size_t)bl * NN * COUT;
    float mx[4] = {-FLT_MAX, -FLT_MAX, -FLT_MAX, -FLT_MAX};
    for (int k = 0; k < KNN; ++k) {
        int m = ip[k];
        float y[4];
        *(float4*)y = *(const float4*)(Yb + (size_t)m * COUT + o0);
        #pragma unroll
        for (int u = 0; u < 4; ++u) {
            float v = (y[u] + c2[u]) * s4[u] + b4[u];
            mx[u] = fmaxf(mx[u], leaky(v));
        }
    }
    *(float4*)iop = *(float4*)mx;
}

// ---------- conv5: 128x128 tile, 8x8 micro-tile, fused partial pooling.
// Wj staged via global_load_lds (linear c-major layout, wave-uniform base + lane*16). ----------
__global__ __launch_bounds__(256) void k_conv5(const float* __restrict__ xcat,
    const float* __restrict__ w5t, const float* __restrict__ s5, const float* __restrict__ b5,
    float* __restrict__ pmax, float* __restrict__ psum) {
    __shared__ __align__(16) float Xi[32 * 128];
    __shared__ __align__(16) float Wj[32 * 128];
    int tid = threadIdx.x;
    int ty = tid >> 4, tx = tid & 15;
    int wv6 = tid >> 6, lane6 = tid & 63;
    int r0 = blockIdx.x * 128;
    int col0 = blockIdx.y * 128;
    int b = r0 / NN, tileInB = (r0 % NN) / 128;
    const float* Fb = xcat + (size_t)r0 * 512;
    float acc[8][8] = {};
    for (int ch = 0; ch < 16; ++ch) {
        int cb = ch * 32;
        if (ch) __syncthreads();
        for (int t = tid; t < 128 * 8; t += 256) {
            int r = t & 127, cc = t >> 7;
            float v[4];
            *(float4*)v = *(const float4*)(Fb + (size_t)r * 512 + cb + 4 * cc);
            #pragma unroll
            for (int u = 0; u < 4; ++u) Xi[(4 * cc + u) * 128 + r] = v[u];
        }
        #pragma unroll
        for (int i = 0; i < 4; ++i) {
            int basec = wv6 * 8 + i * 2;
            const float* gp = w5t + (size_t)(cb + basec + (lane6 >> 5)) * 1024 + col0 + (lane6 & 31) * 4;
            __builtin_amdgcn_global_load_lds((const __attribute__((address_space(1))) void*)gp,
                (__attribute__((address_space(3))) void*)&Wj[basec * 128], 16, 0, 0);
        }
        __syncthreads();
        for (int c = 0; c < 32; ++c) {
            float a0[4], a1[4], w0[4], w1[4];
            *(float4*)a0 = *(const float4*)&Xi[c * 128 + 4 * ty];
            *(float4*)a1 = *(const float4*)&Xi[c * 128 + 64 + 4 * ty];
            *(float4*)w0 = *(const float4*)&Wj[c * 128 + 4 * tx];
            *(float4*)w1 = *(const float4*)&Wj[c * 128 + 64 + 4 * tx];
            #pragma unroll
            for (int r = 0; r < 4; ++r)
                #pragma unroll
                for (int u = 0; u < 4; ++u) {
                    acc[r][u]         += a0[r] * w0[u];
                    acc[r][4 + u]     += a0[r] * w1[u];
                    acc[4 + r][u]     += a1[r] * w0[u];
                    acc[4 + r][4 + u] += a1[r] * w1[u];
                }
        }
    }
    float hmx[2][4], hsm[2][4];
    #pragma unroll
    for (int h = 0; h < 2; ++h)
        #pragma unroll
        for (int u = 0; u < 4; ++u) { hmx[h][u] = -FLT_MAX; hsm[h][u] = 0.f; }
    #pragma unroll
    for (int h = 0; h < 2; ++h)
        #pragma unroll
        for (int u = 0; u < 4; ++u) {
            int o = col0 + 64 * h + 4 * tx + u;
            float sv = s5[o], bv = b5[o];
            #pragma unroll
            for (int r = 0; r < 8; ++r) {
                float hh = leaky(acc[r][4 * h + u] * sv + bv);
                hmx[h][u] = fmaxf(hmx[h][u], hh);
                hsm[h][u] += hh;
            }
        }
    __syncthreads();
    float* redM = Xi;
    float* redS = Wj;
    #pragma unroll
    for (int h = 0; h < 2; ++h) {
        *(float4*)&redM[ty * 128 + 64 * h + 4 * tx] = *(float4*)hmx[h];
        *(float4*)&redS[ty * 128 + 64 * h + 4 * tx] = *(float4*)hsm[h];
    }
    __syncthreads();
    for (int s = 8; s > 0; s >>= 1) {
        if (ty < s) {
            #pragma unroll
            for (int h = 0; h < 2; ++h) {
                int c = 64 * h + 4 * tx;
                float m0[4], m1[4], s0[4], s1[4];
                *(float4*)m0 = *(float4*)&redM[ty * 128 + c];
                *(float4*)m1 = *(float4*)&redM[(ty + s) * 128 + c];
                *(float4*)s0 = *(float4*)&redS[ty * 128 + c];
                *(float4*)s1 = *(float4*)&redS[(ty + s) * 128 + c];
                #pragma unroll
                for (int u = 0; u < 4; ++u) { m0[u] = fmaxf(m0[u], m1[u]); s0[u] += s1[u]; }
                *(float4*)&redM[ty * 128 + c] = *(float4*)m0;
                *(float4*)&redS[ty * 128 + c] = *(float4*)s0;
            }
        }
        __syncthreads();
    }
    if (ty == 0) {
        #pragma unroll
        for (int h = 0; h < 2; ++h) {
            int c = 64 * h + 4 * tx;
            size_t o = ((size_t)b * 16 + tileInB) * 1024 + col0 + c;
            *(float4*)&pmax[o] = *(float4*)&redM[c];
            *(float4*)&psum[o] = *(float4*)&redS[c];
        }
    }
}

__global__ void k_poolreduce(const float* __restrict__ pmax, const float* __restrict__ psum,
                             float* __restrict__ pooled) {
    int i = blockIdx.x * 256 + threadIdx.x;
    if (i >= BB * 1024) return;
    int b = i / 1024, o = i % 1024;
    float mx = -FLT_MAX, sm = 0.f;
    for (int ch = 0; ch < 16; ++ch) {
        mx = fmaxf(mx, pmax[((size_t)b * 16 + ch) * 1024 + o]);
        sm += psum[((size_t)b * 16 + ch) * 1024 + o];
    }
    pooled[(size_t)b * 2048 + o] = mx;
    pooled[(size_t)b * 2048 + 1024 + o] = sm / (float)NN;
}

// ---------- FC: wave-per-output, coalesced float4 weight reads, shfl reduce ----------
template<int CI, bool SCALE, bool RELU>
__global__ __launch_bounds__(256) void k_fcw(const float* __restrict__ in,
                                             const float* __restrict__ w,
                                             const float* __restrict__ sc,
                                             const float* __restrict__ bi,
                                             float* __restrict__ out, int CO) {
    int wv = (blockIdx.x << 2) + (threadIdx.x >> 6);
    int lane = threadIdx.x & 63;
    int o = wv % CO, b = wv / CO;
    const float* ir = in + (size_t)b * CI;
    const float* wr = w + (size_t)o * CI;
    float acc = 0.f;
    #pragma unroll
    for (int q = 0; q < CI / 256; ++q) {
        int ofs = q * 256 + 4 * lane;
        float4 wv4 = *(const float4*)(wr + ofs);
        float4 iv4 = *(const float4*)(ir + ofs);
        acc += wv4.x * iv4.x + wv4.y * iv4.y + wv4.z * iv4.z + wv4.w * iv4.w;
    }
    #pragma unroll
    for (int s = 1; s < 64; s <<= 1) acc += __shfl_xor(acc, s);
    if (lane == 0) {
        float v = SCALE ? (acc * sc[o] + bi[o]) : (acc + bi[o]);
        if (RELU) v = fmaxf(v, 0.f);
        out[wv] = v;
    }
}

extern "C" void kernel_launch(void* const* d_in, const int* in_sizes, int n_in,
                              void* d_out, int out_size, void* d_ws, size_t ws_size,
                              hipStream_t stream) {
    const float* x    = (const float*)d_in[0];
    const float* w1   = (const float*)d_in[1];
    const float* s1   = (const float*)d_in[2];
    const float* b1   = (const float*)d_in[3];
    const float* w2   = (const float*)d_in[4];
    const float* s2   = (const float*)d_in[5];
    const float* b2   = (const float*)d_in[6];
    const float* w3   = (const float*)d_in[7];
    const float* s3   = (const float*)d_in[8];
    const float* b3   = (const float*)d_in[9];
    const float* w4   = (const float*)d_in[10];
    const float* s4   = (const float*)d_in[11];
    const float* b4   = (const float*)d_in[12];
    const float* w5   = (const float*)d_in[13];
    const float* s5   = (const float*)d_in[14];
    const float* b5   = (const float*)d_in[15];
    const float* fc1w = (const float*)d_in[16];
    const float* s6   = (const float*)d_in[17];
    const float* b6   = (const float*)d_in[18];
    const float* fc2w = (const float*)d_in[19];
    const float* s7   = (const float*)d_in[20];
    const float* b7   = (const float*)d_in[21];
    const float* fc3w = (const float*)d_in[22];
    const float* fc3b = (const float*)d_in[23];
    float* out = (float*)d_out;

    char* ws = (char*)d_ws;
    size_t off = 0;
    auto alloc = [&](size_t bytes) {
        void* p = ws + off;
        off = (off + bytes + 255) & ~(size_t)255;
        return p;
    };
    float* xt   = (float*)alloc((size_t)BB * NN * 3 * 4);
    float* xcat = (float*)alloc((size_t)BB * NN * 512 * 4);
    int*   idx  = (int*)  alloc((size_t)BB * NN * KNN * 4);
    float* xx   = (float*)alloc((size_t)BB * NN * 4);
    float* wtA1 = (float*)alloc(3 * 64 * 4);
    float* wtD1 = (float*)alloc(3 * 64 * 4);
    float* wtA2 = (float*)alloc(64 * 64 * 4);
    float* wtD2 = (float*)alloc(64 * 64 * 4);
    float* wtA3 = (float*)alloc(64 * 128 * 4);
    float* wtD3 = (float*)alloc(64 * 128 * 4);
    float* wtA4 = (float*)alloc(128 * 256 * 4);
    float* wtD4 = (float*)alloc(128 * 256 * 4);
    size_t base_end = off;

    // UNION region: D (dist phase, per-batch chunks) / Y (transform) / head buffers
    const size_t D1 = (size_t)NN * NN * 4;
    size_t avail = ws_size > base_end ? ws_size - base_end : 0;
    int nbD = (int)(avail / D1);
    if (nbD < 1) nbD = 1;
    if (nbD > BB) nbD = BB;
    char* uni = ws + base_end;
    float* D      = (float*)uni;
    float* w5t    = (float*)uni;
    float* pmax   = w5t + 512 * 1024;
    float* psum   = pmax + (size_t)BB * 16 * 1024;
    float* pooled = psum + (size_t)BB * 16 * 1024;
    float* f1     = pooled + (size_t)BB * 2048;
    float* f2     = f1 + (size_t)BB * 512;

    k_transpose_x<<<(BB * NN * 3 + 255) / 256, 256, 0, stream>>>(x, xt);
    k_wpair_all<<<(45248 + 255) / 256, 256, 0, stream>>>(w1, w2, w3, w4,
        wtA1, wtD1, wtA2, wtD2, wtA3, wtD3, wtA4, wtD4);

    auto layer = [&](auto cTag, auto coTag, const float* F, int FS,
                     const float* wtA, const float* wtD,
                     const float* sc, const float* bi, float* outp) {
        constexpr int C  = decltype(cTag)::value;
        constexpr int CO = decltype(coTag)::value;
        k_xx<C><<<(BB * NN + 255) / 256, 256, 0, stream>>>(F, FS, xx);
        for (int b0 = 0; b0 < BB; b0 += nbD) {
            int nb = BB - b0 < nbD ? BB - b0 : nbD;
            if constexpr (C >= 32) {
                k_dist128<C><<<nb * 256, 256, 0, stream>>>(F, FS, xx, b0, D);
            } else {
                k_dist<C><<<nb * 1024, 256, 0, stream>>>(F, FS, xx, b0, D);
            }
            k_select<<<nb * NN, 256, 0, stream>>>(D, idx, b0);
        }
        // transform + gather: Y-only union buffer (C2 goes straight into xcat)
        size_t ypb = (size_t)NN * CO * 4;
        int nbY = (int)(avail / ypb);
        if (nbY < 1) nbY = 1;
        if (nbY > BB) nbY = BB;
        for (int b0 = 0; b0 < BB; b0 += nbY) {
            int nb = BB - b0 < nbY ? BB - b0 : nbY;
            float* Yc = (float*)uni;
            dim3 g((nb * NN) / 64, CO / 64);
            k_gemm_pair<C, CO><<<g, 256, 0, stream>>>(F, FS, b0, wtA, wtD, Yc, outp);
            constexpr int PPB = 4 * (64 / (CO / 4));
            k_gather<CO><<<(nb * NN) / PPB, 256, 0, stream>>>(Yc, idx, sc, bi, outp, b0);
        }
    };

    layer(std::integral_constant<int, 3>{},   std::integral_constant<int, 64>{},  xt,         3,   wtA1, wtD1, s1, b1, xcat + 0);
    layer(std::integral_constant<int, 64>{},  std::integral_constant<int, 64>{},  xcat + 0,   512, wtA2, wtD2, s2, b2, xcat + 64);
    layer(std::integral_constant<int, 64>{},  std::integral_constant<int, 128>{}, xcat + 64,  512, wtA3, wtD3, s3, b3, xcat + 128);
    layer(std::integral_constant<int, 128>{}, std::integral_constant<int, 256>{}, xcat + 128, 512, wtA4, wtD4, s4, b4, xcat + 256);

    // head (union region now holds w5t/pmax/psum/pooled/f1/f2)
    dim3 gt(1024 / 64, 512 / 64);
    k_transpose_w_tiled<<<gt, 256, 0, stream>>>(w5, w5t, 1024, 512);
    dim3 g5((BB * NN) / 128, 1024 / 128);
    k_conv5<<<g5, 256, 0, stream>>>(xcat, w5t, s5, b5, pmax, psum);
    k_poolreduce<<<(BB * 1024 + 255) / 256, 256, 0, stream>>>(pmax, psum, pooled);
    k_fcw<2048, true,  true ><<<(BB * 512) / 4, 256, 0, stream>>>(pooled, fc1w, s6, b6, f1, 512);
    k_fcw<512,  true,  true ><<<(BB * 256) / 4, 256, 0, stream>>>(f1, fc2w, s7, b7, f2, 256);
    k_fcw<256,  false, false><<<(BB * 40)  / 4, 256, 0, stream>>>(f2, fc3w, nullptr, fc3b, out, 40);
}

// Round 11
// 1001.757 us; speedup vs baseline: 1.5825x; 1.5825x over previous
//
#include <hip/hip_runtime.h>
#include <float.h>
#include <type_traits>

#define BB 8
#define NN 2048
#define KNN 20

__device__ __forceinline__ float leaky(float v) { return fmaxf(v, 0.2f * v); }

// ---------- transpose x (B,3,N) -> xt (B,N,3) ----------
__global__ void k_transpose_x(const float* __restrict__ x, float* __restrict__ xt) {
    int i = blockIdx.x * 256 + threadIdx.x;
    if (i >= BB * NN * 3) return;
    int c = i % 3; int n = (i / 3) % NN; int b = i / (3 * NN);
    xt[i] = x[((size_t)b * 3 + c) * NN + n];
}

// ---------- LDS-tiled transpose w (CO,CI) -> wt (CI,CO), 64x64 tiles ----------
__global__ __launch_bounds__(256) void k_transpose_w_tiled(const float* __restrict__ w,
                                                           float* __restrict__ wt,
                                                           int CO, int CI) {
    __shared__ float tile[64][65];
    int o0 = blockIdx.x * 64;
    int c0 = blockIdx.y * 64;
    int tid = threadIdx.x;
    for (int i = tid; i < 64 * 64; i += 256) {
        int r = i >> 6, c = i & 63;
        tile[r][c] = w[(size_t)(o0 + r) * CI + c0 + c];
    }
    __syncthreads();
    for (int i = tid; i < 64 * 64; i += 256) {
        int cc = i >> 6, oo = i & 63;
        wt[(size_t)(c0 + cc) * CO + o0 + oo] = tile[oo][cc];
    }
}

// ---------- all 4 edgeconv weight splits in ONE dispatch ----------
__device__ __forceinline__ void wpair_one(const float* __restrict__ w, float* __restrict__ wtA,
                                          float* __restrict__ wtD, int CO, int CI, int i) {
    int o = i / CI, c = i % CI;
    float a = w[(size_t)o * 2 * CI + c];
    float bb = w[(size_t)o * 2 * CI + CI + c];
    wtA[c * CO + o] = a;
    wtD[c * CO + o] = bb - a;
}
__global__ void k_wpair_all(const float* w1, const float* w2, const float* w3, const float* w4,
                            float* A1, float* D1, float* A2, float* D2,
                            float* A3, float* D3, float* A4, float* D4) {
    int i = blockIdx.x * 256 + threadIdx.x;
    if (i < 192)            { wpair_one(w1, A1, D1, 64, 3, i); }
    else if (i < 4288)      { wpair_one(w2, A2, D2, 64, 64, i - 192); }
    else if (i < 12480)     { wpair_one(w3, A3, D3, 128, 64, i - 4288); }
    else if (i < 45248)     { wpair_one(w4, A4, D4, 256, 128, i - 12480); }
}

// ---------- squared norms per point ----------
template<int C>
__global__ void k_xx(const float* __restrict__ F, int FS, float* __restrict__ xx) {
    int i = blockIdx.x * 256 + threadIdx.x;
    if (i >= BB * NN) return;
    const float* r = F + (size_t)i * FS;
    float s = 0.f;
    #pragma unroll
    for (int c = 0; c < C; ++c) { float v = r[c]; s += v * v; }
    xx[i] = s;
}

// ---------- distance matrix, small-C (C=3): 64x64 tile, full grid ----------
template<int C>
__global__ __launch_bounds__(256) void k_dist(const float* __restrict__ F, int FS,
                                              const float* __restrict__ xx, int b0,
                                              float* __restrict__ D) {
    __shared__ __align__(16) float Xi[C * 64];
    __shared__ __align__(16) float Xj[C * 64];
    int tid = threadIdx.x;
    int bl = blockIdx.x >> 10;
    int t  = blockIdx.x & 1023;
    int i0 = (t >> 5) * 64, j0 = (t & 31) * 64;
    int b = b0 + bl;
    const float* Fb = F + (size_t)b * NN * FS;
    int ty = tid >> 4, tx = tid & 15;
    float acc[4][4] = {};
    for (int k = tid; k < 64 * C; k += 256) {
        int r = k & 63, c = k >> 6;
        Xi[c * 64 + r] = Fb[(size_t)(i0 + r) * FS + c];
        Xj[c * 64 + r] = Fb[(size_t)(j0 + r) * FS + c];
    }
    __syncthreads();
    for (int c = 0; c < C; ++c) {
        float a[4], bv[4];
        *(float4*)a  = *(const float4*)&Xi[c * 64 + 4 * ty];
        *(float4*)bv = *(const float4*)&Xj[c * 64 + 4 * tx];
        #pragma unroll
        for (int r = 0; r < 4; ++r)
            #pragma unroll
            for (int s = 0; s < 4; ++s) acc[r][s] += a[r] * bv[s];
    }
    const float* xxb = xx + (size_t)b * NN;
    float xxi[4], xxj[4];
    #pragma unroll
    for (int r = 0; r < 4; ++r) xxi[r] = xxb[i0 + 4 * ty + r];
    #pragma unroll
    for (int s = 0; s < 4; ++s) xxj[s] = xxb[j0 + 4 * tx + s];
    float* Dp = D + (size_t)bl * NN * NN;
    #pragma unroll
    for (int r = 0; r < 4; ++r) {
        float ov[4];
        #pragma unroll
        for (int s = 0; s < 4; ++s) ov[s] = 2.f * acc[r][s] - xxi[r] - xxj[s];
        *(float4*)(Dp + (size_t)(i0 + 4 * ty + r) * NN + j0 + 4 * tx) = *(float4*)ov;
    }
}

// ---------- distance matrix, big-C: SYMMETRIC 128x128 tiles (136 of 256).
// Computes upper-triangle tiles only; off-diagonal tiles also write the
// mirrored block straight from registers (acc[0..3][s] is a contiguous
// ii-quad -> float4 stores at D[j0+jj][i0+4ty]). ----------
template<int C>
__global__ __launch_bounds__(256) void k_dist128s(const float* __restrict__ F, int FS,
                                                  const float* __restrict__ xx, int b0,
                                                  float* __restrict__ D) {
    constexpr int NCH = C / 32;
    __shared__ __align__(16) float Xi[32 * 128];
    __shared__ __align__(16) float Xj[32 * 128];
    int tid = threadIdx.x;
    int ty = tid >> 4, tx = tid & 15;
    int bl = blockIdx.x / 136;
    int t  = blockIdx.x % 136;
    int it = 0, rem = t;
    while (rem >= 16 - it) { rem -= 16 - it; ++it; }
    int jt = it + rem;
    int i0 = it * 128, j0 = jt * 128;
    int b = b0 + bl;
    const float* Fb = F + (size_t)b * NN * FS;
    float acc[8][8] = {};
    for (int ch = 0; ch < NCH; ++ch) {
        int cb = ch * 32;
        if (ch) __syncthreads();
        for (int k = tid; k < 128 * 8; k += 256) {
            int r = k & 127, cc = k >> 7;
            float vi[4], vj[4];
            *(float4*)vi = *(const float4*)(Fb + (size_t)(i0 + r) * FS + cb + 4 * cc);
            *(float4*)vj = *(const float4*)(Fb + (size_t)(j0 + r) * FS + cb + 4 * cc);
            #pragma unroll
            for (int u = 0; u < 4; ++u) {
                Xi[(4 * cc + u) * 128 + r] = vi[u];
                Xj[(4 * cc + u) * 128 + r] = vj[u];
            }
        }
        __syncthreads();
        for (int c = 0; c < 32; ++c) {
            float a0[4], a1[4], w0[4], w1[4];
            *(float4*)a0 = *(const float4*)&Xi[c * 128 + 4 * ty];
            *(float4*)a1 = *(const float4*)&Xi[c * 128 + 64 + 4 * ty];
            *(float4*)w0 = *(const float4*)&Xj[c * 128 + 4 * tx];
            *(float4*)w1 = *(const float4*)&Xj[c * 128 + 64 + 4 * tx];
            #pragma unroll
            for (int r = 0; r < 4; ++r)
                #pragma unroll
                for (int s = 0; s < 4; ++s) {
                    acc[r][s]         += a0[r] * w0[s];
                    acc[r][4 + s]     += a0[r] * w1[s];
                    acc[4 + r][s]     += a1[r] * w0[s];
                    acc[4 + r][4 + s] += a1[r] * w1[s];
                }
        }
    }
    const float* xxb = xx + (size_t)b * NN;
    float xxi[8], xxj[8];
    #pragma unroll
    for (int r = 0; r < 4; ++r) {
        xxi[r]     = xxb[i0 + 4 * ty + r];
        xxi[4 + r] = xxb[i0 + 64 + 4 * ty + r];
        xxj[r]     = xxb[j0 + 4 * tx + r];
        xxj[4 + r] = xxb[j0 + 64 + 4 * tx + r];
    }
    float* Dp = D + (size_t)bl * NN * NN;
    // straight block
    #pragma unroll
    for (int r = 0; r < 8; ++r) {
        int row = i0 + (r < 4 ? 4 * ty + r : 64 + 4 * ty + (r - 4));
        float ov0[4], ov1[4];
        #pragma unroll
        for (int s = 0; s < 4; ++s) {
            ov0[s] = 2.f * acc[r][s]     - xxi[r] - xxj[s];
            ov1[s] = 2.f * acc[r][4 + s] - xxi[r] - xxj[4 + s];
        }
        *(float4*)(Dp + (size_t)row * NN + j0 + 4 * tx)      = *(float4*)ov0;
        *(float4*)(Dp + (size_t)row * NN + j0 + 64 + 4 * tx) = *(float4*)ov1;
    }
    // mirrored block (off-diagonal tiles only)
    if (it != jt) {
        #pragma unroll
        for (int sh = 0; sh < 2; ++sh)
            #pragma unroll
            for (int s = 0; s < 4; ++s) {
                int jrow = j0 + 64 * sh + 4 * tx + s;
                #pragma unroll
                for (int rh = 0; rh < 2; ++rh) {
                    float tv[4];
                    #pragma unroll
                    for (int r = 0; r < 4; ++r)
                        tv[r] = 2.f * acc[4 * rh + r][4 * sh + s] - xxi[4 * rh + r] - xxj[4 * sh + s];
                    *(float4*)(Dp + (size_t)jrow * NN + i0 + 64 * rh + 4 * ty) = *(float4*)tv;
                }
            }
    }
}

// ---------- top-20 selection: one wave per query, row in registers (R8 proven) ----------
__global__ __launch_bounds__(256) void k_select(const float* __restrict__ D,
                                                int* __restrict__ idxo, int b0) {
    int tid = threadIdx.x;
    int lane = tid & 63;
    int w = (blockIdx.x << 2) + (tid >> 6);
    int bl = w / NN, n = w % NN;
    const float* row = D + (size_t)w * NN;
    float d[32];
    #pragma unroll
    for (int q = 0; q < 8; ++q)
        *(float4*)&d[4 * q] = *(const float4*)(row + 4 * lane + 256 * q);
    float bv = d[0]; int bj = 0;
    #pragma unroll
    for (int j = 1; j < 32; ++j) if (d[j] > bv) { bv = d[j]; bj = j; }
    int* op = idxo + ((size_t)(b0 + bl) * NN + n) * KNN;
    for (int k = 0; k < KNN; ++k) {
        float rv = bv;
        int rm = 4 * lane + 256 * (bj >> 2) + (bj & 3);
        #pragma unroll
        for (int s = 1; s < 64; s <<= 1) {
            float ov = __shfl_xor(rv, s);
            int om = __shfl_xor(rm, s);
            if (ov > rv || (ov == rv && om < rm)) { rv = ov; rm = om; }
        }
        if (lane == 0) op[k] = rm;
        if (((rm >> 2) & 63) == lane) {
            int oj = ((rm >> 8) << 2) | (rm & 3);
            #pragma unroll
            for (int j = 0; j < 32; ++j) if (j == oj) d[j] = -FLT_MAX;
            bv = d[0]; bj = 0;
            #pragma unroll
            for (int j = 1; j < 32; ++j) if (d[j] > bv) { bv = d[j]; bj = j; }
        }
    }
}

// ---------- pair GEMM: Y = F*wtA (union buffer), C2 = F*wtD -> xcat slot ----------
template<int CIN, int COUT>
__global__ __launch_bounds__(256) void k_gemm_pair(const float* __restrict__ F, int FS, int b0,
    const float* __restrict__ wtA, const float* __restrict__ wtD,
    float* __restrict__ Y, float* __restrict__ c2x) {
    constexpr int CCH = (CIN >= 32) ? 32 : CIN;
    constexpr int NCH = CIN / CCH;
    __shared__ __align__(16) float Xi[CCH * 64];
    __shared__ __align__(16) float Wa[CCH * 64];
    __shared__ __align__(16) float Wd[CCH * 64];
    int tid = threadIdx.x;
    int r0 = blockIdx.x * 64;
    int c0 = blockIdx.y * 64;
    int b = b0 + r0 / NN;
    int n0 = r0 % NN;
    const float* Fb = F + ((size_t)b * NN + n0) * FS;
    int ty = tid >> 4, tx = tid & 15;
    float accY[4][4] = {}, accD[4][4] = {};
    for (int ch = 0; ch < NCH; ++ch) {
        int cb = ch * CCH;
        if (ch) __syncthreads();
        if constexpr (CCH % 4 == 0) {
            for (int t = tid; t < 64 * (CCH / 4); t += 256) {
                int r = t & 63, cc = t >> 6;
                float v[4];
                *(float4*)v = *(const float4*)(Fb + (size_t)r * FS + cb + 4 * cc);
                #pragma unroll
                for (int u = 0; u < 4; ++u) Xi[(4 * cc + u) * 64 + r] = v[u];
            }
            for (int t = tid; t < CCH * 16; t += 256) {
                int c = t >> 4, q = t & 15;
                *(float4*)&Wa[c * 64 + 4 * q] = *(const float4*)(wtA + (size_t)(cb + c) * COUT + c0 + 4 * q);
                *(float4*)&Wd[c * 64 + 4 * q] = *(const float4*)(wtD + (size_t)(cb + c) * COUT + c0 + 4 * q);
            }
        } else {
            for (int t = tid; t < 64 * CCH; t += 256) {
                int r = t & 63, c = t >> 6;
                Xi[c * 64 + r] = Fb[(size_t)r * FS + cb + c];
            }
            for (int t = tid; t < CCH * 64; t += 256) {
                int col = t & 63, c = t >> 6;
                Wa[c * 64 + col] = wtA[(size_t)(cb + c) * COUT + c0 + col];
                Wd[c * 64 + col] = wtD[(size_t)(cb + c) * COUT + c0 + col];
            }
        }
        __syncthreads();
        for (int c = 0; c < CCH; ++c) {
            float a[4], wa[4], wd[4];
            *(float4*)a  = *(const float4*)&Xi[c * 64 + 4 * ty];
            *(float4*)wa = *(const float4*)&Wa[c * 64 + 4 * tx];
            *(float4*)wd = *(const float4*)&Wd[c * 64 + 4 * tx];
            #pragma unroll
            for (int r = 0; r < 4; ++r)
                #pragma unroll
                for (int s = 0; s < 4; ++s) {
                    accY[r][s] += a[r] * wa[s];
                    accD[r][s] += a[r] * wd[s];
                }
        }
    }
    #pragma unroll
    for (int r = 0; r < 4; ++r) {
        *(float4*)(Y + (size_t)(r0 + 4 * ty + r) * COUT + c0 + 4 * tx) = *(float4*)accY[r];
        *(float4*)(c2x + ((size_t)b0 * NN + r0 + 4 * ty + r) * 512 + c0 + 4 * tx) = *(float4*)accD[r];
    }
}

// ---------- gather-max: io slot holds C2 on entry, final features on exit ----------
template<int COUT>
__global__ __launch_bounds__(256) void k_gather(const float* __restrict__ Y,
    const int* __restrict__ idx, const float* __restrict__ sc, const float* __restrict__ bi,
    float* io, int b0) {
    constexpr int LPP = COUT / 4;
    constexpr int PPW = 64 / LPP;
    constexpr int PPB = 4 * PPW;
    int tid = threadIdx.x;
    int lane = tid & 63, wv = tid >> 6;
    int pl = blockIdx.x * PPB + wv * PPW + lane / LPP;
    int bl = pl / NN, n = pl % NN;
    int o0 = 4 * (lane % LPP);
    float* iop = io + ((size_t)(b0 + bl) * NN + n) * 512 + o0;
    float c2[4], s4[4], b4[4];
    *(float4*)c2 = *(const float4*)iop;
    *(float4*)s4 = *(const float4*)(sc + o0);
    *(float4*)b4 = *(const float4*)(bi + o0);
    const int* ip = idx + ((size_t)(b0 + bl) * NN + n) * KNN;
    const float* Yb = Y + (size_t)bl * NN * COUT;
    float mx[4] = {-FLT_MAX, -FLT_MAX, -FLT_MAX, -FLT_MAX};
    for (int k = 0; k < KNN; ++k) {
        int m = ip[k];
        float y[4];
        *(float4*)y = *(const float4*)(Yb + (size_t)m * COUT + o0);
        #pragma unroll
        for (int u = 0; u < 4; ++u) {
            float v = (y[u] + c2[u]) * s4[u] + b4[u];
            mx[u] = fmaxf(mx[u], leaky(v));
        }
    }
    *(float4*)iop = *(float4*)mx;
}

// ---------- conv5: 128x128 tile, 8x8 micro-tile, fused partial pooling ----------
__global__ __launch_bounds__(256) void k_conv5(const float* __restrict__ xcat,
    const float* __restrict__ w5t, const float* __restrict__ s5, const float* __restrict__ b5,
    float* __restrict__ pmax, float* __restrict__ psum) {
    __shared__ __align__(16) float Xi[32 * 128];
    __shared__ __align__(16) float Wj[32 * 128];
    int tid = threadIdx.x;
    int ty = tid >> 4, tx = tid & 15;
    int wv6 = tid >> 6, lane6 = tid & 63;
    int r0 = blockIdx.x * 128;
    int col0 = blockIdx.y * 128;
    int b = r0 / NN, tileInB = (r0 % NN) / 128;
    const float* Fb = xcat + (size_t)r0 * 512;
    float acc[8][8] = {};
    for (int ch = 0; ch < 16; ++ch) {
        int cb = ch * 32;
        if (ch) __syncthreads();
        for (int t = tid; t < 128 * 8; t += 256) {
            int r = t & 127, cc = t >> 7;
            float v[4];
            *(float4*)v = *(const float4*)(Fb + (size_t)r * 512 + cb + 4 * cc);
            #pragma unroll
            for (int u = 0; u < 4; ++u) Xi[(4 * cc + u) * 128 + r] = v[u];
        }
        #pragma unroll
        for (int i = 0; i < 4; ++i) {
            int basec = wv6 * 8 + i * 2;
            const float* gp = w5t + (size_t)(cb + basec + (lane6 >> 5)) * 1024 + col0 + (lane6 & 31) * 4;
            __builtin_amdgcn_global_load_lds((const __attribute__((address_space(1))) void*)gp,
                (__attribute__((address_space(3))) void*)&Wj[basec * 128], 16, 0, 0);
        }
        __syncthreads();
        for (int c = 0; c < 32; ++c) {
            float a0[4], a1[4], w0[4], w1[4];
            *(float4*)a0 = *(const float4*)&Xi[c * 128 + 4 * ty];
            *(float4*)a1 = *(const float4*)&Xi[c * 128 + 64 + 4 * ty];
            *(float4*)w0 = *(const float4*)&Wj[c * 128 + 4 * tx];
            *(float4*)w1 = *(const float4*)&Wj[c * 128 + 64 + 4 * tx];
            #pragma unroll
            for (int r = 0; r < 4; ++r)
                #pragma unroll
                for (int u = 0; u < 4; ++u) {
                    acc[r][u]         += a0[r] * w0[u];
                    acc[r][4 + u]     += a0[r] * w1[u];
                    acc[4 + r][u]     += a1[r] * w0[u];
                    acc[4 + r][4 + u] += a1[r] * w1[u];
                }
        }
    }
    float hmx[2][4], hsm[2][4];
    #pragma unroll
    for (int h = 0; h < 2; ++h)
        #pragma unroll
        for (int u = 0; u < 4; ++u) { hmx[h][u] = -FLT_MAX; hsm[h][u] = 0.f; }
    #pragma unroll
    for (int h = 0; h < 2; ++h)
        #pragma unroll
        for (int u = 0; u < 4; ++u) {
            int o = col0 + 64 * h + 4 * tx + u;
            float sv = s5[o], bv = b5[o];
            #pragma unroll
            for (int r = 0; r < 8; ++r) {
                float hh = leaky(acc[r][4 * h + u] * sv + bv);
                hmx[h][u] = fmaxf(hmx[h][u], hh);
                hsm[h][u] += hh;
            }
        }
    __syncthreads();
    float* redM = Xi;
    float* redS = Wj;
    #pragma unroll
    for (int h = 0; h < 2; ++h) {
        *(float4*)&redM[ty * 128 + 64 * h + 4 * tx] = *(float4*)hmx[h];
        *(float4*)&redS[ty * 128 + 64 * h + 4 * tx] = *(float4*)hsm[h];
    }
    __syncthreads();
    for (int s = 8; s > 0; s >>= 1) {
        if (ty < s) {
            #pragma unroll
            for (int h = 0; h < 2; ++h) {
                int c = 64 * h + 4 * tx;
                float m0[4], m1[4], s0[4], s1[4];
                *(float4*)m0 = *(float4*)&redM[ty * 128 + c];
                *(float4*)m1 = *(float4*)&redM[(ty + s) * 128 + c];
                *(float4*)s0 = *(float4*)&redS[ty * 128 + c];
                *(float4*)s1 = *(float4*)&redS[(ty + s) * 128 + c];
                #pragma unroll
                for (int u = 0; u < 4; ++u) { m0[u] = fmaxf(m0[u], m1[u]); s0[u] += s1[u]; }
                *(float4*)&redM[ty * 128 + c] = *(float4*)m0;
                *(float4*)&redS[ty * 128 + c] = *(float4*)s0;
            }
        }
        __syncthreads();
    }
    if (ty == 0) {
        #pragma unroll
        for (int h = 0; h < 2; ++h) {
            int c = 64 * h + 4 * tx;
            size_t o = ((size_t)b * 16 + tileInB) * 1024 + col0 + c;
            *(float4*)&pmax[o] = *(float4*)&redM[c];
            *(float4*)&psum[o] = *(float4*)&redS[c];
        }
    }
}

__global__ void k_poolreduce(const float* __restrict__ pmax, const float* __restrict__ psum,
                             float* __restrict__ pooled) {
    int i = blockIdx.x * 256 + threadIdx.x;
    if (i >= BB * 1024) return;
    int b = i / 1024, o = i % 1024;
    float mx = -FLT_MAX, sm = 0.f;
    for (int ch = 0; ch < 16; ++ch) {
        mx = fmaxf(mx, pmax[((size_t)b * 16 + ch) * 1024 + o]);
        sm += psum[((size_t)b * 16 + ch) * 1024 + o];
    }
    pooled[(size_t)b * 2048 + o] = mx;
    pooled[(size_t)b * 2048 + 1024 + o] = sm / (float)NN;
}

// ---------- FC: wave-per-output, coalesced float4 weight reads, shfl reduce ----------
template<int CI, bool SCALE, bool RELU>
__global__ __launch_bounds__(256) void k_fcw(const float* __restrict__ in,
                                             const float* __restrict__ w,
                                             const float* __restrict__ sc,
                                             const float* __restrict__ bi,
                                             float* __restrict__ out, int CO) {
    int wv = (blockIdx.x << 2) + (threadIdx.x >> 6);
    int lane = threadIdx.x & 63;
    int o = wv % CO, b = wv / CO;
    const float* ir = in + (size_t)b * CI;
    const float* wr = w + (size_t)o * CI;
    float acc = 0.f;
    #pragma unroll
    for (int q = 0; q < CI / 256; ++q) {
        int ofs = q * 256 + 4 * lane;
        float4 wv4 = *(const float4*)(wr + ofs);
        float4 iv4 = *(const float4*)(ir + ofs);
        acc += wv4.x * iv4.x + wv4.y * iv4.y + wv4.z * iv4.z + wv4.w * iv4.w;
    }
    #pragma unroll
    for (int s = 1; s < 64; s <<= 1) acc += __shfl_xor(acc, s);
    if (lane == 0) {
        float v = SCALE ? (acc * sc[o] + bi[o]) : (acc + bi[o]);
        if (RELU) v = fmaxf(v, 0.f);
        out[wv] = v;
    }
}

extern "C" void kernel_launch(void* const* d_in, const int* in_sizes, int n_in,
                              void* d_out, int out_size, void* d_ws, size_t ws_size,
                              hipStream_t stream) {
    const float* x    = (const float*)d_in[0];
    const float* w1   = (const float*)d_in[1];
    const float* s1   = (const float*)d_in[2];
    const float* b1   = (const float*)d_in[3];
    const float* w2   = (const float*)d_in[4];
    const float* s2   = (const float*)d_in[5];
    const float* b2   = (const float*)d_in[6];
    const float* w3   = (const float*)d_in[7];
    const float* s3   = (const float*)d_in[8];
    const float* b3   = (const float*)d_in[9];
    const float* w4   = (const float*)d_in[10];
    const float* s4   = (const float*)d_in[11];
    const float* b4   = (const float*)d_in[12];
    const float* w5   = (const float*)d_in[13];
    const float* s5   = (const float*)d_in[14];
    const float* b5   = (const float*)d_in[15];
    const float* fc1w = (const float*)d_in[16];
    const float* s6   = (const float*)d_in[17];
    const float* b6   = (const float*)d_in[18];
    const float* fc2w = (const float*)d_in[19];
    const float* s7   = (const float*)d_in[20];
    const float* b7   = (const float*)d_in[21];
    const float* fc3w = (const float*)d_in[22];
    const float* fc3b = (const float*)d_in[23];
    float* out = (float*)d_out;

    char* ws = (char*)d_ws;
    size_t off = 0;
    auto alloc = [&](size_t bytes) {
        void* p = ws + off;
        off = (off + bytes + 255) & ~(size_t)255;
        return p;
    };
    float* xt   = (float*)alloc((size_t)BB * NN * 3 * 4);
    float* xcat = (float*)alloc((size_t)BB * NN * 512 * 4);
    int*   idx  = (int*)  alloc((size_t)BB * NN * KNN * 4);
    float* xx   = (float*)alloc((size_t)BB * NN * 4);
    float* wtA1 = (float*)alloc(3 * 64 * 4);
    float* wtD1 = (float*)alloc(3 * 64 * 4);
    float* wtA2 = (float*)alloc(64 * 64 * 4);
    float* wtD2 = (float*)alloc(64 * 64 * 4);
    float* wtA3 = (float*)alloc(64 * 128 * 4);
    float* wtD3 = (float*)alloc(64 * 128 * 4);
    float* wtA4 = (float*)alloc(128 * 256 * 4);
    float* wtD4 = (float*)alloc(128 * 256 * 4);
    size_t base_end = off;

    // UNION region: D (dist phase, per-batch chunks) / Y (transform) / head buffers
    const size_t D1 = (size_t)NN * NN * 4;
    size_t avail = ws_size > base_end ? ws_size - base_end : 0;
    int nbD = (int)(avail / D1);
    if (nbD < 1) nbD = 1;
    if (nbD > BB) nbD = BB;
    char* uni = ws + base_end;
    float* D      = (float*)uni;
    float* w5t    = (float*)uni;
    float* pmax   = w5t + 512 * 1024;
    float* psum   = pmax + (size_t)BB * 16 * 1024;
    float* pooled = psum + (size_t)BB * 16 * 1024;
    float* f1     = pooled + (size_t)BB * 2048;
    float* f2     = f1 + (size_t)BB * 512;

    k_transpose_x<<<(BB * NN * 3 + 255) / 256, 256, 0, stream>>>(x, xt);
    k_wpair_all<<<(45248 + 255) / 256, 256, 0, stream>>>(w1, w2, w3, w4,
        wtA1, wtD1, wtA2, wtD2, wtA3, wtD3, wtA4, wtD4);

    auto layer = [&](auto cTag, auto coTag, const float* F, int FS,
                     const float* wtA, const float* wtD,
                     const float* sc, const float* bi, float* outp) {
        constexpr int C  = decltype(cTag)::value;
        constexpr int CO = decltype(coTag)::value;
        k_xx<C><<<(BB * NN + 255) / 256, 256, 0, stream>>>(F, FS, xx);
        for (int b0 = 0; b0 < BB; b0 += nbD) {
            int nb = BB - b0 < nbD ? BB - b0 : nbD;
            if constexpr (C >= 32) {
                k_dist128s<C><<<nb * 136, 256, 0, stream>>>(F, FS, xx, b0, D);
            } else {
                k_dist<C><<<nb * 1024, 256, 0, stream>>>(F, FS, xx, b0, D);
            }
            k_select<<<nb * 512, 256, 0, stream>>>(D, idx, b0);
        }
        // transform + gather: Y-only union buffer (C2 goes straight into xcat)
        size_t ypb = (size_t)NN * CO * 4;
        int nbY = (int)(avail / ypb);
        if (nbY < 1) nbY = 1;
        if (nbY > BB) nbY = BB;
        for (int b0 = 0; b0 < BB; b0 += nbY) {
            int nb = BB - b0 < nbY ? BB - b0 : nbY;
            float* Yc = (float*)uni;
            dim3 g((nb * NN) / 64, CO / 64);
            k_gemm_pair<C, CO><<<g, 256, 0, stream>>>(F, FS, b0, wtA, wtD, Yc, outp);
            constexpr int PPB = 4 * (64 / (CO / 4));
            k_gather<CO><<<(nb * NN) / PPB, 256, 0, stream>>>(Yc, idx, sc, bi, outp, b0);
        }
    };

    layer(std::integral_constant<int, 3>{},   std::integral_constant<int, 64>{},  xt,         3,   wtA1, wtD1, s1, b1, xcat + 0);
    layer(std::integral_constant<int, 64>{},  std::integral_constant<int, 64>{},  xcat + 0,   512, wtA2, wtD2, s2, b2, xcat + 64);
    layer(std::integral_constant<int, 64>{},  std::integral_constant<int, 128>{}, xcat + 64,  512, wtA3, wtD3, s3, b3, xcat + 128);
    layer(std::integral_constant<int, 128>{}, std::integral_constant<int, 256>{}, xcat + 128, 512, wtA4, wtD4, s4, b4, xcat + 256);

    // head (union region now holds w5t/pmax/psum/pooled/f1/f2)
    dim3 gt(1024 / 64, 512 / 64);
    k_transpose_w_tiled<<<gt, 256, 0, stream>>>(w5, w5t, 1024, 512);
    dim3 g5((BB * NN) / 128, 1024 / 128);
    k_conv5<<<g5, 256, 0, stream>>>(xcat, w5t, s5, b5, pmax, psum);
    k_poolreduce<<<(BB * 1024 + 255) / 256, 256, 0, stream>>>(pmax, psum, pooled);
    k_fcw<2048, true,  true ><<<(BB * 512) / 4, 256, 0, stream>>>(pooled, fc1w, s6, b6, f1, 512);
    k_fcw<512,  true,  true ><<<(BB * 256) / 4, 256, 0, stream>>>(f1, fc2w, s7, b7, f2, 256);
    k_fcw<256,  false, false><<<(BB * 40)  / 4, 256, 0, stream>>>(f2, fc3w, nullptr, fc3b, out, 40);
}

// Round 12
// 704.277 us; speedup vs baseline: 2.2509x; 1.4224x over previous
//
#include <hip/hip_runtime.h>
#include <float.h>
#include <type_traits>

#define BB 8
#define NN 2048
#define KNN 20

__device__ __forceinline__ float leaky(float v) { return fmaxf(v, 0.2f * v); }

// ---------- transpose x (B,3,N) -> xt (B,N,3) ----------
__global__ void k_transpose_x(const float* __restrict__ x, float* __restrict__ xt) {
    int i = blockIdx.x * 256 + threadIdx.x;
    if (i >= BB * NN * 3) return;
    int c = i % 3; int n = (i / 3) % NN; int b = i / (3 * NN);
    xt[i] = x[((size_t)b * 3 + c) * NN + n];
}

// ---------- LDS-tiled transpose w (CO,CI) -> wt (CI,CO), 64x64 tiles ----------
__global__ __launch_bounds__(256) void k_transpose_w_tiled(const float* __restrict__ w,
                                                           float* __restrict__ wt,
                                                           int CO, int CI) {
    __shared__ float tile[64][65];
    int o0 = blockIdx.x * 64;
    int c0 = blockIdx.y * 64;
    int tid = threadIdx.x;
    for (int i = tid; i < 64 * 64; i += 256) {
        int r = i >> 6, c = i & 63;
        tile[r][c] = w[(size_t)(o0 + r) * CI + c0 + c];
    }
    __syncthreads();
    for (int i = tid; i < 64 * 64; i += 256) {
        int cc = i >> 6, oo = i & 63;
        wt[(size_t)(c0 + cc) * CO + o0 + oo] = tile[oo][cc];
    }
}

// ---------- all 4 edgeconv weight splits in ONE dispatch ----------
__device__ __forceinline__ void wpair_one(const float* __restrict__ w, float* __restrict__ wtA,
                                          float* __restrict__ wtD, int CO, int CI, int i) {
    int o = i / CI, c = i % CI;
    float a = w[(size_t)o * 2 * CI + c];
    float bb = w[(size_t)o * 2 * CI + CI + c];
    wtA[c * CO + o] = a;
    wtD[c * CO + o] = bb - a;
}
__global__ void k_wpair_all(const float* w1, const float* w2, const float* w3, const float* w4,
                            float* A1, float* D1, float* A2, float* D2,
                            float* A3, float* D3, float* A4, float* D4) {
    int i = blockIdx.x * 256 + threadIdx.x;
    if (i < 192)            { wpair_one(w1, A1, D1, 64, 3, i); }
    else if (i < 4288)      { wpair_one(w2, A2, D2, 64, 64, i - 192); }
    else if (i < 12480)     { wpair_one(w3, A3, D3, 128, 64, i - 4288); }
    else if (i < 45248)     { wpair_one(w4, A4, D4, 256, 128, i - 12480); }
}

// ---------- squared norms per point ----------
template<int C>
__global__ void k_xx(const float* __restrict__ F, int FS, float* __restrict__ xx) {
    int i = blockIdx.x * 256 + threadIdx.x;
    if (i >= BB * NN) return;
    const float* r = F + (size_t)i * FS;
    float s = 0.f;
    #pragma unroll
    for (int c = 0; c < C; ++c) { float v = r[c]; s += v * v; }
    xx[i] = s;
}

// ---------- distance matrix, small-C (C=3): 64x64 tile, full grid ----------
template<int C>
__global__ __launch_bounds__(256) void k_dist(const float* __restrict__ F, int FS,
                                              const float* __restrict__ xx, int b0,
                                              float* __restrict__ D) {
    __shared__ __align__(16) float Xi[C * 64];
    __shared__ __align__(16) float Xj[C * 64];
    int tid = threadIdx.x;
    int bl = blockIdx.x >> 10;
    int t  = blockIdx.x & 1023;
    int i0 = (t >> 5) * 64, j0 = (t & 31) * 64;
    int b = b0 + bl;
    const float* Fb = F + (size_t)b * NN * FS;
    int ty = tid >> 4, tx = tid & 15;
    float acc[4][4] = {};
    for (int k = tid; k < 64 * C; k += 256) {
        int r = k & 63, c = k >> 6;
        Xi[c * 64 + r] = Fb[(size_t)(i0 + r) * FS + c];
        Xj[c * 64 + r] = Fb[(size_t)(j0 + r) * FS + c];
    }
    __syncthreads();
    for (int c = 0; c < C; ++c) {
        float a[4], bv[4];
        *(float4*)a  = *(const float4*)&Xi[c * 64 + 4 * ty];
        *(float4*)bv = *(const float4*)&Xj[c * 64 + 4 * tx];
        #pragma unroll
        for (int r = 0; r < 4; ++r)
            #pragma unroll
            for (int s = 0; s < 4; ++s) acc[r][s] += a[r] * bv[s];
    }
    const float* xxb = xx + (size_t)b * NN;
    float xxi[4], xxj[4];
    #pragma unroll
    for (int r = 0; r < 4; ++r) xxi[r] = xxb[i0 + 4 * ty + r];
    #pragma unroll
    for (int s = 0; s < 4; ++s) xxj[s] = xxb[j0 + 4 * tx + s];
    float* Dp = D + (size_t)bl * NN * NN;
    #pragma unroll
    for (int r = 0; r < 4; ++r) {
        float ov[4];
        #pragma unroll
        for (int s = 0; s < 4; ++s) ov[s] = 2.f * acc[r][s] - xxi[r] - xxj[s];
        *(float4*)(Dp + (size_t)(i0 + 4 * ty + r) * NN + j0 + 4 * tx) = *(float4*)ov;
    }
}

// ---------- distance matrix, big-C: SYMMETRIC 128x128 tiles (136 of 256) ----------
template<int C>
__global__ __launch_bounds__(256) void k_dist128s(const float* __restrict__ F, int FS,
                                                  const float* __restrict__ xx, int b0,
                                                  float* __restrict__ D) {
    constexpr int NCH = C / 32;
    __shared__ __align__(16) float Xi[32 * 128];
    __shared__ __align__(16) float Xj[32 * 128];
    int tid = threadIdx.x;
    int ty = tid >> 4, tx = tid & 15;
    int bl = blockIdx.x / 136;
    int t  = blockIdx.x % 136;
    int it = 0, rem = t;
    while (rem >= 16 - it) { rem -= 16 - it; ++it; }
    int jt = it + rem;
    int i0 = it * 128, j0 = jt * 128;
    int b = b0 + bl;
    const float* Fb = F + (size_t)b * NN * FS;
    float acc[8][8] = {};
    for (int ch = 0; ch < NCH; ++ch) {
        int cb = ch * 32;
        if (ch) __syncthreads();
        for (int k = tid; k < 128 * 8; k += 256) {
            int r = k & 127, cc = k >> 7;
            float vi[4], vj[4];
            *(float4*)vi = *(const float4*)(Fb + (size_t)(i0 + r) * FS + cb + 4 * cc);
            *(float4*)vj = *(const float4*)(Fb + (size_t)(j0 + r) * FS + cb + 4 * cc);
            #pragma unroll
            for (int u = 0; u < 4; ++u) {
                Xi[(4 * cc + u) * 128 + r] = vi[u];
                Xj[(4 * cc + u) * 128 + r] = vj[u];
            }
        }
        __syncthreads();
        for (int c = 0; c < 32; ++c) {
            float a0[4], a1[4], w0[4], w1[4];
            *(float4*)a0 = *(const float4*)&Xi[c * 128 + 4 * ty];
            *(float4*)a1 = *(const float4*)&Xi[c * 128 + 64 + 4 * ty];
            *(float4*)w0 = *(const float4*)&Xj[c * 128 + 4 * tx];
            *(float4*)w1 = *(const float4*)&Xj[c * 128 + 64 + 4 * tx];
            #pragma unroll
            for (int r = 0; r < 4; ++r)
                #pragma unroll
                for (int s = 0; s < 4; ++s) {
                    acc[r][s]         += a0[r] * w0[s];
                    acc[r][4 + s]     += a0[r] * w1[s];
                    acc[4 + r][s]     += a1[r] * w0[s];
                    acc[4 + r][4 + s] += a1[r] * w1[s];
                }
        }
    }
    const float* xxb = xx + (size_t)b * NN;
    float xxi[8], xxj[8];
    #pragma unroll
    for (int r = 0; r < 4; ++r) {
        xxi[r]     = xxb[i0 + 4 * ty + r];
        xxi[4 + r] = xxb[i0 + 64 + 4 * ty + r];
        xxj[r]     = xxb[j0 + 4 * tx + r];
        xxj[4 + r] = xxb[j0 + 64 + 4 * tx + r];
    }
    float* Dp = D + (size_t)bl * NN * NN;
    #pragma unroll
    for (int r = 0; r < 8; ++r) {
        int row = i0 + (r < 4 ? 4 * ty + r : 64 + 4 * ty + (r - 4));
        float ov0[4], ov1[4];
        #pragma unroll
        for (int s = 0; s < 4; ++s) {
            ov0[s] = 2.f * acc[r][s]     - xxi[r] - xxj[s];
            ov1[s] = 2.f * acc[r][4 + s] - xxi[r] - xxj[4 + s];
        }
        *(float4*)(Dp + (size_t)row * NN + j0 + 4 * tx)      = *(float4*)ov0;
        *(float4*)(Dp + (size_t)row * NN + j0 + 64 + 4 * tx) = *(float4*)ov1;
    }
    if (it != jt) {
        #pragma unroll
        for (int sh = 0; sh < 2; ++sh)
            #pragma unroll
            for (int s = 0; s < 4; ++s) {
                int jrow = j0 + 64 * sh + 4 * tx + s;
                #pragma unroll
                for (int rh = 0; rh < 2; ++rh) {
                    float tv[4];
                    #pragma unroll
                    for (int r = 0; r < 4; ++r)
                        tv[r] = 2.f * acc[4 * rh + r][4 * sh + s] - xxi[4 * rh + r] - xxj[4 * sh + s];
                    *(float4*)(Dp + (size_t)jrow * NN + i0 + 64 * rh + 4 * ty) = *(float4*)tv;
                }
            }
    }
}

// ---------- top-20 selection v2: threshold + two bitonic sorts.
// Key = (~ordered_uint(value) << 32) | col  -> smaller key = better rank
// (value desc, col asc) == lax.top_k order. Phase 1: sort 64 lane-maxes,
// lane19 = threshold T (valid: the 20 best lane-maxes all >= T, so true
// top-20 values >= T). If M = #(values >= T) <= 64: compact to LDS, sort
// once more, lanes 0..19 emit. Else: fall back to 20-round extraction. ----------
__global__ __launch_bounds__(256) void k_select(const float* __restrict__ D,
                                                int* __restrict__ idxo, int b0) {
    __shared__ unsigned long long cbuf[4][64];
    int tid = threadIdx.x;
    int lane = tid & 63, wid = tid >> 6;
    int w = (blockIdx.x << 2) + wid;
    int bl = w / NN, n = w % NN;
    const float* row = D + (size_t)w * NN;
    unsigned uv[32];
    #pragma unroll
    for (int q = 0; q < 8; ++q) {
        float4 f4 = *(const float4*)(row + 4 * lane + 256 * q);
        float fv[4] = {f4.x, f4.y, f4.z, f4.w};
        #pragma unroll
        for (int u = 0; u < 4; ++u) {
            unsigned bb_ = __float_as_uint(fv[u]);
            uv[4 * q + u] = bb_ ^ ((bb_ & 0x80000000u) ? 0xFFFFFFFFu : 0x80000000u);
        }
    }
    // local best: max uv, smallest col on ties (ascending slot scan, strict >)
    unsigned bu = uv[0]; int bj = 0;
    #pragma unroll
    for (int j = 1; j < 32; ++j) if (uv[j] > bu) { bu = uv[j]; bj = j; }
    int bcol = 4 * lane + 256 * (bj >> 2) + (bj & 3);
    unsigned long long key = ((unsigned long long)(~bu) << 32) | (unsigned)bcol;
    // bitonic sort across 64 lanes, ascending (lane 0 = best)
    #pragma unroll
    for (int k = 2; k <= 64; k <<= 1)
        #pragma unroll
        for (int j = k >> 1; j > 0; j >>= 1) {
            unsigned long long o = __shfl_xor(key, j);
            bool keepMin = ((lane & k) == 0) == ((lane & j) == 0);
            bool omin = o < key;
            if (omin == keepMin) key = o;
        }
    unsigned long long Tkey = __shfl(key, 19);
    unsigned uT = ~(unsigned)(Tkey >> 32);
    // count candidates
    int cnt = 0;
    #pragma unroll
    for (int j = 0; j < 32; ++j) cnt += (uv[j] >= uT) ? 1 : 0;
    int M = cnt;
    #pragma unroll
    for (int s = 1; s < 64; s <<= 1) M += __shfl_xor(M, s);
    int* op = idxo + ((size_t)(b0 + bl) * NN + n) * KNN;
    if (M <= 64) {
        // exclusive prefix of cnt across lanes
        int inc = cnt;
        #pragma unroll
        for (int s = 1; s < 64; s <<= 1) {
            int t = __shfl_up(inc, s);
            if (lane >= s) inc += t;
        }
        int p = inc - cnt;
        #pragma unroll
        for (int j = 0; j < 32; ++j) {
            if (uv[j] >= uT) {
                int col = 4 * lane + 256 * (j >> 2) + (j & 3);
                cbuf[wid][p++] = ((unsigned long long)(~uv[j]) << 32) | (unsigned)col;
            }
        }
        asm volatile("s_waitcnt lgkmcnt(0)" ::: "memory");
        unsigned long long k2 = (lane < M) ? cbuf[wid][lane] : 0xFFFFFFFFFFFFFFFFull;
        #pragma unroll
        for (int k = 2; k <= 64; k <<= 1)
            #pragma unroll
            for (int j = k >> 1; j > 0; j >>= 1) {
                unsigned long long o = __shfl_xor(k2, j);
                bool keepMin = ((lane & k) == 0) == ((lane & j) == 0);
                bool omin = o < k2;
                if (omin == keepMin) k2 = o;
            }
        if (lane < KNN) op[lane] = (int)(unsigned)(k2 & 0xFFFFFFFFu);
    } else {
        // fallback: proven 20-round extraction on (uv, col)
        for (int k = 0; k < KNN; ++k) {
            unsigned rv = bu;
            int rc = 4 * lane + 256 * (bj >> 2) + (bj & 3);
            #pragma unroll
            for (int s = 1; s < 64; s <<= 1) {
                unsigned ov = __shfl_xor(rv, s);
                int oc = __shfl_xor(rc, s);
                if (ov > rv || (ov == rv && oc < rc)) { rv = ov; rc = oc; }
            }
            if (lane == 0) op[k] = rc;
            if (((rc >> 2) & 63) == lane) {
                int oj = ((rc >> 8) << 2) | (rc & 3);
                #pragma unroll
                for (int j = 0; j < 32; ++j) if (j == oj) uv[j] = 0u;
                bu = uv[0]; bj = 0;
                #pragma unroll
                for (int j = 1; j < 32; ++j) if (uv[j] > bu) { bu = uv[j]; bj = j; }
            }
        }
    }
}

// ---------- pair GEMM: Y = F*wtA (union buffer), C2 = F*wtD -> xcat slot ----------
template<int CIN, int COUT>
__global__ __launch_bounds__(256) void k_gemm_pair(const float* __restrict__ F, int FS, int b0,
    const float* __restrict__ wtA, const float* __restrict__ wtD,
    float* __restrict__ Y, float* __restrict__ c2x) {
    constexpr int CCH = (CIN >= 32) ? 32 : CIN;
    constexpr int NCH = CIN / CCH;
    __shared__ __align__(16) float Xi[CCH * 64];
    __shared__ __align__(16) float Wa[CCH * 64];
    __shared__ __align__(16) float Wd[CCH * 64];
    int tid = threadIdx.x;
    int r0 = blockIdx.x * 64;
    int c0 = blockIdx.y * 64;
    int b = b0 + r0 / NN;
    int n0 = r0 % NN;
    const float* Fb = F + ((size_t)b * NN + n0) * FS;
    int ty = tid >> 4, tx = tid & 15;
    float accY[4][4] = {}, accD[4][4] = {};
    for (int ch = 0; ch < NCH; ++ch) {
        int cb = ch * CCH;
        if (ch) __syncthreads();
        if constexpr (CCH % 4 == 0) {
            for (int t = tid; t < 64 * (CCH / 4); t += 256) {
                int r = t & 63, cc = t >> 6;
                float v[4];
                *(float4*)v = *(const float4*)(Fb + (size_t)r * FS + cb + 4 * cc);
                #pragma unroll
                for (int u = 0; u < 4; ++u) Xi[(4 * cc + u) * 64 + r] = v[u];
            }
            for (int t = tid; t < CCH * 16; t += 256) {
                int c = t >> 4, q = t & 15;
                *(float4*)&Wa[c * 64 + 4 * q] = *(const float4*)(wtA + (size_t)(cb + c) * COUT + c0 + 4 * q);
                *(float4*)&Wd[c * 64 + 4 * q] = *(const float4*)(wtD + (size_t)(cb + c) * COUT + c0 + 4 * q);
            }
        } else {
            for (int t = tid; t < 64 * CCH; t += 256) {
                int r = t & 63, c = t >> 6;
                Xi[c * 64 + r] = Fb[(size_t)r * FS + cb + c];
            }
            for (int t = tid; t < CCH * 64; t += 256) {
                int col = t & 63, c = t >> 6;
                Wa[c * 64 + col] = wtA[(size_t)(cb + c) * COUT + c0 + col];
                Wd[c * 64 + col] = wtD[(size_t)(cb + c) * COUT + c0 + col];
            }
        }
        __syncthreads();
        for (int c = 0; c < CCH; ++c) {
            float a[4], wa[4], wd[4];
            *(float4*)a  = *(const float4*)&Xi[c * 64 + 4 * ty];
            *(float4*)wa = *(const float4*)&Wa[c * 64 + 4 * tx];
            *(float4*)wd = *(const float4*)&Wd[c * 64 + 4 * tx];
            #pragma unroll
            for (int r = 0; r < 4; ++r)
                #pragma unroll
                for (int s = 0; s < 4; ++s) {
                    accY[r][s] += a[r] * wa[s];
                    accD[r][s] += a[r] * wd[s];
                }
        }
    }
    #pragma unroll
    for (int r = 0; r < 4; ++r) {
        *(float4*)(Y + (size_t)(r0 + 4 * ty + r) * COUT + c0 + 4 * tx) = *(float4*)accY[r];
        *(float4*)(c2x + ((size_t)b0 * NN + r0 + 4 * ty + r) * 512 + c0 + 4 * tx) = *(float4*)accD[r];
    }
}

// ---------- gather-max: io slot holds C2 on entry, final features on exit ----------
template<int COUT>
__global__ __launch_bounds__(256) void k_gather(const float* __restrict__ Y,
    const int* __restrict__ idx, const float* __restrict__ sc, const float* __restrict__ bi,
    float* io, int b0) {
    constexpr int LPP = COUT / 4;
    constexpr int PPW = 64 / LPP;
    constexpr int PPB = 4 * PPW;
    int tid = threadIdx.x;
    int lane = tid & 63, wv = tid >> 6;
    int pl = blockIdx.x * PPB + wv * PPW + lane / LPP;
    int bl = pl / NN, n = pl % NN;
    int o0 = 4 * (lane % LPP);
    float* iop = io + ((size_t)(b0 + bl) * NN + n) * 512 + o0;
    float c2[4], s4[4], b4[4];
    *(float4*)c2 = *(const float4*)iop;
    *(float4*)s4 = *(const float4*)(sc + o0);
    *(float4*)b4 = *(const float4*)(bi + o0);
    const int* ip = idx + ((size_t)(b0 + bl) * NN + n) * KNN;
    const float* Yb = Y + (size_t)bl * NN * COUT;
    float mx[4] = {-FLT_MAX, -FLT_MAX, -FLT_MAX, -FLT_MAX};
    for (int k = 0; k < KNN; ++k) {
        int m = ip[k];
        float y[4];
        *(float4*)y = *(const float4*)(Yb + (size_t)m * COUT + o0);
        #pragma unroll
        for (int u = 0; u < 4; ++u) {
            float v = (y[u] + c2[u]) * s4[u] + b4[u];
            mx[u] = fmaxf(mx[u], leaky(v));
        }
    }
    *(float4*)iop = *(float4*)mx;
}

// ---------- conv5: 128x128 tile, 8x8 micro-tile, fused partial pooling ----------
__global__ __launch_bounds__(256) void k_conv5(const float* __restrict__ xcat,
    const float* __restrict__ w5t, const float* __restrict__ s5, const float* __restrict__ b5,
    float* __restrict__ pmax, float* __restrict__ psum) {
    __shared__ __align__(16) float Xi[32 * 128];
    __shared__ __align__(16) float Wj[32 * 128];
    int tid = threadIdx.x;
    int ty = tid >> 4, tx = tid & 15;
    int wv6 = tid >> 6, lane6 = tid & 63;
    int r0 = blockIdx.x * 128;
    int col0 = blockIdx.y * 128;
    int b = r0 / NN, tileInB = (r0 % NN) / 128;
    const float* Fb = xcat + (size_t)r0 * 512;
    float acc[8][8] = {};
    for (int ch = 0; ch < 16; ++ch) {
        int cb = ch * 32;
        if (ch) __syncthreads();
        for (int t = tid; t < 128 * 8; t += 256) {
            int r = t & 127, cc = t >> 7;
            float v[4];
            *(float4*)v = *(const float4*)(Fb + (size_t)r * 512 + cb + 4 * cc);
            #pragma unroll
            for (int u = 0; u < 4; ++u) Xi[(4 * cc + u) * 128 + r] = v[u];
        }
        #pragma unroll
        for (int i = 0; i < 4; ++i) {
            int basec = wv6 * 8 + i * 2;
            const float* gp = w5t + (size_t)(cb + basec + (lane6 >> 5)) * 1024 + col0 + (lane6 & 31) * 4;
            __builtin_amdgcn_global_load_lds((const __attribute__((address_space(1))) void*)gp,
                (__attribute__((address_space(3))) void*)&Wj[basec * 128], 16, 0, 0);
        }
        __syncthreads();
        for (int c = 0; c < 32; ++c) {
            float a0[4], a1[4], w0[4], w1[4];
            *(float4*)a0 = *(const float4*)&Xi[c * 128 + 4 * ty];
            *(float4*)a1 = *(const float4*)&Xi[c * 128 + 64 + 4 * ty];
            *(float4*)w0 = *(const float4*)&Wj[c * 128 + 4 * tx];
            *(float4*)w1 = *(const float4*)&Wj[c * 128 + 64 + 4 * tx];
            #pragma unroll
            for (int r = 0; r < 4; ++r)
                #pragma unroll
                for (int u = 0; u < 4; ++u) {
                    acc[r][u]         += a0[r] * w0[u];
                    acc[r][4 + u]     += a0[r] * w1[u];
                    acc[4 + r][u]     += a1[r] * w0[u];
                    acc[4 + r][4 + u] += a1[r] * w1[u];
                }
        }
    }
    float hmx[2][4], hsm[2][4];
    #pragma unroll
    for (int h = 0; h < 2; ++h)
        #pragma unroll
        for (int u = 0; u < 4; ++u) { hmx[h][u] = -FLT_MAX; hsm[h][u] = 0.f; }
    #pragma unroll
    for (int h = 0; h < 2; ++h)
        #pragma unroll
        for (int u = 0; u < 4; ++u) {
            int o = col0 + 64 * h + 4 * tx + u;
            float sv = s5[o], bv = b5[o];
            #pragma unroll
            for (int r = 0; r < 8; ++r) {
                float hh = leaky(acc[r][4 * h + u] * sv + bv);
                hmx[h][u] = fmaxf(hmx[h][u], hh);
                hsm[h][u] += hh;
            }
        }
    __syncthreads();
    float* redM = Xi;
    float* redS = Wj;
    #pragma unroll
    for (int h = 0; h < 2; ++h) {
        *(float4*)&redM[ty * 128 + 64 * h + 4 * tx] = *(float4*)hmx[h];
        *(float4*)&redS[ty * 128 + 64 * h + 4 * tx] = *(float4*)hsm[h];
    }
    __syncthreads();
    for (int s = 8; s > 0; s >>= 1) {
        if (ty < s) {
            #pragma unroll
            for (int h = 0; h < 2; ++h) {
                int c = 64 * h + 4 * tx;
                float m0[4], m1[4], s0[4], s1[4];
                *(float4*)m0 = *(float4*)&redM[ty * 128 + c];
                *(float4*)m1 = *(float4*)&redM[(ty + s) * 128 + c];
                *(float4*)s0 = *(float4*)&redS[ty * 128 + c];
                *(float4*)s1 = *(float4*)&redS[(ty + s) * 128 + c];
                #pragma unroll
                for (int u = 0; u < 4; ++u) { m0[u] = fmaxf(m0[u], m1[u]); s0[u] += s1[u]; }
                *(float4*)&redM[ty * 128 + c] = *(float4*)m0;
                *(float4*)&redS[ty * 128 + c] = *(float4*)s0;
            }
        }
        __syncthreads();
    }
    if (ty == 0) {
        #pragma unroll
        for (int h = 0; h < 2; ++h) {
            int c = 64 * h + 4 * tx;
            size_t o = ((size_t)b * 16 + tileInB) * 1024 + col0 + c;
            *(float4*)&pmax[o] = *(float4*)&redM[c];
            *(float4*)&psum[o] = *(float4*)&redS[c];
        }
    }
}

__global__ void k_poolreduce(const float* __restrict__ pmax, const float* __restrict__ psum,
                             float* __restrict__ pooled) {
    int i = blockIdx.x * 256 + threadIdx.x;
    if (i >= BB * 1024) return;
    int b = i / 1024, o = i % 1024;
    float mx = -FLT_MAX, sm = 0.f;
    for (int ch = 0; ch < 16; ++ch) {
        mx = fmaxf(mx, pmax[((size_t)b * 16 + ch) * 1024 + o]);
        sm += psum[((size_t)b * 16 + ch) * 1024 + o];
    }
    pooled[(size_t)b * 2048 + o] = mx;
    pooled[(size_t)b * 2048 + 1024 + o] = sm / (float)NN;
}

// ---------- FC: wave-per-output, coalesced float4 weight reads, shfl reduce ----------
template<int CI, bool SCALE, bool RELU>
__global__ __launch_bounds__(256) void k_fcw(const float* __restrict__ in,
                                             const float* __restrict__ w,
                                             const float* __restrict__ sc,
                                             const float* __restrict__ bi,
                                             float* __restrict__ out, int CO) {
    int wv = (blockIdx.x << 2) + (threadIdx.x >> 6);
    int lane = threadIdx.x & 63;
    int o = wv % CO, b = wv / CO;
    const float* ir = in + (size_t)b * CI;
    const float* wr = w + (size_t)o * CI;
    float acc = 0.f;
    #pragma unroll
    for (int q = 0; q < CI / 256; ++q) {
        int ofs = q * 256 + 4 * lane;
        float4 wv4 = *(const float4*)(wr + ofs);
        float4 iv4 = *(const float4*)(ir + ofs);
        acc += wv4.x * iv4.x + wv4.y * iv4.y + wv4.z * iv4.z + wv4.w * iv4.w;
    }
    #pragma unroll
    for (int s = 1; s < 64; s <<= 1) acc += __shfl_xor(acc, s);
    if (lane == 0) {
        float v = SCALE ? (acc * sc[o] + bi[o]) : (acc + bi[o]);
        if (RELU) v = fmaxf(v, 0.f);
        out[wv] = v;
    }
}

extern "C" void kernel_launch(void* const* d_in, const int* in_sizes, int n_in,
                              void* d_out, int out_size, void* d_ws, size_t ws_size,
                              hipStream_t stream) {
    const float* x    = (const float*)d_in[0];
    const float* w1   = (const float*)d_in[1];
    const float* s1   = (const float*)d_in[2];
    const float* b1   = (const float*)d_in[3];
    const float* w2   = (const float*)d_in[4];
    const float* s2   = (const float*)d_in[5];
    const float* b2   = (const float*)d_in[6];
    const float* w3   = (const float*)d_in[7];
    const float* s3   = (const float*)d_in[8];
    const float* b3   = (const float*)d_in[9];
    const float* w4   = (const float*)d_in[10];
    const float* s4   = (const float*)d_in[11];
    const float* b4   = (const float*)d_in[12];
    const float* w5   = (const float*)d_in[13];
    const float* s5   = (const float*)d_in[14];
    const float* b5   = (const float*)d_in[15];
    const float* fc1w = (const float*)d_in[16];
    const float* s6   = (const float*)d_in[17];
    const float* b6   = (const float*)d_in[18];
    const float* fc2w = (const float*)d_in[19];
    const float* s7   = (const float*)d_in[20];
    const float* b7   = (const float*)d_in[21];
    const float* fc3w = (const float*)d_in[22];
    const float* fc3b = (const float*)d_in[23];
    float* out = (float*)d_out;

    char* ws = (char*)d_ws;
    size_t off = 0;
    auto alloc = [&](size_t bytes) {
        void* p = ws + off;
        off = (off + bytes + 255) & ~(size_t)255;
        return p;
    };
    float* xt   = (float*)alloc((size_t)BB * NN * 3 * 4);
    float* xcat = (float*)alloc((size_t)BB * NN * 512 * 4);
    int*   idx  = (int*)  alloc((size_t)BB * NN * KNN * 4);
    float* xx   = (float*)alloc((size_t)BB * NN * 4);
    float* wtA1 = (float*)alloc(3 * 64 * 4);
    float* wtD1 = (float*)alloc(3 * 64 * 4);
    float* wtA2 = (float*)alloc(64 * 64 * 4);
    float* wtD2 = (float*)alloc(64 * 64 * 4);
    float* wtA3 = (float*)alloc(64 * 128 * 4);
    float* wtD3 = (float*)alloc(64 * 128 * 4);
    float* wtA4 = (float*)alloc(128 * 256 * 4);
    float* wtD4 = (float*)alloc(128 * 256 * 4);
    size_t base_end = off;

    // UNION region: D (dist phase, per-batch chunks) / Y (transform) / head buffers
    const size_t D1 = (size_t)NN * NN * 4;
    size_t avail = ws_size > base_end ? ws_size - base_end : 0;
    int nbD = (int)(avail / D1);
    if (nbD < 1) nbD = 1;
    if (nbD > BB) nbD = BB;
    char* uni = ws + base_end;
    float* D      = (float*)uni;
    float* w5t    = (float*)uni;
    float* pmax   = w5t + 512 * 1024;
    float* psum   = pmax + (size_t)BB * 16 * 1024;
    float* pooled = psum + (size_t)BB * 16 * 1024;
    float* f1     = pooled + (size_t)BB * 2048;
    float* f2     = f1 + (size_t)BB * 512;

    k_transpose_x<<<(BB * NN * 3 + 255) / 256, 256, 0, stream>>>(x, xt);
    k_wpair_all<<<(45248 + 255) / 256, 256, 0, stream>>>(w1, w2, w3, w4,
        wtA1, wtD1, wtA2, wtD2, wtA3, wtD3, wtA4, wtD4);

    auto layer = [&](auto cTag, auto coTag, const float* F, int FS,
                     const float* wtA, const float* wtD,
                     const float* sc, const float* bi, float* outp) {
        constexpr int C  = decltype(cTag)::value;
        constexpr int CO = decltype(coTag)::value;
        k_xx<C><<<(BB * NN + 255) / 256, 256, 0, stream>>>(F, FS, xx);
        for (int b0 = 0; b0 < BB; b0 += nbD) {
            int nb = BB - b0 < nbD ? BB - b0 : nbD;
            if constexpr (C >= 32) {
                k_dist128s<C><<<nb * 136, 256, 0, stream>>>(F, FS, xx, b0, D);
            } else {
                k_dist<C><<<nb * 1024, 256, 0, stream>>>(F, FS, xx, b0, D);
            }
            k_select<<<nb * 512, 256, 0, stream>>>(D, idx, b0);
        }
        size_t ypb = (size_t)NN * CO * 4;
        int nbY = (int)(avail / ypb);
        if (nbY < 1) nbY = 1;
        if (nbY > BB) nbY = BB;
        for (int b0 = 0; b0 < BB; b0 += nbY) {
            int nb = BB - b0 < nbY ? BB - b0 : nbY;
            float* Yc = (float*)uni;
            dim3 g((nb * NN) / 64, CO / 64);
            k_gemm_pair<C, CO><<<g, 256, 0, stream>>>(F, FS, b0, wtA, wtD, Yc, outp);
            constexpr int PPB = 4 * (64 / (CO / 4));
            k_gather<CO><<<(nb * NN) / PPB, 256, 0, stream>>>(Yc, idx, sc, bi, outp, b0);
        }
    };

    layer(std::integral_constant<int, 3>{},   std::integral_constant<int, 64>{},  xt,         3,   wtA1, wtD1, s1, b1, xcat + 0);
    layer(std::integral_constant<int, 64>{},  std::integral_constant<int, 64>{},  xcat + 0,   512, wtA2, wtD2, s2, b2, xcat + 64);
    layer(std::integral_constant<int, 64>{},  std::integral_constant<int, 128>{}, xcat + 64,  512, wtA3, wtD3, s3, b3, xcat + 128);
    layer(std::integral_constant<int, 128>{}, std::integral_constant<int, 256>{}, xcat + 128, 512, wtA4, wtD4, s4, b4, xcat + 256);

    // head (union region now holds w5t/pmax/psum/pooled/f1/f2)
    dim3 gt(1024 / 64, 512 / 64);
    k_transpose_w_tiled<<<gt, 256, 0, stream>>>(w5, w5t, 1024, 512);
    dim3 g5((BB * NN) / 128, 1024 / 128);
    k_conv5<<<g5, 256, 0, stream>>>(xcat, w5t, s5, b5, pmax, psum);
    k_poolreduce<<<(BB * 1024 + 255) / 256, 256, 0, stream>>>(pmax, psum, pooled);
    k_fcw<2048, true,  true ><<<(BB * 512) / 4, 256, 0, stream>>>(pooled, fc1w, s6, b6, f1, 512);
    k_fcw<512,  true,  true ><<<(BB * 256) / 4, 256, 0, stream>>>(f1, fc2w, s7, b7, f2, 256);
    k_fcw<256,  false, false><<<(BB * 40)  / 4, 256, 0, stream>>>(f2, fc3w, nullptr, fc3b, out, 40);
}

// Round 13
// 691.945 us; speedup vs baseline: 2.2911x; 1.0178x over previous
//
#include <hip/hip_runtime.h>
#include <float.h>
#include <type_traits>

#define BB 8
#define NN 2048
#define KNN 20

__device__ __forceinline__ float leaky(float v) { return fmaxf(v, 0.2f * v); }

// ---------- transpose x (B,3,N) -> xt (B,N,3) ----------
__global__ void k_transpose_x(const float* __restrict__ x, float* __restrict__ xt) {
    int i = blockIdx.x * 256 + threadIdx.x;
    if (i >= BB * NN * 3) return;
    int c = i % 3; int n = (i / 3) % NN; int b = i / (3 * NN);
    xt[i] = x[((size_t)b * 3 + c) * NN + n];
}

// ---------- LDS-tiled transpose w (CO,CI) -> wt (CI,CO), 64x64 tiles ----------
__global__ __launch_bounds__(256) void k_transpose_w_tiled(const float* __restrict__ w,
                                                           float* __restrict__ wt,
                                                           int CO, int CI) {
    __shared__ float tile[64][65];
    int o0 = blockIdx.x * 64;
    int c0 = blockIdx.y * 64;
    int tid = threadIdx.x;
    for (int i = tid; i < 64 * 64; i += 256) {
        int r = i >> 6, c = i & 63;
        tile[r][c] = w[(size_t)(o0 + r) * CI + c0 + c];
    }
    __syncthreads();
    for (int i = tid; i < 64 * 64; i += 256) {
        int cc = i >> 6, oo = i & 63;
        wt[(size_t)(c0 + cc) * CO + o0 + oo] = tile[oo][cc];
    }
}

// ---------- all 4 edgeconv weight splits in ONE dispatch ----------
__device__ __forceinline__ void wpair_one(const float* __restrict__ w, float* __restrict__ wtA,
                                          float* __restrict__ wtD, int CO, int CI, int i) {
    int o = i / CI, c = i % CI;
    float a = w[(size_t)o * 2 * CI + c];
    float bb = w[(size_t)o * 2 * CI + CI + c];
    wtA[c * CO + o] = a;
    wtD[c * CO + o] = bb - a;
}
__global__ void k_wpair_all(const float* w1, const float* w2, const float* w3, const float* w4,
                            float* A1, float* D1, float* A2, float* D2,
                            float* A3, float* D3, float* A4, float* D4) {
    int i = blockIdx.x * 256 + threadIdx.x;
    if (i < 192)            { wpair_one(w1, A1, D1, 64, 3, i); }
    else if (i < 4288)      { wpair_one(w2, A2, D2, 64, 64, i - 192); }
    else if (i < 12480)     { wpair_one(w3, A3, D3, 128, 64, i - 4288); }
    else if (i < 45248)     { wpair_one(w4, A4, D4, 256, 128, i - 12480); }
}

// ---------- squared norms, C=3 (coalesced as-is, exact order) ----------
__global__ void k_xx3(const float* __restrict__ F, float* __restrict__ xx) {
    int i = blockIdx.x * 256 + threadIdx.x;
    if (i >= BB * NN) return;
    const float* r = F + (size_t)i * 3;
    float s = 0.f;
    #pragma unroll
    for (int c = 0; c < 3; ++c) { float v = r[c]; s += v * v; }
    xx[i] = s;
}

// ---------- squared norms, big-C: LDS-tiled (coalesced reads, EXACT same
// sequential-c summation order as the old per-thread version) ----------
template<int C>
__global__ __launch_bounds__(256) void k_xxt(const float* __restrict__ F, int FS,
                                             float* __restrict__ xx) {
    __shared__ float tile[64][C + 1];
    int p0 = blockIdx.x * 64;
    int tid = threadIdx.x;
    constexpr int C4 = C / 4;
    for (int t = tid; t < 64 * C4; t += 256) {
        int r = t / C4, c4 = t % C4;
        float4 v = *(const float4*)(F + (size_t)(p0 + r) * FS + 4 * c4);
        tile[r][4 * c4]     = v.x;
        tile[r][4 * c4 + 1] = v.y;
        tile[r][4 * c4 + 2] = v.z;
        tile[r][4 * c4 + 3] = v.w;
    }
    __syncthreads();
    if (tid < 64) {
        float s = 0.f;
        #pragma unroll
        for (int c = 0; c < C; ++c) { float v = tile[tid][c]; s += v * v; }
        xx[p0 + tid] = s;
    }
}

// ---------- distance matrix, big-C: SYMMETRIC 128x128 tiles (136 of 256) ----------
template<int C>
__global__ __launch_bounds__(256) void k_dist128s(const float* __restrict__ F, int FS,
                                                  const float* __restrict__ xx, int b0,
                                                  float* __restrict__ D) {
    constexpr int NCH = C / 32;
    __shared__ __align__(16) float Xi[32 * 128];
    __shared__ __align__(16) float Xj[32 * 128];
    int tid = threadIdx.x;
    int ty = tid >> 4, tx = tid & 15;
    int bl = blockIdx.x / 136;
    int t  = blockIdx.x % 136;
    int it = 0, rem = t;
    while (rem >= 16 - it) { rem -= 16 - it; ++it; }
    int jt = it + rem;
    int i0 = it * 128, j0 = jt * 128;
    int b = b0 + bl;
    const float* Fb = F + (size_t)b * NN * FS;
    float acc[8][8] = {};
    for (int ch = 0; ch < NCH; ++ch) {
        int cb = ch * 32;
        if (ch) __syncthreads();
        for (int k = tid; k < 128 * 8; k += 256) {
            int r = k & 127, cc = k >> 7;
            float vi[4], vj[4];
            *(float4*)vi = *(const float4*)(Fb + (size_t)(i0 + r) * FS + cb + 4 * cc);
            *(float4*)vj = *(const float4*)(Fb + (size_t)(j0 + r) * FS + cb + 4 * cc);
            #pragma unroll
            for (int u = 0; u < 4; ++u) {
                Xi[(4 * cc + u) * 128 + r] = vi[u];
                Xj[(4 * cc + u) * 128 + r] = vj[u];
            }
        }
        __syncthreads();
        for (int c = 0; c < 32; ++c) {
            float a0[4], a1[4], w0[4], w1[4];
            *(float4*)a0 = *(const float4*)&Xi[c * 128 + 4 * ty];
            *(float4*)a1 = *(const float4*)&Xi[c * 128 + 64 + 4 * ty];
            *(float4*)w0 = *(const float4*)&Xj[c * 128 + 4 * tx];
            *(float4*)w1 = *(const float4*)&Xj[c * 128 + 64 + 4 * tx];
            #pragma unroll
            for (int r = 0; r < 4; ++r)
                #pragma unroll
                for (int s = 0; s < 4; ++s) {
                    acc[r][s]         += a0[r] * w0[s];
                    acc[r][4 + s]     += a0[r] * w1[s];
                    acc[4 + r][s]     += a1[r] * w0[s];
                    acc[4 + r][4 + s] += a1[r] * w1[s];
                }
        }
    }
    const float* xxb = xx + (size_t)b * NN;
    float xxi[8], xxj[8];
    #pragma unroll
    for (int r = 0; r < 4; ++r) {
        xxi[r]     = xxb[i0 + 4 * ty + r];
        xxi[4 + r] = xxb[i0 + 64 + 4 * ty + r];
        xxj[r]     = xxb[j0 + 4 * tx + r];
        xxj[4 + r] = xxb[j0 + 64 + 4 * tx + r];
    }
    float* Dp = D + (size_t)bl * NN * NN;
    #pragma unroll
    for (int r = 0; r < 8; ++r) {
        int row = i0 + (r < 4 ? 4 * ty + r : 64 + 4 * ty + (r - 4));
        float ov0[4], ov1[4];
        #pragma unroll
        for (int s = 0; s < 4; ++s) {
            ov0[s] = 2.f * acc[r][s]     - xxi[r] - xxj[s];
            ov1[s] = 2.f * acc[r][4 + s] - xxi[r] - xxj[4 + s];
        }
        *(float4*)(Dp + (size_t)row * NN + j0 + 4 * tx)      = *(float4*)ov0;
        *(float4*)(Dp + (size_t)row * NN + j0 + 64 + 4 * tx) = *(float4*)ov1;
    }
    if (it != jt) {
        #pragma unroll
        for (int sh = 0; sh < 2; ++sh)
            #pragma unroll
            for (int s = 0; s < 4; ++s) {
                int jrow = j0 + 64 * sh + 4 * tx + s;
                #pragma unroll
                for (int rh = 0; rh < 2; ++rh) {
                    float tv[4];
                    #pragma unroll
                    for (int r = 0; r < 4; ++r)
                        tv[r] = 2.f * acc[4 * rh + r][4 * sh + s] - xxi[4 * rh + r] - xxj[4 * sh + s];
                    *(float4*)(Dp + (size_t)jrow * NN + i0 + 64 * rh + 4 * ty) = *(float4*)tv;
                }
            }
    }
}

// ---------- top-20 selection v2 (D-based, layers 2-4) ----------
__global__ __launch_bounds__(256) void k_select(const float* __restrict__ D,
                                                int* __restrict__ idxo, int b0) {
    __shared__ unsigned long long cbuf[4][64];
    int tid = threadIdx.x;
    int lane = tid & 63, wid = tid >> 6;
    int w = (blockIdx.x << 2) + wid;
    int bl = w / NN, n = w % NN;
    const float* row = D + (size_t)w * NN;
    unsigned uv[32];
    #pragma unroll
    for (int q = 0; q < 8; ++q) {
        float4 f4 = *(const float4*)(row + 4 * lane + 256 * q);
        float fv[4] = {f4.x, f4.y, f4.z, f4.w};
        #pragma unroll
        for (int u = 0; u < 4; ++u) {
            unsigned bb_ = __float_as_uint(fv[u]);
            uv[4 * q + u] = bb_ ^ ((bb_ & 0x80000000u) ? 0xFFFFFFFFu : 0x80000000u);
        }
    }
    unsigned bu = uv[0]; int bj = 0;
    #pragma unroll
    for (int j = 1; j < 32; ++j) if (uv[j] > bu) { bu = uv[j]; bj = j; }
    int bcol = 4 * lane + 256 * (bj >> 2) + (bj & 3);
    unsigned long long key = ((unsigned long long)(~bu) << 32) | (unsigned)bcol;
    #pragma unroll
    for (int k = 2; k <= 64; k <<= 1)
        #pragma unroll
        for (int j = k >> 1; j > 0; j >>= 1) {
            unsigned long long o = __shfl_xor(key, j);
            bool keepMin = ((lane & k) == 0) == ((lane & j) == 0);
            bool omin = o < key;
            if (omin == keepMin) key = o;
        }
    unsigned long long Tkey = __shfl(key, 19);
    unsigned uT = ~(unsigned)(Tkey >> 32);
    int cnt = 0;
    #pragma unroll
    for (int j = 0; j < 32; ++j) cnt += (uv[j] >= uT) ? 1 : 0;
    int M = cnt;
    #pragma unroll
    for (int s = 1; s < 64; s <<= 1) M += __shfl_xor(M, s);
    int* op = idxo + ((size_t)(b0 + bl) * NN + n) * KNN;
    if (M <= 64) {
        int inc = cnt;
        #pragma unroll
        for (int s = 1; s < 64; s <<= 1) {
            int t = __shfl_up(inc, s);
            if (lane >= s) inc += t;
        }
        int p = inc - cnt;
        #pragma unroll
        for (int j = 0; j < 32; ++j) {
            if (uv[j] >= uT) {
                int col = 4 * lane + 256 * (j >> 2) + (j & 3);
                cbuf[wid][p++] = ((unsigned long long)(~uv[j]) << 32) | (unsigned)col;
            }
        }
        asm volatile("s_waitcnt lgkmcnt(0)" ::: "memory");
        unsigned long long k2 = (lane < M) ? cbuf[wid][lane] : 0xFFFFFFFFFFFFFFFFull;
        #pragma unroll
        for (int k = 2; k <= 64; k <<= 1)
            #pragma unroll
            for (int j = k >> 1; j > 0; j >>= 1) {
                unsigned long long o = __shfl_xor(k2, j);
                bool keepMin = ((lane & k) == 0) == ((lane & j) == 0);
                bool omin = o < k2;
                if (omin == keepMin) k2 = o;
            }
        if (lane < KNN) op[lane] = (int)(unsigned)(k2 & 0xFFFFFFFFu);
    } else {
        for (int k = 0; k < KNN; ++k) {
            unsigned rv = bu;
            int rc = 4 * lane + 256 * (bj >> 2) + (bj & 3);
            #pragma unroll
            for (int s = 1; s < 64; s <<= 1) {
                unsigned ov = __shfl_xor(rv, s);
                int oc = __shfl_xor(rc, s);
                if (ov > rv || (ov == rv && oc < rc)) { rv = ov; rc = oc; }
            }
            if (lane == 0) op[k] = rc;
            if (((rc >> 2) & 63) == lane) {
                int oj = ((rc >> 8) << 2) | (rc & 3);
                #pragma unroll
                for (int j = 0; j < 32; ++j) if (j == oj) uv[j] = 0u;
                bu = uv[0]; bj = 0;
                #pragma unroll
                for (int j = 1; j < 32; ++j) if (uv[j] > bu) { bu = uv[j]; bj = j; }
            }
        }
    }
}

// ---------- fused C=3 KNN: batch coords+norms staged in LDS (SoA, bank-free),
// distances computed per lane with identical fma-chain order as old k_dist<3>,
// then the same threshold/bitonic select. No D buffer, no dist dispatches. ----------
__global__ __launch_bounds__(256) void k_select3(const float* __restrict__ xt,
                                                 const float* __restrict__ xx,
                                                 int* __restrict__ idxo) {
    __shared__ float xs[NN], ys[NN], zs[NN], xxs[NN];
    __shared__ unsigned long long cbuf[4][64];
    int tid = threadIdx.x;
    int lane = tid & 63, wid = tid >> 6;
    int b = blockIdx.x >> 9;
    int n = (blockIdx.x & 511) * 4 + wid;
    const float* Fb = xt + (size_t)b * NN * 3;
    for (int t = tid; t < NN; t += 256) {
        xs[t] = Fb[3 * t];
        ys[t] = Fb[3 * t + 1];
        zs[t] = Fb[3 * t + 2];
        xxs[t] = xx[(size_t)b * NN + t];
    }
    __syncthreads();
    float qx = xs[n], qy = ys[n], qz = zs[n], xxn = xxs[n];
    unsigned uv[32];
    #pragma unroll
    for (int j = 0; j < 32; ++j) {
        int m = lane + 64 * j;
        float dot = qx * xs[m];
        dot = fmaf(qy, ys[m], dot);
        dot = fmaf(qz, zs[m], dot);
        float d = 2.f * dot - xxn - xxs[m];
        unsigned bb_ = __float_as_uint(d);
        uv[j] = bb_ ^ ((bb_ & 0x80000000u) ? 0xFFFFFFFFu : 0x80000000u);
    }
    // local best (j ascending == col ascending for fixed lane; strict > keeps smallest)
    unsigned bu = uv[0]; int bj = 0;
    #pragma unroll
    for (int j = 1; j < 32; ++j) if (uv[j] > bu) { bu = uv[j]; bj = j; }
    int bcol = lane + 64 * bj;
    unsigned long long key = ((unsigned long long)(~bu) << 32) | (unsigned)bcol;
    #pragma unroll
    for (int k = 2; k <= 64; k <<= 1)
        #pragma unroll
        for (int j = k >> 1; j > 0; j >>= 1) {
            unsigned long long o = __shfl_xor(key, j);
            bool keepMin = ((lane & k) == 0) == ((lane & j) == 0);
            bool omin = o < key;
            if (omin == keepMin) key = o;
        }
    unsigned long long Tkey = __shfl(key, 19);
    unsigned uT = ~(unsigned)(Tkey >> 32);
    int cnt = 0;
    #pragma unroll
    for (int j = 0; j < 32; ++j) cnt += (uv[j] >= uT) ? 1 : 0;
    int M = cnt;
    #pragma unroll
    for (int s = 1; s < 64; s <<= 1) M += __shfl_xor(M, s);
    int* op = idxo + ((size_t)b * NN + n) * KNN;
    if (M <= 64) {
        int inc = cnt;
        #pragma unroll
        for (int s = 1; s < 64; s <<= 1) {
            int t = __shfl_up(inc, s);
            if (lane >= s) inc += t;
        }
        int p = inc - cnt;
        #pragma unroll
        for (int j = 0; j < 32; ++j) {
            if (uv[j] >= uT) {
                int col = lane + 64 * j;
                cbuf[wid][p++] = ((unsigned long long)(~uv[j]) << 32) | (unsigned)col;
            }
        }
        asm volatile("s_waitcnt lgkmcnt(0)" ::: "memory");
        unsigned long long k2 = (lane < M) ? cbuf[wid][lane] : 0xFFFFFFFFFFFFFFFFull;
        #pragma unroll
        for (int k = 2; k <= 64; k <<= 1)
            #pragma unroll
            for (int j = k >> 1; j > 0; j >>= 1) {
                unsigned long long o = __shfl_xor(k2, j);
                bool keepMin = ((lane & k) == 0) == ((lane & j) == 0);
                bool omin = o < k2;
                if (omin == keepMin) k2 = o;
            }
        if (lane < KNN) op[lane] = (int)(unsigned)(k2 & 0xFFFFFFFFu);
    } else {
        for (int k = 0; k < KNN; ++k) {
            unsigned rv = bu;
            int rc = lane + 64 * bj;
            #pragma unroll
            for (int s = 1; s < 64; s <<= 1) {
                unsigned ov = __shfl_xor(rv, s);
                int oc = __shfl_xor(rc, s);
                if (ov > rv || (ov == rv && oc < rc)) { rv = ov; rc = oc; }
            }
            if (lane == 0) op[k] = rc;
            if ((rc & 63) == lane) {
                int oj = rc >> 6;
                #pragma unroll
                for (int j = 0; j < 32; ++j) if (j == oj) uv[j] = 0u;
                bu = uv[0]; bj = 0;
                #pragma unroll
                for (int j = 1; j < 32; ++j) if (uv[j] > bu) { bu = uv[j]; bj = j; }
            }
        }
    }
}

// ---------- pair GEMM: Y = F*wtA (union buffer), C2 = F*wtD -> xcat slot ----------
template<int CIN, int COUT>
__global__ __launch_bounds__(256) void k_gemm_pair(const float* __restrict__ F, int FS, int b0,
    const float* __restrict__ wtA, const float* __restrict__ wtD,
    float* __restrict__ Y, float* __restrict__ c2x) {
    constexpr int CCH = (CIN >= 32) ? 32 : CIN;
    constexpr int NCH = CIN / CCH;
    __shared__ __align__(16) float Xi[CCH * 64];
    __shared__ __align__(16) float Wa[CCH * 64];
    __shared__ __align__(16) float Wd[CCH * 64];
    int tid = threadIdx.x;
    int r0 = blockIdx.x * 64;
    int c0 = blockIdx.y * 64;
    int b = b0 + r0 / NN;
    int n0 = r0 % NN;
    const float* Fb = F + ((size_t)b * NN + n0) * FS;
    int ty = tid >> 4, tx = tid & 15;
    float accY[4][4] = {}, accD[4][4] = {};
    for (int ch = 0; ch < NCH; ++ch) {
        int cb = ch * CCH;
        if (ch) __syncthreads();
        if constexpr (CCH % 4 == 0) {
            for (int t = tid; t < 64 * (CCH / 4); t += 256) {
                int r = t & 63, cc = t >> 6;
                float v[4];
                *(float4*)v = *(const float4*)(Fb + (size_t)r * FS + cb + 4 * cc);
                #pragma unroll
                for (int u = 0; u < 4; ++u) Xi[(4 * cc + u) * 64 + r] = v[u];
            }
            for (int t = tid; t < CCH * 16; t += 256) {
                int c = t >> 4, q = t & 15;
                *(float4*)&Wa[c * 64 + 4 * q] = *(const float4*)(wtA + (size_t)(cb + c) * COUT + c0 + 4 * q);
                *(float4*)&Wd[c * 64 + 4 * q] = *(const float4*)(wtD + (size_t)(cb + c) * COUT + c0 + 4 * q);
            }
        } else {
            for (int t = tid; t < 64 * CCH; t += 256) {
                int r = t & 63, c = t >> 6;
                Xi[c * 64 + r] = Fb[(size_t)r * FS + cb + c];
            }
            for (int t = tid; t < CCH * 64; t += 256) {
                int col = t & 63, c = t >> 6;
                Wa[c * 64 + col] = wtA[(size_t)(cb + c) * COUT + c0 + col];
                Wd[c * 64 + col] = wtD[(size_t)(cb + c) * COUT + c0 + col];
            }
        }
        __syncthreads();
        for (int c = 0; c < CCH; ++c) {
            float a[4], wa[4], wd[4];
            *(float4*)a  = *(const float4*)&Xi[c * 64 + 4 * ty];
            *(float4*)wa = *(const float4*)&Wa[c * 64 + 4 * tx];
            *(float4*)wd = *(const float4*)&Wd[c * 64 + 4 * tx];
            #pragma unroll
            for (int r = 0; r < 4; ++r)
                #pragma unroll
                for (int s = 0; s < 4; ++s) {
                    accY[r][s] += a[r] * wa[s];
                    accD[r][s] += a[r] * wd[s];
                }
        }
    }
    #pragma unroll
    for (int r = 0; r < 4; ++r) {
        *(float4*)(Y + (size_t)(r0 + 4 * ty + r) * COUT + c0 + 4 * tx) = *(float4*)accY[r];
        *(float4*)(c2x + ((size_t)b0 * NN + r0 + 4 * ty + r) * 512 + c0 + 4 * tx) = *(float4*)accD[r];
    }
}

// ---------- gather-max: io slot holds C2 on entry, final features on exit ----------
template<int COUT>
__global__ __launch_bounds__(256) void k_gather(const float* __restrict__ Y,
    const int* __restrict__ idx, const float* __restrict__ sc, const float* __restrict__ bi,
    float* io, int b0) {
    constexpr int LPP = COUT / 4;
    constexpr int PPW = 64 / LPP;
    constexpr int PPB = 4 * PPW;
    int tid = threadIdx.x;
    int lane = tid & 63, wv = tid >> 6;
    int pl = blockIdx.x * PPB + wv * PPW + lane / LPP;
    int bl = pl / NN, n = pl % NN;
    int o0 = 4 * (lane % LPP);
    float* iop = io + ((size_t)(b0 + bl) * NN + n) * 512 + o0;
    float c2[4], s4[4], b4[4];
    *(float4*)c2 = *(const float4*)iop;
    *(float4*)s4 = *(const float4*)(sc + o0);
    *(float4*)b4 = *(const float4*)(bi + o0);
    const int* ip = idx + ((size_t)(b0 + bl) * NN + n) * KNN;
    const float* Yb = Y + (size_t)bl * NN * COUT;
    float mx[4] = {-FLT_MAX, -FLT_MAX, -FLT_MAX, -FLT_MAX};
    for (int k = 0; k < KNN; ++k) {
        int m = ip[k];
        float y[4];
        *(float4*)y = *(const float4*)(Yb + (size_t)m * COUT + o0);
        #pragma unroll
        for (int u = 0; u < 4; ++u) {
            float v = (y[u] + c2[u]) * s4[u] + b4[u];
            mx[u] = fmaxf(mx[u], leaky(v));
        }
    }
    *(float4*)iop = *(float4*)mx;
}

// ---------- conv5: 128x128 tile, 8x8 micro-tile, fused partial pooling ----------
__global__ __launch_bounds__(256) void k_conv5(const float* __restrict__ xcat,
    const float* __restrict__ w5t, const float* __restrict__ s5, const float* __restrict__ b5,
    float* __restrict__ pmax, float* __restrict__ psum) {
    __shared__ __align__(16) float Xi[32 * 128];
    __shared__ __align__(16) float Wj[32 * 128];
    int tid = threadIdx.x;
    int ty = tid >> 4, tx = tid & 15;
    int wv6 = tid >> 6, lane6 = tid & 63;
    int r0 = blockIdx.x * 128;
    int col0 = blockIdx.y * 128;
    int b = r0 / NN, tileInB = (r0 % NN) / 128;
    const float* Fb = xcat + (size_t)r0 * 512;
    float acc[8][8] = {};
    for (int ch = 0; ch < 16; ++ch) {
        int cb = ch * 32;
        if (ch) __syncthreads();
        for (int t = tid; t < 128 * 8; t += 256) {
            int r = t & 127, cc = t >> 7;
            float v[4];
            *(float4*)v = *(const float4*)(Fb + (size_t)r * 512 + cb + 4 * cc);
            #pragma unroll
            for (int u = 0; u < 4; ++u) Xi[(4 * cc + u) * 128 + r] = v[u];
        }
        #pragma unroll
        for (int i = 0; i < 4; ++i) {
            int basec = wv6 * 8 + i * 2;
            const float* gp = w5t + (size_t)(cb + basec + (lane6 >> 5)) * 1024 + col0 + (lane6 & 31) * 4;
            __builtin_amdgcn_global_load_lds((const __attribute__((address_space(1))) void*)gp,
                (__attribute__((address_space(3))) void*)&Wj[basec * 128], 16, 0, 0);
        }
        __syncthreads();
        for (int c = 0; c < 32; ++c) {
            float a0[4], a1[4], w0[4], w1[4];
            *(float4*)a0 = *(const float4*)&Xi[c * 128 + 4 * ty];
            *(float4*)a1 = *(const float4*)&Xi[c * 128 + 64 + 4 * ty];
            *(float4*)w0 = *(const float4*)&Wj[c * 128 + 4 * tx];
            *(float4*)w1 = *(const float4*)&Wj[c * 128 + 64 + 4 * tx];
            #pragma unroll
            for (int r = 0; r < 4; ++r)
                #pragma unroll
                for (int u = 0; u < 4; ++u) {
                    acc[r][u]         += a0[r] * w0[u];
                    acc[r][4 + u]     += a0[r] * w1[u];
                    acc[4 + r][u]     += a1[r] * w0[u];
                    acc[4 + r][4 + u] += a1[r] * w1[u];
                }
        }
    }
    float hmx[2][4], hsm[2][4];
    #pragma unroll
    for (int h = 0; h < 2; ++h)
        #pragma unroll
        for (int u = 0; u < 4; ++u) { hmx[h][u] = -FLT_MAX; hsm[h][u] = 0.f; }
    #pragma unroll
    for (int h = 0; h < 2; ++h)
        #pragma unroll
        for (int u = 0; u < 4; ++u) {
            int o = col0 + 64 * h + 4 * tx + u;
            float sv = s5[o], bv = b5[o];
            #pragma unroll
            for (int r = 0; r < 8; ++r) {
                float hh = leaky(acc[r][4 * h + u] * sv + bv);
                hmx[h][u] = fmaxf(hmx[h][u], hh);
                hsm[h][u] += hh;
            }
        }
    __syncthreads();
    float* redM = Xi;
    float* redS = Wj;
    #pragma unroll
    for (int h = 0; h < 2; ++h) {
        *(float4*)&redM[ty * 128 + 64 * h + 4 * tx] = *(float4*)hmx[h];
        *(float4*)&redS[ty * 128 + 64 * h + 4 * tx] = *(float4*)hsm[h];
    }
    __syncthreads();
    for (int s = 8; s > 0; s >>= 1) {
        if (ty < s) {
            #pragma unroll
            for (int h = 0; h < 2; ++h) {
                int c = 64 * h + 4 * tx;
                float m0[4], m1[4], s0[4], s1[4];
                *(float4*)m0 = *(float4*)&redM[ty * 128 + c];
                *(float4*)m1 = *(float4*)&redM[(ty + s) * 128 + c];
                *(float4*)s0 = *(float4*)&redS[ty * 128 + c];
                *(float4*)s1 = *(float4*)&redS[(ty + s) * 128 + c];
                #pragma unroll
                for (int u = 0; u < 4; ++u) { m0[u] = fmaxf(m0[u], m1[u]); s0[u] += s1[u]; }
                *(float4*)&redM[ty * 128 + c] = *(float4*)m0;
                *(float4*)&redS[ty * 128 + c] = *(float4*)s0;
            }
        }
        __syncthreads();
    }
    if (ty == 0) {
        #pragma unroll
        for (int h = 0; h < 2; ++h) {
            int c = 64 * h + 4 * tx;
            size_t o = ((size_t)b * 16 + tileInB) * 1024 + col0 + c;
            *(float4*)&pmax[o] = *(float4*)&redM[c];
            *(float4*)&psum[o] = *(float4*)&redS[c];
        }
    }
}

__global__ void k_poolreduce(const float* __restrict__ pmax, const float* __restrict__ psum,
                             float* __restrict__ pooled) {
    int i = blockIdx.x * 256 + threadIdx.x;
    if (i >= BB * 1024) return;
    int b = i / 1024, o = i % 1024;
    float mx = -FLT_MAX, sm = 0.f;
    for (int ch = 0; ch < 16; ++ch) {
        mx = fmaxf(mx, pmax[((size_t)b * 16 + ch) * 1024 + o]);
        sm += psum[((size_t)b * 16 + ch) * 1024 + o];
    }
    pooled[(size_t)b * 2048 + o] = mx;
    pooled[(size_t)b * 2048 + 1024 + o] = sm / (float)NN;
}

// ---------- FC: wave-per-output, coalesced float4 weight reads, shfl reduce ----------
template<int CI, bool SCALE, bool RELU>
__global__ __launch_bounds__(256) void k_fcw(const float* __restrict__ in,
                                             const float* __restrict__ w,
                                             const float* __restrict__ sc,
                                             const float* __restrict__ bi,
                                             float* __restrict__ out, int CO) {
    int wv = (blockIdx.x << 2) + (threadIdx.x >> 6);
    int lane = threadIdx.x & 63;
    int o = wv % CO, b = wv / CO;
    const float* ir = in + (size_t)b * CI;
    const float* wr = w + (size_t)o * CI;
    float acc = 0.f;
    #pragma unroll
    for (int q = 0; q < CI / 256; ++q) {
        int ofs = q * 256 + 4 * lane;
        float4 wv4 = *(const float4*)(wr + ofs);
        float4 iv4 = *(const float4*)(ir + ofs);
        acc += wv4.x * iv4.x + wv4.y * iv4.y + wv4.z * iv4.z + wv4.w * iv4.w;
    }
    #pragma unroll
    for (int s = 1; s < 64; s <<= 1) acc += __shfl_xor(acc, s);
    if (lane == 0) {
        float v = SCALE ? (acc * sc[o] + bi[o]) : (acc + bi[o]);
        if (RELU) v = fmaxf(v, 0.f);
        out[wv] = v;
    }
}

extern "C" void kernel_launch(void* const* d_in, const int* in_sizes, int n_in,
                              void* d_out, int out_size, void* d_ws, size_t ws_size,
                              hipStream_t stream) {
    const float* x    = (const float*)d_in[0];
    const float* w1   = (const float*)d_in[1];
    const float* s1   = (const float*)d_in[2];
    const float* b1   = (const float*)d_in[3];
    const float* w2   = (const float*)d_in[4];
    const float* s2   = (const float*)d_in[5];
    const float* b2   = (const float*)d_in[6];
    const float* w3   = (const float*)d_in[7];
    const float* s3   = (const float*)d_in[8];
    const float* b3   = (const float*)d_in[9];
    const float* w4   = (const float*)d_in[10];
    const float* s4   = (const float*)d_in[11];
    const float* b4   = (const float*)d_in[12];
    const float* w5   = (const float*)d_in[13];
    const float* s5   = (const float*)d_in[14];
    const float* b5   = (const float*)d_in[15];
    const float* fc1w = (const float*)d_in[16];
    const float* s6   = (const float*)d_in[17];
    const float* b6   = (const float*)d_in[18];
    const float* fc2w = (const float*)d_in[19];
    const float* s7   = (const float*)d_in[20];
    const float* b7   = (const float*)d_in[21];
    const float* fc3w = (const float*)d_in[22];
    const float* fc3b = (const float*)d_in[23];
    float* out = (float*)d_out;

    char* ws = (char*)d_ws;
    size_t off = 0;
    auto alloc = [&](size_t bytes) {
        void* p = ws + off;
        off = (off + bytes + 255) & ~(size_t)255;
        return p;
    };
    float* xt   = (float*)alloc((size_t)BB * NN * 3 * 4);
    float* xcat = (float*)alloc((size_t)BB * NN * 512 * 4);
    int*   idx  = (int*)  alloc((size_t)BB * NN * KNN * 4);
    float* xx   = (float*)alloc((size_t)BB * NN * 4);
    float* wtA1 = (float*)alloc(3 * 64 * 4);
    float* wtD1 = (float*)alloc(3 * 64 * 4);
    float* wtA2 = (float*)alloc(64 * 64 * 4);
    float* wtD2 = (float*)alloc(64 * 64 * 4);
    float* wtA3 = (float*)alloc(64 * 128 * 4);
    float* wtD3 = (float*)alloc(64 * 128 * 4);
    float* wtA4 = (float*)alloc(128 * 256 * 4);
    float* wtD4 = (float*)alloc(128 * 256 * 4);
    size_t base_end = off;

    // UNION region: D (dist phase, per-batch chunks) / Y (transform) / head buffers
    const size_t D1 = (size_t)NN * NN * 4;
    size_t avail = ws_size > base_end ? ws_size - base_end : 0;
    int nbD = (int)(avail / D1);
    if (nbD < 1) nbD = 1;
    if (nbD > BB) nbD = BB;
    char* uni = ws + base_end;
    float* D      = (float*)uni;
    float* w5t    = (float*)uni;
    float* pmax   = w5t + 512 * 1024;
    float* psum   = pmax + (size_t)BB * 16 * 1024;
    float* pooled = psum + (size_t)BB * 16 * 1024;
    float* f1     = pooled + (size_t)BB * 2048;
    float* f2     = f1 + (size_t)BB * 512;

    k_transpose_x<<<(BB * NN * 3 + 255) / 256, 256, 0, stream>>>(x, xt);
    k_wpair_all<<<(45248 + 255) / 256, 256, 0, stream>>>(w1, w2, w3, w4,
        wtA1, wtD1, wtA2, wtD2, wtA3, wtD3, wtA4, wtD4);

    // transform + gather helper (Y-only union buffer; C2 straight into xcat)
    auto xform = [&](auto cTag, auto coTag, const float* F, int FS,
                     const float* wtA, const float* wtD,
                     const float* sc, const float* bi, float* outp) {
        constexpr int C  = decltype(cTag)::value;
        constexpr int CO = decltype(coTag)::value;
        size_t ypb = (size_t)NN * CO * 4;
        int nbY = (int)(avail / ypb);
        if (nbY < 1) nbY = 1;
        if (nbY > BB) nbY = BB;
        for (int b0 = 0; b0 < BB; b0 += nbY) {
            int nb = BB - b0 < nbY ? BB - b0 : nbY;
            float* Yc = (float*)uni;
            dim3 g((nb * NN) / 64, CO / 64);
            k_gemm_pair<C, CO><<<g, 256, 0, stream>>>(F, FS, b0, wtA, wtD, Yc, outp);
            constexpr int PPB = 4 * (64 / (CO / 4));
            k_gather<CO><<<(nb * NN) / PPB, 256, 0, stream>>>(Yc, idx, sc, bi, outp, b0);
        }
    };

    // ---- Layer 1 (C=3): fused dist+select, no D buffer ----
    k_xx3<<<(BB * NN + 255) / 256, 256, 0, stream>>>(xt, xx);
    k_select3<<<BB * 512, 256, 0, stream>>>(xt, xx, idx);
    xform(std::integral_constant<int, 3>{}, std::integral_constant<int, 64>{},
          xt, 3, wtA1, wtD1, s1, b1, xcat + 0);

    // ---- Layers 2-4 (C>=64): tiled xx, symmetric dist, threshold select ----
    auto layerBig = [&](auto cTag, auto coTag, const float* F, int FS,
                        const float* wtA, const float* wtD,
                        const float* sc, const float* bi, float* outp) {
        constexpr int C  = decltype(cTag)::value;
        constexpr int CO = decltype(coTag)::value;
        k_xxt<C><<<BB * NN / 64, 256, 0, stream>>>(F, FS, xx);
        for (int b0 = 0; b0 < BB; b0 += nbD) {
            int nb = BB - b0 < nbD ? BB - b0 : nbD;
            k_dist128s<C><<<nb * 136, 256, 0, stream>>>(F, FS, xx, b0, D);
            k_select<<<nb * 512, 256, 0, stream>>>(D, idx, b0);
        }
        xform(cTag, coTag, F, FS, wtA, wtD, sc, bi, outp);
    };

    layerBig(std::integral_constant<int, 64>{},  std::integral_constant<int, 64>{},  xcat + 0,   512, wtA2, wtD2, s2, b2, xcat + 64);
    layerBig(std::integral_constant<int, 64>{},  std::integral_constant<int, 128>{}, xcat + 64,  512, wtA3, wtD3, s3, b3, xcat + 128);
    layerBig(std::integral_constant<int, 128>{}, std::integral_constant<int, 256>{}, xcat + 128, 512, wtA4, wtD4, s4, b4, xcat + 256);

    // head (union region now holds w5t/pmax/psum/pooled/f1/f2)
    dim3 gt(1024 / 64, 512 / 64);
    k_transpose_w_tiled<<<gt, 256, 0, stream>>>(w5, w5t, 1024, 512);
    dim3 g5((BB * NN) / 128, 1024 / 128);
    k_conv5<<<g5, 256, 0, stream>>>(xcat, w5t, s5, b5, pmax, psum);
    k_poolreduce<<<(BB * 1024 + 255) / 256, 256, 0, stream>>>(pmax, psum, pooled);
    k_fcw<2048, true,  true ><<<(BB * 512) / 4, 256, 0, stream>>>(pooled, fc1w, s6, b6, f1, 512);
    k_fcw<512,  true,  true ><<<(BB * 256) / 4, 256, 0, stream>>>(f1, fc2w, s7, b7, f2, 256);
    k_fcw<256,  false, false><<<(BB * 40)  / 4, 256, 0, stream>>>(f2, fc3w, nullptr, fc3b, out, 40);
}

// Round 14
// 676.385 us; speedup vs baseline: 2.3438x; 1.0230x over previous
//
#include <hip/hip_runtime.h>
#include <float.h>
#include <type_traits>

#define BB 8
#define NN 2048
#define KNN 20

__device__ __forceinline__ float leaky(float v) { return fmaxf(v, 0.2f * v); }

// ---------- transpose x (B,3,N) -> xt (B,N,3) ----------
__global__ void k_transpose_x(const float* __restrict__ x, float* __restrict__ xt) {
    int i = blockIdx.x * 256 + threadIdx.x;
    if (i >= BB * NN * 3) return;
    int c = i % 3; int n = (i / 3) % NN; int b = i / (3 * NN);
    xt[i] = x[((size_t)b * 3 + c) * NN + n];
}

// ---------- LDS-tiled transpose w (CO,CI) -> wt (CI,CO), 64x64 tiles ----------
__global__ __launch_bounds__(256) void k_transpose_w_tiled(const float* __restrict__ w,
                                                           float* __restrict__ wt,
                                                           int CO, int CI) {
    __shared__ float tile[64][65];
    int o0 = blockIdx.x * 64;
    int c0 = blockIdx.y * 64;
    int tid = threadIdx.x;
    for (int i = tid; i < 64 * 64; i += 256) {
        int r = i >> 6, c = i & 63;
        tile[r][c] = w[(size_t)(o0 + r) * CI + c0 + c];
    }
    __syncthreads();
    for (int i = tid; i < 64 * 64; i += 256) {
        int cc = i >> 6, oo = i & 63;
        wt[(size_t)(c0 + cc) * CO + o0 + oo] = tile[oo][cc];
    }
}

// ---------- all 4 edgeconv weight splits in ONE dispatch ----------
__device__ __forceinline__ void wpair_one(const float* __restrict__ w, float* __restrict__ wtA,
                                          float* __restrict__ wtD, int CO, int CI, int i) {
    int o = i / CI, c = i % CI;
    float a = w[(size_t)o * 2 * CI + c];
    float bb = w[(size_t)o * 2 * CI + CI + c];
    wtA[c * CO + o] = a;
    wtD[c * CO + o] = bb - a;
}
__global__ void k_wpair_all(const float* w1, const float* w2, const float* w3, const float* w4,
                            float* A1, float* D1, float* A2, float* D2,
                            float* A3, float* D3, float* A4, float* D4) {
    int i = blockIdx.x * 256 + threadIdx.x;
    if (i < 192)            { wpair_one(w1, A1, D1, 64, 3, i); }
    else if (i < 4288)      { wpair_one(w2, A2, D2, 64, 64, i - 192); }
    else if (i < 12480)     { wpair_one(w3, A3, D3, 128, 64, i - 4288); }
    else if (i < 45248)     { wpair_one(w4, A4, D4, 256, 128, i - 12480); }
}

// ---------- distance matrix, big-C: SYMMETRIC 128x128 tiles (136 of 256),
// row-norms computed INLINE from staged LDS (one owner thread per row,
// sequential-c order == old k_xxt exactly). ----------
template<int C>
__global__ __launch_bounds__(256) void k_dist128s(const float* __restrict__ F, int FS,
                                                  int b0, float* __restrict__ D) {
    constexpr int NCH = C / 32;
    __shared__ __align__(16) float Xi[32 * 128];
    __shared__ __align__(16) float Xj[32 * 128];
    __shared__ float sxx[256];   // [0..127]=i-rows, [128..255]=j-rows
    int tid = threadIdx.x;
    int ty = tid >> 4, tx = tid & 15;
    int bl = blockIdx.x / 136;
    int t  = blockIdx.x % 136;
    int it = 0, rem = t;
    while (rem >= 16 - it) { rem -= 16 - it; ++it; }
    int jt = it + rem;
    int i0 = it * 128, j0 = jt * 128;
    int b = b0 + bl;
    const float* Fb = F + (size_t)b * NN * FS;
    float acc[8][8] = {};
    float rn = 0.f;              // owned-row running norm
    const float* ownBase = (tid < 128) ? Xi : Xj;
    int ownR = tid & 127;
    for (int ch = 0; ch < NCH; ++ch) {
        int cb = ch * 32;
        if (ch) __syncthreads();
        for (int k = tid; k < 128 * 8; k += 256) {
            int r = k & 127, cc = k >> 7;
            float vi[4], vj[4];
            *(float4*)vi = *(const float4*)(Fb + (size_t)(i0 + r) * FS + cb + 4 * cc);
            *(float4*)vj = *(const float4*)(Fb + (size_t)(j0 + r) * FS + cb + 4 * cc);
            #pragma unroll
            for (int u = 0; u < 4; ++u) {
                Xi[(4 * cc + u) * 128 + r] = vi[u];
                Xj[(4 * cc + u) * 128 + r] = vj[u];
            }
        }
        __syncthreads();
        // inline row-norm accumulation (sequential c order, exact)
        for (int c = 0; c < 32; ++c) { float v = ownBase[c * 128 + ownR]; rn += v * v; }
        for (int c = 0; c < 32; ++c) {
            float a0[4], a1[4], w0[4], w1[4];
            *(float4*)a0 = *(const float4*)&Xi[c * 128 + 4 * ty];
            *(float4*)a1 = *(const float4*)&Xi[c * 128 + 64 + 4 * ty];
            *(float4*)w0 = *(const float4*)&Xj[c * 128 + 4 * tx];
            *(float4*)w1 = *(const float4*)&Xj[c * 128 + 64 + 4 * tx];
            #pragma unroll
            for (int r = 0; r < 4; ++r)
                #pragma unroll
                for (int s = 0; s < 4; ++s) {
                    acc[r][s]         += a0[r] * w0[s];
                    acc[r][4 + s]     += a0[r] * w1[s];
                    acc[4 + r][s]     += a1[r] * w0[s];
                    acc[4 + r][4 + s] += a1[r] * w1[s];
                }
        }
    }
    sxx[tid] = rn;
    __syncthreads();
    float xxi[8], xxj[8];
    #pragma unroll
    for (int r = 0; r < 4; ++r) {
        xxi[r]     = sxx[4 * ty + r];
        xxi[4 + r] = sxx[64 + 4 * ty + r];
        xxj[r]     = sxx[128 + 4 * tx + r];
        xxj[4 + r] = sxx[128 + 64 + 4 * tx + r];
    }
    float* Dp = D + (size_t)bl * NN * NN;
    #pragma unroll
    for (int r = 0; r < 8; ++r) {
        int row = i0 + (r < 4 ? 4 * ty + r : 64 + 4 * ty + (r - 4));
        float ov0[4], ov1[4];
        #pragma unroll
        for (int s = 0; s < 4; ++s) {
            ov0[s] = 2.f * acc[r][s]     - xxi[r] - xxj[s];
            ov1[s] = 2.f * acc[r][4 + s] - xxi[r] - xxj[4 + s];
        }
        *(float4*)(Dp + (size_t)row * NN + j0 + 4 * tx)      = *(float4*)ov0;
        *(float4*)(Dp + (size_t)row * NN + j0 + 64 + 4 * tx) = *(float4*)ov1;
    }
    if (it != jt) {
        #pragma unroll
        for (int sh = 0; sh < 2; ++sh)
            #pragma unroll
            for (int s = 0; s < 4; ++s) {
                int jrow = j0 + 64 * sh + 4 * tx + s;
                #pragma unroll
                for (int rh = 0; rh < 2; ++rh) {
                    float tv[4];
                    #pragma unroll
                    for (int r = 0; r < 4; ++r)
                        tv[r] = 2.f * acc[4 * rh + r][4 * sh + s] - xxi[4 * rh + r] - xxj[4 * sh + s];
                    *(float4*)(Dp + (size_t)jrow * NN + i0 + 64 * rh + 4 * ty) = *(float4*)tv;
                }
            }
    }
}

// ---------- top-20 selection v2 (D-based, layers 2-4) ----------
__global__ __launch_bounds__(256) void k_select(const float* __restrict__ D,
                                                int* __restrict__ idxo, int b0) {
    __shared__ unsigned long long cbuf[4][64];
    int tid = threadIdx.x;
    int lane = tid & 63, wid = tid >> 6;
    int w = (blockIdx.x << 2) + wid;
    int bl = w / NN, n = w % NN;
    const float* row = D + (size_t)w * NN;
    unsigned uv[32];
    #pragma unroll
    for (int q = 0; q < 8; ++q) {
        float4 f4 = *(const float4*)(row + 4 * lane + 256 * q);
        float fv[4] = {f4.x, f4.y, f4.z, f4.w};
        #pragma unroll
        for (int u = 0; u < 4; ++u) {
            unsigned bb_ = __float_as_uint(fv[u]);
            uv[4 * q + u] = bb_ ^ ((bb_ & 0x80000000u) ? 0xFFFFFFFFu : 0x80000000u);
        }
    }
    unsigned bu = uv[0]; int bj = 0;
    #pragma unroll
    for (int j = 1; j < 32; ++j) if (uv[j] > bu) { bu = uv[j]; bj = j; }
    int bcol = 4 * lane + 256 * (bj >> 2) + (bj & 3);
    unsigned long long key = ((unsigned long long)(~bu) << 32) | (unsigned)bcol;
    #pragma unroll
    for (int k = 2; k <= 64; k <<= 1)
        #pragma unroll
        for (int j = k >> 1; j > 0; j >>= 1) {
            unsigned long long o = __shfl_xor(key, j);
            bool keepMin = ((lane & k) == 0) == ((lane & j) == 0);
            bool omin = o < key;
            if (omin == keepMin) key = o;
        }
    unsigned long long Tkey = __shfl(key, 19);
    unsigned uT = ~(unsigned)(Tkey >> 32);
    int cnt = 0;
    #pragma unroll
    for (int j = 0; j < 32; ++j) cnt += (uv[j] >= uT) ? 1 : 0;
    int M = cnt;
    #pragma unroll
    for (int s = 1; s < 64; s <<= 1) M += __shfl_xor(M, s);
    int* op = idxo + ((size_t)(b0 + bl) * NN + n) * KNN;
    if (M <= 64) {
        int inc = cnt;
        #pragma unroll
        for (int s = 1; s < 64; s <<= 1) {
            int t = __shfl_up(inc, s);
            if (lane >= s) inc += t;
        }
        int p = inc - cnt;
        #pragma unroll
        for (int j = 0; j < 32; ++j) {
            if (uv[j] >= uT) {
                int col = 4 * lane + 256 * (j >> 2) + (j & 3);
                cbuf[wid][p++] = ((unsigned long long)(~uv[j]) << 32) | (unsigned)col;
            }
        }
        asm volatile("s_waitcnt lgkmcnt(0)" ::: "memory");
        unsigned long long k2 = (lane < M) ? cbuf[wid][lane] : 0xFFFFFFFFFFFFFFFFull;
        #pragma unroll
        for (int k = 2; k <= 64; k <<= 1)
            #pragma unroll
            for (int j = k >> 1; j > 0; j >>= 1) {
                unsigned long long o = __shfl_xor(k2, j);
                bool keepMin = ((lane & k) == 0) == ((lane & j) == 0);
                bool omin = o < k2;
                if (omin == keepMin) k2 = o;
            }
        if (lane < KNN) op[lane] = (int)(unsigned)(k2 & 0xFFFFFFFFu);
    } else {
        for (int k = 0; k < KNN; ++k) {
            unsigned rv = bu;
            int rc = 4 * lane + 256 * (bj >> 2) + (bj & 3);
            #pragma unroll
            for (int s = 1; s < 64; s <<= 1) {
                unsigned ov = __shfl_xor(rv, s);
                int oc = __shfl_xor(rc, s);
                if (ov > rv || (ov == rv && oc < rc)) { rv = ov; rc = oc; }
            }
            if (lane == 0) op[k] = rc;
            if (((rc >> 2) & 63) == lane) {
                int oj = ((rc >> 8) << 2) | (rc & 3);
                #pragma unroll
                for (int j = 0; j < 32; ++j) if (j == oj) uv[j] = 0u;
                bu = uv[0]; bj = 0;
                #pragma unroll
                for (int j = 1; j < 32; ++j) if (uv[j] > bu) { bu = uv[j]; bj = j; }
            }
        }
    }
}

// ---------- fused C=3 KNN: coords + inline norms staged in LDS, threshold select ----------
__global__ __launch_bounds__(256) void k_select3(const float* __restrict__ xt,
                                                 int* __restrict__ idxo) {
    __shared__ float xs[NN], ys[NN], zs[NN], xxs[NN];
    __shared__ unsigned long long cbuf[4][64];
    int tid = threadIdx.x;
    int lane = tid & 63, wid = tid >> 6;
    int b = blockIdx.x >> 9;
    int n = (blockIdx.x & 511) * 4 + wid;
    const float* Fb = xt + (size_t)b * NN * 3;
    for (int t = tid; t < NN; t += 256) {
        float xv = Fb[3 * t], yv = Fb[3 * t + 1], zv = Fb[3 * t + 2];
        xs[t] = xv; ys[t] = yv; zs[t] = zv;
        float s = 0.f; s += xv * xv; s += yv * yv; s += zv * zv;
        xxs[t] = s;
    }
    __syncthreads();
    float qx = xs[n], qy = ys[n], qz = zs[n], xxn = xxs[n];
    unsigned uv[32];
    #pragma unroll
    for (int j = 0; j < 32; ++j) {
        int m = lane + 64 * j;
        float dot = qx * xs[m];
        dot = fmaf(qy, ys[m], dot);
        dot = fmaf(qz, zs[m], dot);
        float d = 2.f * dot - xxn - xxs[m];
        unsigned bb_ = __float_as_uint(d);
        uv[j] = bb_ ^ ((bb_ & 0x80000000u) ? 0xFFFFFFFFu : 0x80000000u);
    }
    unsigned bu = uv[0]; int bj = 0;
    #pragma unroll
    for (int j = 1; j < 32; ++j) if (uv[j] > bu) { bu = uv[j]; bj = j; }
    int bcol = lane + 64 * bj;
    unsigned long long key = ((unsigned long long)(~bu) << 32) | (unsigned)bcol;
    #pragma unroll
    for (int k = 2; k <= 64; k <<= 1)
        #pragma unroll
        for (int j = k >> 1; j > 0; j >>= 1) {
            unsigned long long o = __shfl_xor(key, j);
            bool keepMin = ((lane & k) == 0) == ((lane & j) == 0);
            bool omin = o < key;
            if (omin == keepMin) key = o;
        }
    unsigned long long Tkey = __shfl(key, 19);
    unsigned uT = ~(unsigned)(Tkey >> 32);
    int cnt = 0;
    #pragma unroll
    for (int j = 0; j < 32; ++j) cnt += (uv[j] >= uT) ? 1 : 0;
    int M = cnt;
    #pragma unroll
    for (int s = 1; s < 64; s <<= 1) M += __shfl_xor(M, s);
    int* op = idxo + ((size_t)b * NN + n) * KNN;
    if (M <= 64) {
        int inc = cnt;
        #pragma unroll
        for (int s = 1; s < 64; s <<= 1) {
            int t = __shfl_up(inc, s);
            if (lane >= s) inc += t;
        }
        int p = inc - cnt;
        #pragma unroll
        for (int j = 0; j < 32; ++j) {
            if (uv[j] >= uT) {
                int col = lane + 64 * j;
                cbuf[wid][p++] = ((unsigned long long)(~uv[j]) << 32) | (unsigned)col;
            }
        }
        asm volatile("s_waitcnt lgkmcnt(0)" ::: "memory");
        unsigned long long k2 = (lane < M) ? cbuf[wid][lane] : 0xFFFFFFFFFFFFFFFFull;
        #pragma unroll
        for (int k = 2; k <= 64; k <<= 1)
            #pragma unroll
            for (int j = k >> 1; j > 0; j >>= 1) {
                unsigned long long o = __shfl_xor(k2, j);
                bool keepMin = ((lane & k) == 0) == ((lane & j) == 0);
                bool omin = o < k2;
                if (omin == keepMin) k2 = o;
            }
        if (lane < KNN) op[lane] = (int)(unsigned)(k2 & 0xFFFFFFFFu);
    } else {
        for (int k = 0; k < KNN; ++k) {
            unsigned rv = bu;
            int rc = lane + 64 * bj;
            #pragma unroll
            for (int s = 1; s < 64; s <<= 1) {
                unsigned ov = __shfl_xor(rv, s);
                int oc = __shfl_xor(rc, s);
                if (ov > rv || (ov == rv && oc < rc)) { rv = ov; rc = oc; }
            }
            if (lane == 0) op[k] = rc;
            if ((rc & 63) == lane) {
                int oj = rc >> 6;
                #pragma unroll
                for (int j = 0; j < 32; ++j) if (j == oj) uv[j] = 0u;
                bu = uv[0]; bj = 0;
                #pragma unroll
                for (int j = 1; j < 32; ++j) if (uv[j] > bu) { bu = uv[j]; bj = j; }
            }
        }
    }
}

// ---------- pair GEMM: Y = F*wtA (union buffer), C2 = F*wtD -> xcat slot ----------
template<int CIN, int COUT>
__global__ __launch_bounds__(256) void k_gemm_pair(const float* __restrict__ F, int FS, int b0,
    const float* __restrict__ wtA, const float* __restrict__ wtD,
    float* __restrict__ Y, float* __restrict__ c2x) {
    constexpr int CCH = (CIN >= 32) ? 32 : CIN;
    constexpr int NCH = CIN / CCH;
    __shared__ __align__(16) float Xi[CCH * 64];
    __shared__ __align__(16) float Wa[CCH * 64];
    __shared__ __align__(16) float Wd[CCH * 64];
    int tid = threadIdx.x;
    int r0 = blockIdx.x * 64;
    int c0 = blockIdx.y * 64;
    int b = b0 + r0 / NN;
    int n0 = r0 % NN;
    const float* Fb = F + ((size_t)b * NN + n0) * FS;
    int ty = tid >> 4, tx = tid & 15;
    float accY[4][4] = {}, accD[4][4] = {};
    for (int ch = 0; ch < NCH; ++ch) {
        int cb = ch * CCH;
        if (ch) __syncthreads();
        if constexpr (CCH % 4 == 0) {
            for (int t = tid; t < 64 * (CCH / 4); t += 256) {
                int r = t & 63, cc = t >> 6;
                float v[4];
                *(float4*)v = *(const float4*)(Fb + (size_t)r * FS + cb + 4 * cc);
                #pragma unroll
                for (int u = 0; u < 4; ++u) Xi[(4 * cc + u) * 64 + r] = v[u];
            }
            for (int t = tid; t < CCH * 16; t += 256) {
                int c = t >> 4, q = t & 15;
                *(float4*)&Wa[c * 64 + 4 * q] = *(const float4*)(wtA + (size_t)(cb + c) * COUT + c0 + 4 * q);
                *(float4*)&Wd[c * 64 + 4 * q] = *(const float4*)(wtD + (size_t)(cb + c) * COUT + c0 + 4 * q);
            }
        } else {
            for (int t = tid; t < 64 * CCH; t += 256) {
                int r = t & 63, c = t >> 6;
                Xi[c * 64 + r] = Fb[(size_t)r * FS + cb + c];
            }
            for (int t = tid; t < CCH * 64; t += 256) {
                int col = t & 63, c = t >> 6;
                Wa[c * 64 + col] = wtA[(size_t)(cb + c) * COUT + c0 + col];
                Wd[c * 64 + col] = wtD[(size_t)(cb + c) * COUT + c0 + col];
            }
        }
        __syncthreads();
        for (int c = 0; c < CCH; ++c) {
            float a[4], wa[4], wd[4];
            *(float4*)a  = *(const float4*)&Xi[c * 64 + 4 * ty];
            *(float4*)wa = *(const float4*)&Wa[c * 64 + 4 * tx];
            *(float4*)wd = *(const float4*)&Wd[c * 64 + 4 * tx];
            #pragma unroll
            for (int r = 0; r < 4; ++r)
                #pragma unroll
                for (int s = 0; s < 4; ++s) {
                    accY[r][s] += a[r] * wa[s];
                    accD[r][s] += a[r] * wd[s];
                }
        }
    }
    #pragma unroll
    for (int r = 0; r < 4; ++r) {
        *(float4*)(Y + (size_t)(r0 + 4 * ty + r) * COUT + c0 + 4 * tx) = *(float4*)accY[r];
        *(float4*)(c2x + ((size_t)b0 * NN + r0 + 4 * ty + r) * 512 + c0 + 4 * tx) = *(float4*)accD[r];
    }
}

// ---------- gather-max: io slot holds C2 on entry, final features on exit ----------
template<int COUT>
__global__ __launch_bounds__(256) void k_gather(const float* __restrict__ Y,
    const int* __restrict__ idx, const float* __restrict__ sc, const float* __restrict__ bi,
    float* io, int b0) {
    constexpr int LPP = COUT / 4;
    constexpr int PPW = 64 / LPP;
    constexpr int PPB = 4 * PPW;
    int tid = threadIdx.x;
    int lane = tid & 63, wv = tid >> 6;
    int pl = blockIdx.x * PPB + wv * PPW + lane / LPP;
    int bl = pl / NN, n = pl % NN;
    int o0 = 4 * (lane % LPP);
    float* iop = io + ((size_t)(b0 + bl) * NN + n) * 512 + o0;
    float c2[4], s4[4], b4[4];
    *(float4*)c2 = *(const float4*)iop;
    *(float4*)s4 = *(const float4*)(sc + o0);
    *(float4*)b4 = *(const float4*)(bi + o0);
    const int* ip = idx + ((size_t)(b0 + bl) * NN + n) * KNN;
    const float* Yb = Y + (size_t)bl * NN * COUT;
    float mx[4] = {-FLT_MAX, -FLT_MAX, -FLT_MAX, -FLT_MAX};
    for (int k = 0; k < KNN; ++k) {
        int m = ip[k];
        float y[4];
        *(float4*)y = *(const float4*)(Yb + (size_t)m * COUT + o0);
        #pragma unroll
        for (int u = 0; u < 4; ++u) {
            float v = (y[u] + c2[u]) * s4[u] + b4[u];
            mx[u] = fmaxf(mx[u], leaky(v));
        }
    }
    *(float4*)iop = *(float4*)mx;
}

// ---------- conv5 v2: 128x128 tile, Wj double-buffered (async glob_lds
// prefetched one ch ahead), Xi reg-prefetched (T14 split). ----------
__global__ __launch_bounds__(256) void k_conv5(const float* __restrict__ xcat,
    const float* __restrict__ w5t, const float* __restrict__ s5, const float* __restrict__ b5,
    float* __restrict__ pmax, float* __restrict__ psum) {
    __shared__ __align__(16) float Xi[32 * 128];        // 16KB
    __shared__ __align__(16) float Wj[2][32 * 128];     // 32KB
    int tid = threadIdx.x;
    int ty = tid >> 4, tx = tid & 15;
    int wv6 = tid >> 6, lane6 = tid & 63;
    int r0 = blockIdx.x * 128;
    int col0 = blockIdx.y * 128;
    int b = r0 / NN, tileInB = (r0 % NN) / 128;
    const float* Fb = xcat + (size_t)r0 * 512;
    float acc[8][8] = {};
    // per-thread Xi quads: t_i = tid + 256*i -> (r, cc)
    int xr_r[4], xr_c[4];
    #pragma unroll
    for (int i = 0; i < 4; ++i) { int t = tid + 256 * i; xr_r[i] = t & 127; xr_c[i] = t >> 7; }
    auto issueWj = [&](int buf, int cb) {
        #pragma unroll
        for (int i = 0; i < 4; ++i) {
            int basec = wv6 * 8 + i * 2;
            const float* gp = w5t + (size_t)(cb + basec + (lane6 >> 5)) * 1024 + col0 + (lane6 & 31) * 4;
            __builtin_amdgcn_global_load_lds((const __attribute__((address_space(1))) void*)gp,
                (__attribute__((address_space(3))) void*)&Wj[buf][basec * 128], 16, 0, 0);
        }
    };
    float4 xr[4];
    // prologue: load Xi(0) regs -> LDS, issue Wj(0)
    #pragma unroll
    for (int i = 0; i < 4; ++i)
        xr[i] = *(const float4*)(Fb + (size_t)xr_r[i] * 512 + 4 * xr_c[i]);
    issueWj(0, 0);
    #pragma unroll
    for (int i = 0; i < 4; ++i) {
        float v[4]; *(float4*)v = xr[i];
        #pragma unroll
        for (int u = 0; u < 4; ++u) Xi[(4 * xr_c[i] + u) * 128 + xr_r[i]] = v[u];
    }
    __syncthreads();
    for (int ch = 0; ch < 16; ++ch) {
        int nxt = ch + 1;
        if (nxt < 16) {
            issueWj(nxt & 1, nxt * 32);
            #pragma unroll
            for (int i = 0; i < 4; ++i)
                xr[i] = *(const float4*)(Fb + (size_t)xr_r[i] * 512 + nxt * 32 + 4 * xr_c[i]);
        }
        const float* Wc = Wj[ch & 1];
        for (int c = 0; c < 32; ++c) {
            float a0[4], a1[4], w0[4], w1[4];
            *(float4*)a0 = *(const float4*)&Xi[c * 128 + 4 * ty];
            *(float4*)a1 = *(const float4*)&Xi[c * 128 + 64 + 4 * ty];
            *(float4*)w0 = *(const float4*)&Wc[c * 128 + 4 * tx];
            *(float4*)w1 = *(const float4*)&Wc[c * 128 + 64 + 4 * tx];
            #pragma unroll
            for (int r = 0; r < 4; ++r)
                #pragma unroll
                for (int u = 0; u < 4; ++u) {
                    acc[r][u]         += a0[r] * w0[u];
                    acc[r][4 + u]     += a0[r] * w1[u];
                    acc[4 + r][u]     += a1[r] * w0[u];
                    acc[4 + r][4 + u] += a1[r] * w1[u];
                }
        }
        __syncthreads();            // Xi reads done; Wj(nxt) drained here too
        if (nxt < 16) {
            #pragma unroll
            for (int i = 0; i < 4; ++i) {
                float v[4]; *(float4*)v = xr[i];
                #pragma unroll
                for (int u = 0; u < 4; ++u) Xi[(4 * xr_c[i] + u) * 128 + xr_r[i]] = v[u];
            }
            __syncthreads();        // Xi(nxt) ready
        }
    }
    float hmx[2][4], hsm[2][4];
    #pragma unroll
    for (int h = 0; h < 2; ++h)
        #pragma unroll
        for (int u = 0; u < 4; ++u) { hmx[h][u] = -FLT_MAX; hsm[h][u] = 0.f; }
    #pragma unroll
    for (int h = 0; h < 2; ++h)
        #pragma unroll
        for (int u = 0; u < 4; ++u) {
            int o = col0 + 64 * h + 4 * tx + u;
            float sv = s5[o], bv = b5[o];
            #pragma unroll
            for (int r = 0; r < 8; ++r) {
                float hh = leaky(acc[r][4 * h + u] * sv + bv);
                hmx[h][u] = fmaxf(hmx[h][u], hh);
                hsm[h][u] += hh;
            }
        }
    __syncthreads();
    float* redM = Xi;
    float* redS = Wj[0];
    #pragma unroll
    for (int h = 0; h < 2; ++h) {
        *(float4*)&redM[ty * 128 + 64 * h + 4 * tx] = *(float4*)hmx[h];
        *(float4*)&redS[ty * 128 + 64 * h + 4 * tx] = *(float4*)hsm[h];
    }
    __syncthreads();
    for (int s = 8; s > 0; s >>= 1) {
        if (ty < s) {
            #pragma unroll
            for (int h = 0; h < 2; ++h) {
                int c = 64 * h + 4 * tx;
                float m0[4], m1[4], s0[4], s1[4];
                *(float4*)m0 = *(float4*)&redM[ty * 128 + c];
                *(float4*)m1 = *(float4*)&redM[(ty + s) * 128 + c];
                *(float4*)s0 = *(float4*)&redS[ty * 128 + c];
                *(float4*)s1 = *(float4*)&redS[(ty + s) * 128 + c];
                #pragma unroll
                for (int u = 0; u < 4; ++u) { m0[u] = fmaxf(m0[u], m1[u]); s0[u] += s1[u]; }
                *(float4*)&redM[ty * 128 + c] = *(float4*)m0;
                *(float4*)&redS[ty * 128 + c] = *(float4*)s0;
            }
        }
        __syncthreads();
    }
    if (ty == 0) {
        #pragma unroll
        for (int h = 0; h < 2; ++h) {
            int c = 64 * h + 4 * tx;
            size_t o = ((size_t)b * 16 + tileInB) * 1024 + col0 + c;
            *(float4*)&pmax[o] = *(float4*)&redM[c];
            *(float4*)&psum[o] = *(float4*)&redS[c];
        }
    }
}

__global__ void k_poolreduce(const float* __restrict__ pmax, const float* __restrict__ psum,
                             float* __restrict__ pooled) {
    int i = blockIdx.x * 256 + threadIdx.x;
    if (i >= BB * 1024) return;
    int b = i / 1024, o = i % 1024;
    float mx = -FLT_MAX, sm = 0.f;
    for (int ch = 0; ch < 16; ++ch) {
        mx = fmaxf(mx, pmax[((size_t)b * 16 + ch) * 1024 + o]);
        sm += psum[((size_t)b * 16 + ch) * 1024 + o];
    }
    pooled[(size_t)b * 2048 + o] = mx;
    pooled[(size_t)b * 2048 + 1024 + o] = sm / (float)NN;
}

// ---------- FC: wave-per-output, coalesced float4 weight reads, shfl reduce ----------
template<int CI, bool SCALE, bool RELU>
__global__ __launch_bounds__(256) void k_fcw(const float* __restrict__ in,
                                             const float* __restrict__ w,
                                             const float* __restrict__ sc,
                                             const float* __restrict__ bi,
                                             float* __restrict__ out, int CO) {
    int wv = (blockIdx.x << 2) + (threadIdx.x >> 6);
    int lane = threadIdx.x & 63;
    int o = wv % CO, b = wv / CO;
    const float* ir = in + (size_t)b * CI;
    const float* wr = w + (size_t)o * CI;
    float acc = 0.f;
    #pragma unroll
    for (int q = 0; q < CI / 256; ++q) {
        int ofs = q * 256 + 4 * lane;
        float4 wv4 = *(const float4*)(wr + ofs);
        float4 iv4 = *(const float4*)(ir + ofs);
        acc += wv4.x * iv4.x + wv4.y * iv4.y + wv4.z * iv4.z + wv4.w * iv4.w;
    }
    #pragma unroll
    for (int s = 1; s < 64; s <<= 1) acc += __shfl_xor(acc, s);
    if (lane == 0) {
        float v = SCALE ? (acc * sc[o] + bi[o]) : (acc + bi[o]);
        if (RELU) v = fmaxf(v, 0.f);
        out[wv] = v;
    }
}

extern "C" void kernel_launch(void* const* d_in, const int* in_sizes, int n_in,
                              void* d_out, int out_size, void* d_ws, size_t ws_size,
                              hipStream_t stream) {
    const float* x    = (const float*)d_in[0];
    const float* w1   = (const float*)d_in[1];
    const float* s1   = (const float*)d_in[2];
    const float* b1   = (const float*)d_in[3];
    const float* w2   = (const float*)d_in[4];
    const float* s2   = (const float*)d_in[5];
    const float* b2   = (const float*)d_in[6];
    const float* w3   = (const float*)d_in[7];
    const float* s3   = (const float*)d_in[8];
    const float* b3   = (const float*)d_in[9];
    const float* w4   = (const float*)d_in[10];
    const float* s4   = (const float*)d_in[11];
    const float* b4   = (const float*)d_in[12];
    const float* w5   = (const float*)d_in[13];
    const float* s5   = (const float*)d_in[14];
    const float* b5   = (const float*)d_in[15];
    const float* fc1w = (const float*)d_in[16];
    const float* s6   = (const float*)d_in[17];
    const float* b6   = (const float*)d_in[18];
    const float* fc2w = (const float*)d_in[19];
    const float* s7   = (const float*)d_in[20];
    const float* b7   = (const float*)d_in[21];
    const float* fc3w = (const float*)d_in[22];
    const float* fc3b = (const float*)d_in[23];
    float* out = (float*)d_out;

    char* ws = (char*)d_ws;
    size_t off = 0;
    auto alloc = [&](size_t bytes) {
        void* p = ws + off;
        off = (off + bytes + 255) & ~(size_t)255;
        return p;
    };
    float* xt   = (float*)alloc((size_t)BB * NN * 3 * 4);
    float* xcat = (float*)alloc((size_t)BB * NN * 512 * 4);
    int*   idx  = (int*)  alloc((size_t)BB * NN * KNN * 4);
    float* wtA1 = (float*)alloc(3 * 64 * 4);
    float* wtD1 = (float*)alloc(3 * 64 * 4);
    float* wtA2 = (float*)alloc(64 * 64 * 4);
    float* wtD2 = (float*)alloc(64 * 64 * 4);
    float* wtA3 = (float*)alloc(64 * 128 * 4);
    float* wtD3 = (float*)alloc(64 * 128 * 4);
    float* wtA4 = (float*)alloc(128 * 256 * 4);
    float* wtD4 = (float*)alloc(128 * 256 * 4);
    size_t base_end = off;

    // UNION region: D (dist phase, per-batch chunks) / Y (transform) / head buffers
    const size_t D1 = (size_t)NN * NN * 4;
    size_t avail = ws_size > base_end ? ws_size - base_end : 0;
    int nbD = (int)(avail / D1);
    if (nbD < 1) nbD = 1;
    if (nbD > BB) nbD = BB;
    char* uni = ws + base_end;
    float* D      = (float*)uni;
    float* w5t    = (float*)uni;
    float* pmax   = w5t + 512 * 1024;
    float* psum   = pmax + (size_t)BB * 16 * 1024;
    float* pooled = psum + (size_t)BB * 16 * 1024;
    float* f1     = pooled + (size_t)BB * 2048;
    float* f2     = f1 + (size_t)BB * 512;

    k_transpose_x<<<(BB * NN * 3 + 255) / 256, 256, 0, stream>>>(x, xt);
    k_wpair_all<<<(45248 + 255) / 256, 256, 0, stream>>>(w1, w2, w3, w4,
        wtA1, wtD1, wtA2, wtD2, wtA3, wtD3, wtA4, wtD4);

    // transform + gather helper (Y-only union buffer; C2 straight into xcat)
    auto xform = [&](auto cTag, auto coTag, const float* F, int FS,
                     const float* wtA, const float* wtD,
                     const float* sc, const float* bi, float* outp) {
        constexpr int C  = decltype(cTag)::value;
        constexpr int CO = decltype(coTag)::value;
        size_t ypb = (size_t)NN * CO * 4;
        int nbY = (int)(avail / ypb);
        if (nbY < 1) nbY = 1;
        if (nbY > BB) nbY = BB;
        for (int b0 = 0; b0 < BB; b0 += nbY) {
            int nb = BB - b0 < nbY ? BB - b0 : nbY;
            float* Yc = (float*)uni;
            dim3 g((nb * NN) / 64, CO / 64);
            k_gemm_pair<C, CO><<<g, 256, 0, stream>>>(F, FS, b0, wtA, wtD, Yc, outp);
            constexpr int PPB = 4 * (64 / (CO / 4));
            k_gather<CO><<<(nb * NN) / PPB, 256, 0, stream>>>(Yc, idx, sc, bi, outp, b0);
        }
    };

    // ---- Layer 1 (C=3): fused dist+select (inline norms), no D buffer ----
    k_select3<<<BB * 512, 256, 0, stream>>>(xt, idx);
    xform(std::integral_constant<int, 3>{}, std::integral_constant<int, 64>{},
          xt, 3, wtA1, wtD1, s1, b1, xcat + 0);

    // ---- Layers 2-4 (C>=64): symmetric dist w/ inline norms, threshold select ----
    auto layerBig = [&](auto cTag, auto coTag, const float* F, int FS,
                        const float* wtA, const float* wtD,
                        const float* sc, const float* bi, float* outp) {
        constexpr int C  = decltype(cTag)::value;
        for (int b0 = 0; b0 < BB; b0 += nbD) {
            int nb = BB - b0 < nbD ? BB - b0 : nbD;
            k_dist128s<C><<<nb * 136, 256, 0, stream>>>(F, FS, b0, D);
            k_select<<<nb * 512, 256, 0, stream>>>(D, idx, b0);
        }
        xform(cTag, coTag, F, FS, wtA, wtD, sc, bi, outp);
    };

    layerBig(std::integral_constant<int, 64>{},  std::integral_constant<int, 64>{},  xcat + 0,   512, wtA2, wtD2, s2, b2, xcat + 64);
    layerBig(std::integral_constant<int, 64>{},  std::integral_constant<int, 128>{}, xcat + 64,  512, wtA3, wtD3, s3, b3, xcat + 128);
    layerBig(std::integral_constant<int, 128>{}, std::integral_constant<int, 256>{}, xcat + 128, 512, wtA4, wtD4, s4, b4, xcat + 256);

    // head (union region now holds w5t/pmax/psum/pooled/f1/f2)
    dim3 gt(1024 / 64, 512 / 64);
    k_transpose_w_tiled<<<gt, 256, 0, stream>>>(w5, w5t, 1024, 512);
    dim3 g5((BB * NN) / 128, 1024 / 128);
    k_conv5<<<g5, 256, 0, stream>>>(xcat, w5t, s5, b5, pmax, psum);
    k_poolreduce<<<(BB * 1024 + 255) / 256, 256, 0, stream>>>(pmax, psum, pooled);
    k_fcw<2048, true,  true ><<<(BB * 512) / 4, 256, 0, stream>>>(pooled, fc1w, s6, b6, f1, 512);
    k_fcw<512,  true,  true ><<<(BB * 256) / 4, 256, 0, stream>>>(f1, fc2w, s7, b7, f2, 256);
    k_fcw<256,  false, false><<<(BB * 40)  / 4, 256, 0, stream>>>(f2, fc3w, nullptr, fc3b, out, 40);
}

// Round 15
// 658.282 us; speedup vs baseline: 2.4082x; 1.0275x over previous
//
#include <hip/hip_runtime.h>
#include <float.h>
#include <type_traits>

#define BB 8
#define NN 2048
#define KNN 20

__device__ __forceinline__ float leaky(float v) { return fmaxf(v, 0.2f * v); }

// ---------- LDS-tiled transpose w (CO,CI) -> wt (CI,CO), 64x64 tiles ----------
__global__ __launch_bounds__(256) void k_transpose_w_tiled(const float* __restrict__ w,
                                                           float* __restrict__ wt,
                                                           int CO, int CI) {
    __shared__ float tile[64][65];
    int o0 = blockIdx.x * 64;
    int c0 = blockIdx.y * 64;
    int tid = threadIdx.x;
    for (int i = tid; i < 64 * 64; i += 256) {
        int r = i >> 6, c = i & 63;
        tile[r][c] = w[(size_t)(o0 + r) * CI + c0 + c];
    }
    __syncthreads();
    for (int i = tid; i < 64 * 64; i += 256) {
        int cc = i >> 6, oo = i & 63;
        wt[(size_t)(c0 + cc) * CO + o0 + oo] = tile[oo][cc];
    }
}

// ---------- all 4 edgeconv weight splits in ONE dispatch ----------
__device__ __forceinline__ void wpair_one(const float* __restrict__ w, float* __restrict__ wtA,
                                          float* __restrict__ wtD, int CO, int CI, int i) {
    int o = i / CI, c = i % CI;
    float a = w[(size_t)o * 2 * CI + c];
    float bb = w[(size_t)o * 2 * CI + CI + c];
    wtA[c * CO + o] = a;
    wtD[c * CO + o] = bb - a;
}
__global__ void k_wpair_all(const float* w1, const float* w2, const float* w3, const float* w4,
                            float* A1, float* D1, float* A2, float* D2,
                            float* A3, float* D3, float* A4, float* D4) {
    int i = blockIdx.x * 256 + threadIdx.x;
    if (i < 192)            { wpair_one(w1, A1, D1, 64, 3, i); }
    else if (i < 4288)      { wpair_one(w2, A2, D2, 64, 64, i - 192); }
    else if (i < 12480)     { wpair_one(w3, A3, D3, 128, 64, i - 4288); }
    else if (i < 45248)     { wpair_one(w4, A4, D4, 256, 128, i - 12480); }
}

// ---------- distance matrix, big-C: SYMMETRIC 128x128 tiles (136 of 256),
// row-norms computed INLINE from staged LDS ----------
template<int C>
__global__ __launch_bounds__(256) void k_dist128s(const float* __restrict__ F, int FS,
                                                  int b0, float* __restrict__ D) {
    constexpr int NCH = C / 32;
    __shared__ __align__(16) float Xi[32 * 128];
    __shared__ __align__(16) float Xj[32 * 128];
    __shared__ float sxx[256];
    int tid = threadIdx.x;
    int ty = tid >> 4, tx = tid & 15;
    int bl = blockIdx.x / 136;
    int t  = blockIdx.x % 136;
    int it = 0, rem = t;
    while (rem >= 16 - it) { rem -= 16 - it; ++it; }
    int jt = it + rem;
    int i0 = it * 128, j0 = jt * 128;
    int b = b0 + bl;
    const float* Fb = F + (size_t)b * NN * FS;
    float acc[8][8] = {};
    float rn = 0.f;
    const float* ownBase = (tid < 128) ? Xi : Xj;
    int ownR = tid & 127;
    for (int ch = 0; ch < NCH; ++ch) {
        int cb = ch * 32;
        if (ch) __syncthreads();
        for (int k = tid; k < 128 * 8; k += 256) {
            int r = k & 127, cc = k >> 7;
            float vi[4], vj[4];
            *(float4*)vi = *(const float4*)(Fb + (size_t)(i0 + r) * FS + cb + 4 * cc);
            *(float4*)vj = *(const float4*)(Fb + (size_t)(j0 + r) * FS + cb + 4 * cc);
            #pragma unroll
            for (int u = 0; u < 4; ++u) {
                Xi[(4 * cc + u) * 128 + r] = vi[u];
                Xj[(4 * cc + u) * 128 + r] = vj[u];
            }
        }
        __syncthreads();
        for (int c = 0; c < 32; ++c) { float v = ownBase[c * 128 + ownR]; rn += v * v; }
        for (int c = 0; c < 32; ++c) {
            float a0[4], a1[4], w0[4], w1[4];
            *(float4*)a0 = *(const float4*)&Xi[c * 128 + 4 * ty];
            *(float4*)a1 = *(const float4*)&Xi[c * 128 + 64 + 4 * ty];
            *(float4*)w0 = *(const float4*)&Xj[c * 128 + 4 * tx];
            *(float4*)w1 = *(const float4*)&Xj[c * 128 + 64 + 4 * tx];
            #pragma unroll
            for (int r = 0; r < 4; ++r)
                #pragma unroll
                for (int s = 0; s < 4; ++s) {
                    acc[r][s]         += a0[r] * w0[s];
                    acc[r][4 + s]     += a0[r] * w1[s];
                    acc[4 + r][s]     += a1[r] * w0[s];
                    acc[4 + r][4 + s] += a1[r] * w1[s];
                }
        }
    }
    sxx[tid] = rn;
    __syncthreads();
    float xxi[8], xxj[8];
    #pragma unroll
    for (int r = 0; r < 4; ++r) {
        xxi[r]     = sxx[4 * ty + r];
        xxi[4 + r] = sxx[64 + 4 * ty + r];
        xxj[r]     = sxx[128 + 4 * tx + r];
        xxj[4 + r] = sxx[128 + 64 + 4 * tx + r];
    }
    float* Dp = D + (size_t)bl * NN * NN;
    #pragma unroll
    for (int r = 0; r < 8; ++r) {
        int row = i0 + (r < 4 ? 4 * ty + r : 64 + 4 * ty + (r - 4));
        float ov0[4], ov1[4];
        #pragma unroll
        for (int s = 0; s < 4; ++s) {
            ov0[s] = 2.f * acc[r][s]     - xxi[r] - xxj[s];
            ov1[s] = 2.f * acc[r][4 + s] - xxi[r] - xxj[4 + s];
        }
        *(float4*)(Dp + (size_t)row * NN + j0 + 4 * tx)      = *(float4*)ov0;
        *(float4*)(Dp + (size_t)row * NN + j0 + 64 + 4 * tx) = *(float4*)ov1;
    }
    if (it != jt) {
        #pragma unroll
        for (int sh = 0; sh < 2; ++sh)
            #pragma unroll
            for (int s = 0; s < 4; ++s) {
                int jrow = j0 + 64 * sh + 4 * tx + s;
                #pragma unroll
                for (int rh = 0; rh < 2; ++rh) {
                    float tv[4];
                    #pragma unroll
                    for (int r = 0; r < 4; ++r)
                        tv[r] = 2.f * acc[4 * rh + r][4 * sh + s] - xxi[4 * rh + r] - xxj[4 * sh + s];
                    *(float4*)(Dp + (size_t)jrow * NN + i0 + 64 * rh + 4 * ty) = *(float4*)tv;
                }
            }
    }
}

// ---------- top-20 selection v2 (D-based, layers 2-4) ----------
__global__ __launch_bounds__(256) void k_select(const float* __restrict__ D,
                                                int* __restrict__ idxo, int b0) {
    __shared__ unsigned long long cbuf[4][64];
    int tid = threadIdx.x;
    int lane = tid & 63, wid = tid >> 6;
    int w = (blockIdx.x << 2) + wid;
    int bl = w / NN, n = w % NN;
    const float* row = D + (size_t)w * NN;
    unsigned uv[32];
    #pragma unroll
    for (int q = 0; q < 8; ++q) {
        float4 f4 = *(const float4*)(row + 4 * lane + 256 * q);
        float fv[4] = {f4.x, f4.y, f4.z, f4.w};
        #pragma unroll
        for (int u = 0; u < 4; ++u) {
            unsigned bb_ = __float_as_uint(fv[u]);
            uv[4 * q + u] = bb_ ^ ((bb_ & 0x80000000u) ? 0xFFFFFFFFu : 0x80000000u);
        }
    }
    unsigned bu = uv[0]; int bj = 0;
    #pragma unroll
    for (int j = 1; j < 32; ++j) if (uv[j] > bu) { bu = uv[j]; bj = j; }
    int bcol = 4 * lane + 256 * (bj >> 2) + (bj & 3);
    unsigned long long key = ((unsigned long long)(~bu) << 32) | (unsigned)bcol;
    #pragma unroll
    for (int k = 2; k <= 64; k <<= 1)
        #pragma unroll
        for (int j = k >> 1; j > 0; j >>= 1) {
            unsigned long long o = __shfl_xor(key, j);
            bool keepMin = ((lane & k) == 0) == ((lane & j) == 0);
            bool omin = o < key;
            if (omin == keepMin) key = o;
        }
    unsigned long long Tkey = __shfl(key, 19);
    unsigned uT = ~(unsigned)(Tkey >> 32);
    int cnt = 0;
    #pragma unroll
    for (int j = 0; j < 32; ++j) cnt += (uv[j] >= uT) ? 1 : 0;
    int M = cnt;
    #pragma unroll
    for (int s = 1; s < 64; s <<= 1) M += __shfl_xor(M, s);
    int* op = idxo + ((size_t)(b0 + bl) * NN + n) * KNN;
    if (M <= 64) {
        int inc = cnt;
        #pragma unroll
        for (int s = 1; s < 64; s <<= 1) {
            int t = __shfl_up(inc, s);
            if (lane >= s) inc += t;
        }
        int p = inc - cnt;
        #pragma unroll
        for (int j = 0; j < 32; ++j) {
            if (uv[j] >= uT) {
                int col = 4 * lane + 256 * (j >> 2) + (j & 3);
                cbuf[wid][p++] = ((unsigned long long)(~uv[j]) << 32) | (unsigned)col;
            }
        }
        asm volatile("s_waitcnt lgkmcnt(0)" ::: "memory");
        unsigned long long k2 = (lane < M) ? cbuf[wid][lane] : 0xFFFFFFFFFFFFFFFFull;
        #pragma unroll
        for (int k = 2; k <= 64; k <<= 1)
            #pragma unroll
            for (int j = k >> 1; j > 0; j >>= 1) {
                unsigned long long o = __shfl_xor(k2, j);
                bool keepMin = ((lane & k) == 0) == ((lane & j) == 0);
                bool omin = o < k2;
                if (omin == keepMin) k2 = o;
            }
        if (lane < KNN) op[lane] = (int)(unsigned)(k2 & 0xFFFFFFFFu);
    } else {
        for (int k = 0; k < KNN; ++k) {
            unsigned rv = bu;
            int rc = 4 * lane + 256 * (bj >> 2) + (bj & 3);
            #pragma unroll
            for (int s = 1; s < 64; s <<= 1) {
                unsigned ov = __shfl_xor(rv, s);
                int oc = __shfl_xor(rc, s);
                if (ov > rv || (ov == rv && oc < rc)) { rv = ov; rc = oc; }
            }
            if (lane == 0) op[k] = rc;
            if (((rc >> 2) & 63) == lane) {
                int oj = ((rc >> 8) << 2) | (rc & 3);
                #pragma unroll
                for (int j = 0; j < 32; ++j) if (j == oj) uv[j] = 0u;
                bu = uv[0]; bj = 0;
                #pragma unroll
                for (int j = 1; j < 32; ++j) if (uv[j] > bu) { bu = uv[j]; bj = j; }
            }
        }
    }
}

// ---------- fused C=3 KNN: reads x natively (B,3,N); coords + inline norms in LDS ----------
__global__ __launch_bounds__(256) void k_select3(const float* __restrict__ x,
                                                 int* __restrict__ idxo) {
    __shared__ float xs[NN], ys[NN], zs[NN], xxs[NN];
    __shared__ unsigned long long cbuf[4][64];
    int tid = threadIdx.x;
    int lane = tid & 63, wid = tid >> 6;
    int b = blockIdx.x >> 9;
    int n = (blockIdx.x & 511) * 4 + wid;
    const float* Fb = x + (size_t)b * 3 * NN;
    for (int t = tid; t < NN; t += 256) {
        float xv = Fb[t], yv = Fb[NN + t], zv = Fb[2 * NN + t];
        xs[t] = xv; ys[t] = yv; zs[t] = zv;
        float s = 0.f; s += xv * xv; s += yv * yv; s += zv * zv;
        xxs[t] = s;
    }
    __syncthreads();
    float qx = xs[n], qy = ys[n], qz = zs[n], xxn = xxs[n];
    unsigned uv[32];
    #pragma unroll
    for (int j = 0; j < 32; ++j) {
        int m = lane + 64 * j;
        float dot = qx * xs[m];
        dot = fmaf(qy, ys[m], dot);
        dot = fmaf(qz, zs[m], dot);
        float d = 2.f * dot - xxn - xxs[m];
        unsigned bb_ = __float_as_uint(d);
        uv[j] = bb_ ^ ((bb_ & 0x80000000u) ? 0xFFFFFFFFu : 0x80000000u);
    }
    unsigned bu = uv[0]; int bj = 0;
    #pragma unroll
    for (int j = 1; j < 32; ++j) if (uv[j] > bu) { bu = uv[j]; bj = j; }
    int bcol = lane + 64 * bj;
    unsigned long long key = ((unsigned long long)(~bu) << 32) | (unsigned)bcol;
    #pragma unroll
    for (int k = 2; k <= 64; k <<= 1)
        #pragma unroll
        for (int j = k >> 1; j > 0; j >>= 1) {
            unsigned long long o = __shfl_xor(key, j);
            bool keepMin = ((lane & k) == 0) == ((lane & j) == 0);
            bool omin = o < key;
            if (omin == keepMin) key = o;
        }
    unsigned long long Tkey = __shfl(key, 19);
    unsigned uT = ~(unsigned)(Tkey >> 32);
    int cnt = 0;
    #pragma unroll
    for (int j = 0; j < 32; ++j) cnt += (uv[j] >= uT) ? 1 : 0;
    int M = cnt;
    #pragma unroll
    for (int s = 1; s < 64; s <<= 1) M += __shfl_xor(M, s);
    int* op = idxo + ((size_t)b * NN + n) * KNN;
    if (M <= 64) {
        int inc = cnt;
        #pragma unroll
        for (int s = 1; s < 64; s <<= 1) {
            int t = __shfl_up(inc, s);
            if (lane >= s) inc += t;
        }
        int p = inc - cnt;
        #pragma unroll
        for (int j = 0; j < 32; ++j) {
            if (uv[j] >= uT) {
                int col = lane + 64 * j;
                cbuf[wid][p++] = ((unsigned long long)(~uv[j]) << 32) | (unsigned)col;
            }
        }
        asm volatile("s_waitcnt lgkmcnt(0)" ::: "memory");
        unsigned long long k2 = (lane < M) ? cbuf[wid][lane] : 0xFFFFFFFFFFFFFFFFull;
        #pragma unroll
        for (int k = 2; k <= 64; k <<= 1)
            #pragma unroll
            for (int j = k >> 1; j > 0; j >>= 1) {
                unsigned long long o = __shfl_xor(k2, j);
                bool keepMin = ((lane & k) == 0) == ((lane & j) == 0);
                bool omin = o < k2;
                if (omin == keepMin) k2 = o;
            }
        if (lane < KNN) op[lane] = (int)(unsigned)(k2 & 0xFFFFFFFFu);
    } else {
        for (int k = 0; k < KNN; ++k) {
            unsigned rv = bu;
            int rc = lane + 64 * bj;
            #pragma unroll
            for (int s = 1; s < 64; s <<= 1) {
                unsigned ov = __shfl_xor(rv, s);
                int oc = __shfl_xor(rc, s);
                if (ov > rv || (ov == rv && oc < rc)) { rv = ov; rc = oc; }
            }
            if (lane == 0) op[k] = rc;
            if ((rc & 63) == lane) {
                int oj = rc >> 6;
                #pragma unroll
                for (int j = 0; j < 32; ++j) if (j == oj) uv[j] = 0u;
                bu = uv[0]; bj = 0;
                #pragma unroll
                for (int j = 1; j < 32; ++j) if (uv[j] > bu) { bu = uv[j]; bj = j; }
            }
        }
    }
}

// ---------- pair GEMM: Y = F*wtA (union buffer), C2 = F*wtD -> xcat slot.
// CMAJ=true: F is x in (B,3,N) layout (layer 1). ----------
template<int CIN, int COUT, bool CMAJ>
__global__ __launch_bounds__(256) void k_gemm_pair(const float* __restrict__ F, int FS, int b0,
    const float* __restrict__ wtA, const float* __restrict__ wtD,
    float* __restrict__ Y, float* __restrict__ c2x) {
    constexpr int CCH = (CIN >= 32) ? 32 : CIN;
    constexpr int NCH = CIN / CCH;
    __shared__ __align__(16) float Xi[CCH * 64];
    __shared__ __align__(16) float Wa[CCH * 64];
    __shared__ __align__(16) float Wd[CCH * 64];
    int tid = threadIdx.x;
    int r0 = blockIdx.x * 64;
    int c0 = blockIdx.y * 64;
    int b = b0 + r0 / NN;
    int n0 = r0 % NN;
    const float* Fb = CMAJ ? (F + (size_t)b * CIN * NN + n0)
                           : (F + ((size_t)b * NN + n0) * FS);
    int ty = tid >> 4, tx = tid & 15;
    float accY[4][4] = {}, accD[4][4] = {};
    for (int ch = 0; ch < NCH; ++ch) {
        int cb = ch * CCH;
        if (ch) __syncthreads();
        if constexpr (CMAJ) {
            for (int t = tid; t < 64 * CCH; t += 256) {
                int r = t & 63, c = t >> 6;
                Xi[c * 64 + r] = Fb[(size_t)(cb + c) * NN + r];
            }
            for (int t = tid; t < CCH * 64; t += 256) {
                int col = t & 63, c = t >> 6;
                Wa[c * 64 + col] = wtA[(size_t)(cb + c) * COUT + c0 + col];
                Wd[c * 64 + col] = wtD[(size_t)(cb + c) * COUT + c0 + col];
            }
        } else if constexpr (CCH % 4 == 0) {
            for (int t = tid; t < 64 * (CCH / 4); t += 256) {
                int r = t & 63, cc = t >> 6;
                float v[4];
                *(float4*)v = *(const float4*)(Fb + (size_t)r * FS + cb + 4 * cc);
                #pragma unroll
                for (int u = 0; u < 4; ++u) Xi[(4 * cc + u) * 64 + r] = v[u];
            }
            for (int t = tid; t < CCH * 16; t += 256) {
                int c = t >> 4, q = t & 15;
                *(float4*)&Wa[c * 64 + 4 * q] = *(const float4*)(wtA + (size_t)(cb + c) * COUT + c0 + 4 * q);
                *(float4*)&Wd[c * 64 + 4 * q] = *(const float4*)(wtD + (size_t)(cb + c) * COUT + c0 + 4 * q);
            }
        } else {
            for (int t = tid; t < 64 * CCH; t += 256) {
                int r = t & 63, c = t >> 6;
                Xi[c * 64 + r] = Fb[(size_t)r * FS + cb + c];
            }
            for (int t = tid; t < CCH * 64; t += 256) {
                int col = t & 63, c = t >> 6;
                Wa[c * 64 + col] = wtA[(size_t)(cb + c) * COUT + c0 + col];
                Wd[c * 64 + col] = wtD[(size_t)(cb + c) * COUT + c0 + col];
            }
        }
        __syncthreads();
        for (int c = 0; c < CCH; ++c) {
            float a[4], wa[4], wd[4];
            *(float4*)a  = *(const float4*)&Xi[c * 64 + 4 * ty];
            *(float4*)wa = *(const float4*)&Wa[c * 64 + 4 * tx];
            *(float4*)wd = *(const float4*)&Wd[c * 64 + 4 * tx];
            #pragma unroll
            for (int r = 0; r < 4; ++r)
                #pragma unroll
                for (int s = 0; s < 4; ++s) {
                    accY[r][s] += a[r] * wa[s];
                    accD[r][s] += a[r] * wd[s];
                }
        }
    }
    #pragma unroll
    for (int r = 0; r < 4; ++r) {
        *(float4*)(Y + (size_t)(r0 + 4 * ty + r) * COUT + c0 + 4 * tx) = *(float4*)accY[r];
        *(float4*)(c2x + ((size_t)b0 * NN + r0 + 4 * ty + r) * 512 + c0 + 4 * tx) = *(float4*)accD[r];
    }
}

// ---------- gather-max: 4 independent max groups (exact; max is assoc/comm),
// all 20 indices preloaded -> deep memory ILP ----------
template<int COUT>
__global__ __launch_bounds__(256) void k_gather(const float* __restrict__ Y,
    const int* __restrict__ idx, const float* __restrict__ sc, const float* __restrict__ bi,
    float* io, int b0) {
    constexpr int LPP = COUT / 4;
    constexpr int PPW = 64 / LPP;
    constexpr int PPB = 4 * PPW;
    int tid = threadIdx.x;
    int lane = tid & 63, wv = tid >> 6;
    int pl = blockIdx.x * PPB + wv * PPW + lane / LPP;
    int bl = pl / NN, n = pl % NN;
    int o0 = 4 * (lane % LPP);
    float* iop = io + ((size_t)(b0 + bl) * NN + n) * 512 + o0;
    float c2[4], s4[4], b4[4];
    *(float4*)c2 = *(const float4*)iop;
    *(float4*)s4 = *(const float4*)(sc + o0);
    *(float4*)b4 = *(const float4*)(bi + o0);
    const int* ip = idx + ((size_t)(b0 + bl) * NN + n) * KNN;
    int mi[KNN];
    #pragma unroll
    for (int k = 0; k < KNN; ++k) mi[k] = ip[k];
    const float* Yb = Y + (size_t)bl * NN * COUT;
    float mx[4][4];
    #pragma unroll
    for (int g = 0; g < 4; ++g)
        #pragma unroll
        for (int u = 0; u < 4; ++u) mx[g][u] = -FLT_MAX;
    #pragma unroll
    for (int kk = 0; kk < KNN / 4; ++kk) {
        float y[4][4];
        #pragma unroll
        for (int g = 0; g < 4; ++g)
            *(float4*)y[g] = *(const float4*)(Yb + (size_t)mi[kk * 4 + g] * COUT + o0);
        #pragma unroll
        for (int g = 0; g < 4; ++g)
            #pragma unroll
            for (int u = 0; u < 4; ++u) {
                float v = (y[g][u] + c2[u]) * s4[u] + b4[u];
                mx[g][u] = fmaxf(mx[g][u], leaky(v));
            }
    }
    float res[4];
    #pragma unroll
    for (int u = 0; u < 4; ++u)
        res[u] = fmaxf(fmaxf(mx[0][u], mx[1][u]), fmaxf(mx[2][u], mx[3][u]));
    *(float4*)iop = *(float4*)res;
}

// ---------- conv5 (R13 proven): 128x128 tile, 8x8 micro-tile, Wj via
// global_load_lds, fused partial pooling ----------
__global__ __launch_bounds__(256) void k_conv5(const float* __restrict__ xcat,
    const float* __restrict__ w5t, const float* __restrict__ s5, const float* __restrict__ b5,
    float* __restrict__ pmax, float* __restrict__ psum) {
    __shared__ __align__(16) float Xi[32 * 128];
    __shared__ __align__(16) float Wj[32 * 128];
    int tid = threadIdx.x;
    int ty = tid >> 4, tx = tid & 15;
    int wv6 = tid >> 6, lane6 = tid & 63;
    int r0 = blockIdx.x * 128;
    int col0 = blockIdx.y * 128;
    int b = r0 / NN, tileInB = (r0 % NN) / 128;
    const float* Fb = xcat + (size_t)r0 * 512;
    float acc[8][8] = {};
    for (int ch = 0; ch < 16; ++ch) {
        int cb = ch * 32;
        if (ch) __syncthreads();
        for (int t = tid; t < 128 * 8; t += 256) {
            int r = t & 127, cc = t >> 7;
            float v[4];
            *(float4*)v = *(const float4*)(Fb + (size_t)r * 512 + cb + 4 * cc);
            #pragma unroll
            for (int u = 0; u < 4; ++u) Xi[(4 * cc + u) * 128 + r] = v[u];
        }
        #pragma unroll
        for (int i = 0; i < 4; ++i) {
            int basec = wv6 * 8 + i * 2;
            const float* gp = w5t + (size_t)(cb + basec + (lane6 >> 5)) * 1024 + col0 + (lane6 & 31) * 4;
            __builtin_amdgcn_global_load_lds((const __attribute__((address_space(1))) void*)gp,
                (__attribute__((address_space(3))) void*)&Wj[basec * 128], 16, 0, 0);
        }
        __syncthreads();
        for (int c = 0; c < 32; ++c) {
            float a0[4], a1[4], w0[4], w1[4];
            *(float4*)a0 = *(const float4*)&Xi[c * 128 + 4 * ty];
            *(float4*)a1 = *(const float4*)&Xi[c * 128 + 64 + 4 * ty];
            *(float4*)w0 = *(const float4*)&Wj[c * 128 + 4 * tx];
            *(float4*)w1 = *(const float4*)&Wj[c * 128 + 64 + 4 * tx];
            #pragma unroll
            for (int r = 0; r < 4; ++r)
                #pragma unroll
                for (int u = 0; u < 4; ++u) {
                    acc[r][u]         += a0[r] * w0[u];
                    acc[r][4 + u]     += a0[r] * w1[u];
                    acc[4 + r][u]     += a1[r] * w0[u];
                    acc[4 + r][4 + u] += a1[r] * w1[u];
                }
        }
    }
    float hmx[2][4], hsm[2][4];
    #pragma unroll
    for (int h = 0; h < 2; ++h)
        #pragma unroll
        for (int u = 0; u < 4; ++u) { hmx[h][u] = -FLT_MAX; hsm[h][u] = 0.f; }
    #pragma unroll
    for (int h = 0; h < 2; ++h)
        #pragma unroll
        for (int u = 0; u < 4; ++u) {
            int o = col0 + 64 * h + 4 * tx + u;
            float sv = s5[o], bv = b5[o];
            #pragma unroll
            for (int r = 0; r < 8; ++r) {
                float hh = leaky(acc[r][4 * h + u] * sv + bv);
                hmx[h][u] = fmaxf(hmx[h][u], hh);
                hsm[h][u] += hh;
            }
        }
    __syncthreads();
    float* redM = Xi;
    float* redS = Wj;
    #pragma unroll
    for (int h = 0; h < 2; ++h) {
        *(float4*)&redM[ty * 128 + 64 * h + 4 * tx] = *(float4*)hmx[h];
        *(float4*)&redS[ty * 128 + 64 * h + 4 * tx] = *(float4*)hsm[h];
    }
    __syncthreads();
    for (int s = 8; s > 0; s >>= 1) {
        if (ty < s) {
            #pragma unroll
            for (int h = 0; h < 2; ++h) {
                int c = 64 * h + 4 * tx;
                float m0[4], m1[4], s0[4], s1[4];
                *(float4*)m0 = *(float4*)&redM[ty * 128 + c];
                *(float4*)m1 = *(float4*)&redM[(ty + s) * 128 + c];
                *(float4*)s0 = *(float4*)&redS[ty * 128 + c];
                *(float4*)s1 = *(float4*)&redS[(ty + s) * 128 + c];
                #pragma unroll
                for (int u = 0; u < 4; ++u) { m0[u] = fmaxf(m0[u], m1[u]); s0[u] += s1[u]; }
                *(float4*)&redM[ty * 128 + c] = *(float4*)m0;
                *(float4*)&redS[ty * 128 + c] = *(float4*)s0;
            }
        }
        __syncthreads();
    }
    if (ty == 0) {
        #pragma unroll
        for (int h = 0; h < 2; ++h) {
            int c = 64 * h + 4 * tx;
            size_t o = ((size_t)b * 16 + tileInB) * 1024 + col0 + c;
            *(float4*)&pmax[o] = *(float4*)&redM[c];
            *(float4*)&psum[o] = *(float4*)&redS[c];
        }
    }
}

__global__ void k_poolreduce(const float* __restrict__ pmax, const float* __restrict__ psum,
                             float* __restrict__ pooled) {
    int i = blockIdx.x * 256 + threadIdx.x;
    if (i >= BB * 1024) return;
    int b = i / 1024, o = i % 1024;
    float mx = -FLT_MAX, sm = 0.f;
    for (int ch = 0; ch < 16; ++ch) {
        mx = fmaxf(mx, pmax[((size_t)b * 16 + ch) * 1024 + o]);
        sm += psum[((size_t)b * 16 + ch) * 1024 + o];
    }
    pooled[(size_t)b * 2048 + o] = mx;
    pooled[(size_t)b * 2048 + 1024 + o] = sm / (float)NN;
}

// ---------- FC: wave-per-output, coalesced float4 weight reads, shfl reduce ----------
template<int CI, bool SCALE, bool RELU>
__global__ __launch_bounds__(256) void k_fcw(const float* __restrict__ in,
                                             const float* __restrict__ w,
                                             const float* __restrict__ sc,
                                             const float* __restrict__ bi,
                                             float* __restrict__ out, int CO) {
    int wv = (blockIdx.x << 2) + (threadIdx.x >> 6);
    int lane = threadIdx.x & 63;
    int o = wv % CO, b = wv / CO;
    const float* ir = in + (size_t)b * CI;
    const float* wr = w + (size_t)o * CI;
    float acc = 0.f;
    #pragma unroll
    for (int q = 0; q < CI / 256; ++q) {
        int ofs = q * 256 + 4 * lane;
        float4 wv4 = *(const float4*)(wr + ofs);
        float4 iv4 = *(const float4*)(ir + ofs);
        acc += wv4.x * iv4.x + wv4.y * iv4.y + wv4.z * iv4.z + wv4.w * iv4.w;
    }
    #pragma unroll
    for (int s = 1; s < 64; s <<= 1) acc += __shfl_xor(acc, s);
    if (lane == 0) {
        float v = SCALE ? (acc * sc[o] + bi[o]) : (acc + bi[o]);
        if (RELU) v = fmaxf(v, 0.f);
        out[wv] = v;
    }
}

extern "C" void kernel_launch(void* const* d_in, const int* in_sizes, int n_in,
                              void* d_out, int out_size, void* d_ws, size_t ws_size,
                              hipStream_t stream) {
    const float* x    = (const float*)d_in[0];
    const float* w1   = (const float*)d_in[1];
    const float* s1   = (const float*)d_in[2];
    const float* b1   = (const float*)d_in[3];
    const float* w2   = (const float*)d_in[4];
    const float* s2   = (const float*)d_in[5];
    const float* b2   = (const float*)d_in[6];
    const float* w3   = (const float*)d_in[7];
    const float* s3   = (const float*)d_in[8];
    const float* b3   = (const float*)d_in[9];
    const float* w4   = (const float*)d_in[10];
    const float* s4   = (const float*)d_in[11];
    const float* b4   = (const float*)d_in[12];
    const float* w5   = (const float*)d_in[13];
    const float* s5   = (const float*)d_in[14];
    const float* b5   = (const float*)d_in[15];
    const float* fc1w = (const float*)d_in[16];
    const float* s6   = (const float*)d_in[17];
    const float* b6   = (const float*)d_in[18];
    const float* fc2w = (const float*)d_in[19];
    const float* s7   = (const float*)d_in[20];
    const float* b7   = (const float*)d_in[21];
    const float* fc3w = (const float*)d_in[22];
    const float* fc3b = (const float*)d_in[23];
    float* out = (float*)d_out;

    char* ws = (char*)d_ws;
    size_t off = 0;
    auto alloc = [&](size_t bytes) {
        void* p = ws + off;
        off = (off + bytes + 255) & ~(size_t)255;
        return p;
    };
    float* xcat = (float*)alloc((size_t)BB * NN * 512 * 4);
    int*   idx  = (int*)  alloc((size_t)BB * NN * KNN * 4);
    float* wtA1 = (float*)alloc(3 * 64 * 4);
    float* wtD1 = (float*)alloc(3 * 64 * 4);
    float* wtA2 = (float*)alloc(64 * 64 * 4);
    float* wtD2 = (float*)alloc(64 * 64 * 4);
    float* wtA3 = (float*)alloc(64 * 128 * 4);
    float* wtD3 = (float*)alloc(64 * 128 * 4);
    float* wtA4 = (float*)alloc(128 * 256 * 4);
    float* wtD4 = (float*)alloc(128 * 256 * 4);
    size_t base_end = off;

    // UNION region: D (dist phase, per-batch chunks) / Y (transform) / head buffers
    const size_t D1 = (size_t)NN * NN * 4;
    size_t avail = ws_size > base_end ? ws_size - base_end : 0;
    int nbD = (int)(avail / D1);
    if (nbD < 1) nbD = 1;
    if (nbD > BB) nbD = BB;
    char* uni = ws + base_end;
    float* D      = (float*)uni;
    float* w5t    = (float*)uni;
    float* pmax   = w5t + 512 * 1024;
    float* psum   = pmax + (size_t)BB * 16 * 1024;
    float* pooled = psum + (size_t)BB * 16 * 1024;
    float* f1     = pooled + (size_t)BB * 2048;
    float* f2     = f1 + (size_t)BB * 512;

    k_wpair_all<<<(45248 + 255) / 256, 256, 0, stream>>>(w1, w2, w3, w4,
        wtA1, wtD1, wtA2, wtD2, wtA3, wtD3, wtA4, wtD4);

    // transform + gather helper (Y-only union buffer; C2 straight into xcat)
    auto xform = [&](auto cTag, auto coTag, auto cmajTag, const float* F, int FS,
                     const float* wtA, const float* wtD,
                     const float* sc, const float* bi, float* outp) {
        constexpr int C  = decltype(cTag)::value;
        constexpr int CO = decltype(coTag)::value;
        constexpr bool CM = decltype(cmajTag)::value;
        size_t ypb = (size_t)NN * CO * 4;
        int nbY = (int)(avail / ypb);
        if (nbY < 1) nbY = 1;
        if (nbY > BB) nbY = BB;
        for (int b0 = 0; b0 < BB; b0 += nbY) {
            int nb = BB - b0 < nbY ? BB - b0 : nbY;
            float* Yc = (float*)uni;
            dim3 g((nb * NN) / 64, CO / 64);
            k_gemm_pair<C, CO, CM><<<g, 256, 0, stream>>>(F, FS, b0, wtA, wtD, Yc, outp);
            constexpr int PPB = 4 * (64 / (CO / 4));
            k_gather<CO><<<(nb * NN) / PPB, 256, 0, stream>>>(Yc, idx, sc, bi, outp, b0);
        }
    };

    // ---- Layer 1 (C=3): fused dist+select from native x, no D buffer ----
    k_select3<<<BB * 512, 256, 0, stream>>>(x, idx);
    xform(std::integral_constant<int, 3>{}, std::integral_constant<int, 64>{},
          std::integral_constant<bool, true>{}, x, 3, wtA1, wtD1, s1, b1, xcat + 0);

    // ---- Layers 2-4 (C>=64): symmetric dist w/ inline norms, threshold select ----
    auto layerBig = [&](auto cTag, auto coTag, const float* F, int FS,
                        const float* wtA, const float* wtD,
                        const float* sc, const float* bi, float* outp) {
        constexpr int C  = decltype(cTag)::value;
        for (int b0 = 0; b0 < BB; b0 += nbD) {
            int nb = BB - b0 < nbD ? BB - b0 : nbD;
            k_dist128s<C><<<nb * 136, 256, 0, stream>>>(F, FS, b0, D);
            k_select<<<nb * 512, 256, 0, stream>>>(D, idx, b0);
        }
        xform(cTag, coTag, std::integral_constant<bool, false>{}, F, FS, wtA, wtD, sc, bi, outp);
    };

    layerBig(std::integral_constant<int, 64>{},  std::integral_constant<int, 64>{},  xcat + 0,   512, wtA2, wtD2, s2, b2, xcat + 64);
    layerBig(std::integral_constant<int, 64>{},  std::integral_constant<int, 128>{}, xcat + 64,  512, wtA3, wtD3, s3, b3, xcat + 128);
    layerBig(std::integral_constant<int, 128>{}, std::integral_constant<int, 256>{}, xcat + 128, 512, wtA4, wtD4, s4, b4, xcat + 256);

    // head (union region now holds w5t/pmax/psum/pooled/f1/f2)
    dim3 gt(1024 / 64, 512 / 64);
    k_transpose_w_tiled<<<gt, 256, 0, stream>>>(w5, w5t, 1024, 512);
    dim3 g5((BB * NN) / 128, 1024 / 128);
    k_conv5<<<g5, 256, 0, stream>>>(xcat, w5t, s5, b5, pmax, psum);
    k_poolreduce<<<(BB * 1024 + 255) / 256, 256, 0, stream>>>(pmax, psum, pooled);
    k_fcw<2048, true,  true ><<<(BB * 512) / 4, 256, 0, stream>>>(pooled, fc1w, s6, b6, f1, 512);
    k_fcw<512,  true,  true ><<<(BB * 256) / 4, 256, 0, stream>>>(f1, fc2w, s7, b7, f2, 256);
    k_fcw<256,  false, false><<<(BB * 40)  / 4, 256, 0, stream>>>(f2, fc3w, nullptr, fc3b, out, 40);
}